// Round 1
// baseline (668.088 us; speedup 1.0000x reference)
//
#include <hip/hip_runtime.h>
#include <float.h>
#include <math.h>

#define HF 128
#define SCAN_CHUNK 4096  // 256 threads x 16 elems
#define FILL_CHUNK 2048  // edges per fill block-group (8 iters x 256)
#define CE_ST 16         // cnt_e stride (ints): 1 counter per 64B line
#define CV_ST 8          // cnt_v stride (ints): 1 counter per 32B sector

static inline int idiv(int a, int b) { return (a + b - 1) / b; }

__device__ inline unsigned short f2bf(float x) {  // RNE float->bf16
  unsigned u = __float_as_uint(x);
  return (unsigned short)((u + 0x7fffu + ((u >> 16) & 1u)) >> 16);
}
__device__ inline unsigned packbf(float a, float b) {
  return (unsigned)f2bf(a) | ((unsigned)f2bf(b) << 16);
}
#define BFLO(w) __uint_as_float((w) << 16)
#define BFHI(w) __uint_as_float((w) & 0xffff0000u)

// ---------------- CSR construction (device bodies for horizontal fusion) ----------------
// count: 4 edges/thread, batched independent atomics (4x memory-level parallelism).
// Interleaved parity: even threads hit cnt_e, odd hit cnt_v.

__device__ void count_body(const int* __restrict__ nidx, const int* __restrict__ hidx,
                           int E2, int* cnt_v, int* cnt_e,
                           unsigned short* __restrict__ rank_h,
                           unsigned short* __restrict__ rank_v, int bx) {
  int tid = threadIdx.x;
  int base = bx * 1024 + tid;
  bool odd = tid & 1;  // stride 256 keeps parity constant per thread
  int e[4], seg[4], rr[4];
  bool val[4];
#pragma unroll
  for (int i = 0; i < 4; ++i) {
    int t = base + i * 256;
    val[i] = t < E2;
    e[i] = t >> 1;
  }
#pragma unroll
  for (int i = 0; i < 4; ++i)
    if (val[i]) seg[i] = odd ? nidx[e[i]] : hidx[e[i]];
#pragma unroll
  for (int i = 0; i < 4; ++i)
    if (val[i]) rr[i] = odd ? atomicAdd(&cnt_v[seg[i] * CV_ST], 1)
                            : atomicAdd(&cnt_e[seg[i] * CE_ST], 1);
#pragma unroll
  for (int i = 0; i < 4; ++i)
    if (val[i]) {
      if (odd) rank_v[e[i]] = (unsigned short)rr[i];
      else     rank_h[e[i]] = (unsigned short)rr[i];
    }
}

// ---- fused 3-phase multi-block exclusive scan over both (strided) count arrays ----

__global__ __launch_bounds__(256) void scanA2(const int* __restrict__ inE, int nE, int nbE,
                                              int* __restrict__ partE,
                                              const int* __restrict__ inV, int nV,
                                              int* __restrict__ partV) {
  const int* in; int n, st, b; int* partials;
  if ((int)blockIdx.x < nbE) { in = inE; n = nE; st = CE_ST; b = blockIdx.x; partials = partE; }
  else { in = inV; n = nV; st = CV_ST; b = blockIdx.x - nbE; partials = partV; }
  __shared__ int lds[256];
  int tid = threadIdx.x;
  int base = b * SCAN_CHUNK + tid * 16;
  int s = 0;
#pragma unroll
  for (int i = 0; i < 16; ++i) {
    int idx = base + i;
    if (idx < n) s += in[(size_t)idx * st];
  }
  lds[tid] = s;
  __syncthreads();
  for (int off = 128; off; off >>= 1) {
    if (tid < off) lds[tid] += lds[tid + off];
    __syncthreads();
  }
  if (tid == 0) partials[b] = lds[0];
}

__global__ __launch_bounds__(256) void scanB2(int* __restrict__ partE, int nbE,
                                              int* __restrict__ partV, int nbV) {
  int* partials = (blockIdx.x == 0) ? partE : partV;
  int nb = (blockIdx.x == 0) ? nbE : nbV;
  __shared__ int lds[256];
  int tid = threadIdx.x;
  int v = (tid < nb) ? partials[tid] : 0;
  lds[tid] = v;
  __syncthreads();
  for (int off = 1; off < 256; off <<= 1) {
    int add = (tid >= off) ? lds[tid - off] : 0;
    __syncthreads();
    lds[tid] += add;
    __syncthreads();
  }
  if (tid < nb) partials[tid] = lds[tid] - v;  // exclusive
  if (tid == nb - 1) partials[nb] = lds[tid];  // total
}

__global__ __launch_bounds__(256) void scanC2(const int* __restrict__ inE, int nE, int nbE,
                                              const int* __restrict__ partE, int* __restrict__ outE,
                                              const int* __restrict__ inV, int nV, int nbV,
                                              const int* __restrict__ partV, int* __restrict__ outV) {
  const int* in; const int* partials; int* out; int n, st, b, nb;
  if ((int)blockIdx.x < nbE) { in = inE; n = nE; st = CE_ST; b = blockIdx.x; partials = partE; out = outE; nb = nbE; }
  else { in = inV; n = nV; st = CV_ST; b = blockIdx.x - nbE; partials = partV; out = outV; nb = nbV; }
  __shared__ int lds[256];
  int tid = threadIdx.x;
  int base = b * SCAN_CHUNK + tid * 16;
  int vals[16];
  int s = 0;
#pragma unroll
  for (int i = 0; i < 16; ++i) {
    int idx = base + i;
    int v = (idx < n) ? in[(size_t)idx * st] : 0;
    vals[i] = s;
    s += v;
  }
  lds[tid] = s;
  __syncthreads();
  int own = s;
  for (int off = 1; off < 256; off <<= 1) {
    int add = (tid >= off) ? lds[tid - off] : 0;
    __syncthreads();
    lds[tid] += add;
    __syncthreads();
  }
  int excl = lds[tid] - own + partials[b];
#pragma unroll
  for (int i = 0; i < 16; ++i) {
    int idx = base + i;
    if (idx < n) out[idx] = excl + vals[i];
  }
  if (b == 0 && tid == 0) out[n] = partials[nb];
}

// Atomic-free XCD-localized scatter: pos = off[seg] + rank[e]; store only.
__device__ void fill_body(const int* __restrict__ nidx,
                          const int* __restrict__ hidx,
                          const unsigned short* __restrict__ rank_h,
                          const unsigned short* __restrict__ rank_v,
                          int E, int M, int N,
                          const int* __restrict__ off_e,
                          const int* __restrict__ off_v,
                          unsigned short* __restrict__ by_h,
                          unsigned short* __restrict__ by_v, int bx) {
  int cls = bx & 7;
  int base = (bx >> 3) * FILL_CHUNK + threadIdx.x;
#pragma unroll 1
  for (int i = 0; i < FILL_CHUNK / 256; ++i) {
    int e = base + i * 256;
    if (e < E) {
      int hh = hidx[e];
      int vv = nidx[e];
      if ((hh * 8) / M == cls) by_h[off_e[hh] + rank_h[e]] = (unsigned short)vv;
      if ((int)(((long long)vv * 8) / N) == cls) by_v[off_v[vv] + rank_v[e]] = (unsigned short)hh;
    }
  }
}

// wqt = Wq^T * (1/sqrt(128)) [score scale folded]; wcat[:,128:256] = Wv.
__device__ void prep_att_body(const float* __restrict__ Wq, const float* __restrict__ Wv,
                              float* __restrict__ wqt, float* __restrict__ wcat, int bx) {
  int i = bx * 256 + threadIdx.x;  // 128*128
  if (i >= 128 * 128) return;
  int r = i >> 7, c = i & 127;
  wqt[c * 128 + r] = Wq[i] * 0.08838834764831845f;
  wcat[r * 256 + 128 + c] = Wv[i];
}

// ---------------- GEMM A: 128x64 tile, 8x4 micro, fused input-norm / bf16-out / fp32+bf16 shadow ----------------

__device__ void gemm128_body(const float* __restrict__ A,
                             const float* __restrict__ W,
                             const float* __restrict__ bias,
                             float* __restrict__ out,
                             int R, int K, int C, int act,
                             const float* __restrict__ insc,
                             const float* __restrict__ insh, int inact,
                             int obf16,
                             unsigned short* __restrict__ out16,
                             int bx, int by) {
  __shared__ __align__(16) float As[128][20];
  __shared__ __align__(16) float Bs[16][64];
  int tid = threadIdx.x;
  int tx = tid & 15;
  int ty = tid >> 4;
  int rowBase = bx * 128;
  int colBase = by * 64;

  float acc[8][4] = {};

  for (int k0 = 0; k0 < K; k0 += 16) {
#pragma unroll
    for (int p = 0; p < 2; ++p) {
      int li = tid + 256 * p;
      int arow = li >> 2, ac = (li & 3) * 4;
      int gr = rowBase + arow;
      float4 av = make_float4(0.f, 0.f, 0.f, 0.f);
      if (gr < R) av = *(const float4*)(A + (size_t)gr * K + k0 + ac);
      if (insc) {
        float vv[4] = {av.x, av.y, av.z, av.w};
#pragma unroll
        for (int i = 0; i < 4; ++i) {
          float s = insc[k0 + ac + i], sh = insh[k0 + ac + i];
          float v = vv[i] * s + sh;
          if (inact) v = v > 0.f ? v : 0.01f * v;
          vv[i] = v;
        }
        av = make_float4(vv[0], vv[1], vv[2], vv[3]);
      }
      *(float4*)&As[arow][ac] = av;
    }
    {
      int bk = tid >> 4, bc = (tid & 15) * 4;
      *(float4*)&Bs[bk][bc] = *(const float4*)(W + (size_t)(k0 + bk) * C + colBase + bc);
    }
    __syncthreads();
#pragma unroll
    for (int kg = 0; kg < 16; kg += 4) {
      float af[8][4], bf[4][4];
#pragma unroll
      for (int i = 0; i < 4; ++i) {
        *(float4*)af[i]     = *(const float4*)&As[ty * 4 + i][kg];
        *(float4*)af[i + 4] = *(const float4*)&As[64 + ty * 4 + i][kg];
      }
#pragma unroll
      for (int kk = 0; kk < 4; ++kk)
        *(float4*)bf[kk] = *(const float4*)&Bs[kg + kk][tx * 4];
#pragma unroll
      for (int kk = 0; kk < 4; ++kk)
#pragma unroll
        for (int i = 0; i < 8; ++i)
#pragma unroll
          for (int j = 0; j < 4; ++j)
            acc[i][j] = fmaf(af[i][kk], bf[kk][j], acc[i][j]);
    }
    __syncthreads();
  }

#pragma unroll
  for (int i = 0; i < 8; ++i) {
    int r = rowBase + ty * 4 + (i & 3) + (i >> 2) * 64;
    if (r >= R) continue;
    float vals[4];
#pragma unroll
    for (int j = 0; j < 4; ++j) {
      float v = acc[i][j];
      if (bias) v += bias[colBase + tx * 4 + j];
      if (act) v = v > 0.f ? v : 0.01f * v;
      vals[j] = v;
    }
    if (obf16) {
      unsigned short* o16 = (unsigned short*)out;
      ushort4 w = make_ushort4(f2bf(vals[0]), f2bf(vals[1]), f2bf(vals[2]), f2bf(vals[3]));
      *(ushort4*)(o16 + (size_t)r * C + colBase + tx * 4) = w;
    } else {
      *(float4*)(out + (size_t)r * C + colBase + tx * 4) =
          make_float4(vals[0], vals[1], vals[2], vals[3]);
      if (out16) {
        uint2 w = make_uint2(packbf(vals[0], vals[1]), packbf(vals[2], vals[3]));
        *(uint2*)(out16 + (size_t)r * C + colBase + tx * 4) = w;
      }
    }
  }
}

// ---------------- GEMM A2: 64x64 tile, 4x4 micro; ldo = output row stride ----------------

__device__ void gemm64_body(const float* __restrict__ A,
                            const float* __restrict__ W,
                            const float* __restrict__ bias,
                            float* __restrict__ out,
                            int R, int K, int C, int act,
                            const float* __restrict__ insc,
                            const float* __restrict__ insh, int inact,
                            int ldo, int bx, int by) {
  __shared__ __align__(16) float As2[64][20];
  __shared__ __align__(16) float Bs2[16][64];
  int tid = threadIdx.x;
  int tx = tid & 15;
  int ty = tid >> 4;
  int rowBase = bx * 64;
  int colBase = by * 64;

  float acc[4][4] = {};

  for (int k0 = 0; k0 < K; k0 += 16) {
    {
      int arow = tid >> 2, ac = (tid & 3) * 4;
      int gr = rowBase + arow;
      float4 av = make_float4(0.f, 0.f, 0.f, 0.f);
      if (gr < R) av = *(const float4*)(A + (size_t)gr * K + k0 + ac);
      if (insc) {
        float vv[4] = {av.x, av.y, av.z, av.w};
#pragma unroll
        for (int i = 0; i < 4; ++i) {
          float s = insc[k0 + ac + i], sh = insh[k0 + ac + i];
          float v = vv[i] * s + sh;
          if (inact) v = v > 0.f ? v : 0.01f * v;
          vv[i] = v;
        }
        av = make_float4(vv[0], vv[1], vv[2], vv[3]);
      }
      *(float4*)&As2[arow][ac] = av;
    }
    {
      int bk = tid >> 4, bc = (tid & 15) * 4;
      *(float4*)&Bs2[bk][bc] = *(const float4*)(W + (size_t)(k0 + bk) * C + colBase + bc);
    }
    __syncthreads();
#pragma unroll
    for (int kg = 0; kg < 16; kg += 4) {
      float af[4][4], bf[4][4];
#pragma unroll
      for (int i = 0; i < 4; ++i)
        *(float4*)af[i] = *(const float4*)&As2[ty * 4 + i][kg];
#pragma unroll
      for (int kk = 0; kk < 4; ++kk)
        *(float4*)bf[kk] = *(const float4*)&Bs2[kg + kk][tx * 4];
#pragma unroll
      for (int kk = 0; kk < 4; ++kk)
#pragma unroll
        for (int i = 0; i < 4; ++i)
#pragma unroll
          for (int j = 0; j < 4; ++j)
            acc[i][j] = fmaf(af[i][kk], bf[kk][j], acc[i][j]);
    }
    __syncthreads();
  }

#pragma unroll
  for (int i = 0; i < 4; ++i) {
    int r = rowBase + ty * 4 + i;
    if (r >= R) continue;
    float vals[4];
#pragma unroll
    for (int j = 0; j < 4; ++j) {
      float v = acc[i][j];
      if (bias) v += bias[colBase + tx * 4 + j];
      if (act) v = v > 0.f ? v : 0.01f * v;
      vals[j] = v;
    }
    *(float4*)(out + (size_t)r * ldo + colBase + tx * 4) = make_float4(vals[0], vals[1], vals[2], vals[3]);
  }
}

// Global wrappers for standalone uses (sr2 / ef / cls)
__global__ __launch_bounds__(256) void gemm128(const float* __restrict__ A,
                                               const float* __restrict__ W,
                                               const float* __restrict__ bias,
                                               float* __restrict__ out,
                                               int R, int K, int C, int act,
                                               const float* __restrict__ insc,
                                               const float* __restrict__ insh, int inact,
                                               int obf16,
                                               unsigned short* __restrict__ out16) {
  gemm128_body(A, W, bias, out, R, K, C, act, insc, insh, inact, obf16, out16,
               blockIdx.x, blockIdx.y);
}

__global__ __launch_bounds__(256) void gemm64(const float* __restrict__ A,
                                              const float* __restrict__ W,
                                              const float* __restrict__ bias,
                                              float* __restrict__ out,
                                              int R, int K, int C, int act,
                                              const float* __restrict__ insc,
                                              const float* __restrict__ insh, int inact,
                                              int ldo) {
  gemm64_body(A, W, bias, out, R, K, C, act, insc, insh, inact, ldo,
              blockIdx.x, blockIdx.y);
}

// ---------------- segment ops: one wave per segment; 4 x 16-lane groups, 8 feats/lane ----------------

__device__ void seg_mean_e_body(const unsigned short* __restrict__ h16,
                                const int* __restrict__ off_e,
                                const unsigned short* __restrict__ by_h,
                                unsigned short* __restrict__ m_e16, int M, int bx) {
  int m = (bx * 256 + (int)threadIdx.x) >> 6;
  if (m >= M) return;
  int lane = threadIdx.x & 63;
  int g = lane >> 4;
  int fl = lane & 15;
  int s = off_e[m], e1 = off_e[m + 1];
  float4 a0 = make_float4(0.f, 0.f, 0.f, 0.f), a1 = a0;
  for (int j = s + g; j < e1; j += 4) {
    int vi = by_h[j];
    uint4 hw = *(const uint4*)(h16 + (size_t)vi * HF + fl * 8);
    a0.x += BFLO(hw.x); a0.y += BFHI(hw.x); a0.z += BFLO(hw.y); a0.w += BFHI(hw.y);
    a1.x += BFLO(hw.z); a1.y += BFHI(hw.z); a1.z += BFLO(hw.w); a1.w += BFHI(hw.w);
  }
#pragma unroll
  for (int mask = 16; mask <= 32; mask <<= 1) {
    a0.x += __shfl_xor(a0.x, mask); a0.y += __shfl_xor(a0.y, mask);
    a0.z += __shfl_xor(a0.z, mask); a0.w += __shfl_xor(a0.w, mask);
    a1.x += __shfl_xor(a1.x, mask); a1.y += __shfl_xor(a1.y, mask);
    a1.z += __shfl_xor(a1.z, mask); a1.w += __shfl_xor(a1.w, mask);
  }
  if (g == 0) {
    int cnt = e1 - s;
    float r = 1.f / (float)(cnt > 0 ? cnt : 1);
    uint4 w = make_uint4(packbf(a0.x * r, a0.y * r), packbf(a0.z * r, a0.w * r),
                         packbf(a1.x * r, a1.y * r), packbf(a1.z * r, a1.w * r));
    *(uint4*)(m_e16 + (size_t)m * HF + fl * 8) = w;
  }
}

__global__ __launch_bounds__(256) void seg_mean_v_add(float* __restrict__ h,
                                                      const unsigned short* __restrict__ m_e16,
                                                      const int* __restrict__ off_v,
                                                      const unsigned short* __restrict__ by_v,
                                                      int N) {
  int n = (blockIdx.x * blockDim.x + threadIdx.x) >> 6;
  if (n >= N) return;
  int lane = threadIdx.x & 63;
  int g = lane >> 4;
  int fl = lane & 15;
  int s = off_v[n], e1 = off_v[n + 1];
  float4 a0 = make_float4(0.f, 0.f, 0.f, 0.f), a1 = a0;
  for (int j = s + g; j < e1; j += 4) {
    int he = by_v[j];
    uint4 hw = *(const uint4*)(m_e16 + (size_t)he * HF + fl * 8);
    a0.x += BFLO(hw.x); a0.y += BFHI(hw.x); a0.z += BFLO(hw.y); a0.w += BFHI(hw.y);
    a1.x += BFLO(hw.z); a1.y += BFHI(hw.z); a1.z += BFLO(hw.w); a1.w += BFHI(hw.w);
  }
#pragma unroll
  for (int mask = 16; mask <= 32; mask <<= 1) {
    a0.x += __shfl_xor(a0.x, mask); a0.y += __shfl_xor(a0.y, mask);
    a0.z += __shfl_xor(a0.z, mask); a0.w += __shfl_xor(a0.w, mask);
    a1.x += __shfl_xor(a1.x, mask); a1.y += __shfl_xor(a1.y, mask);
    a1.z += __shfl_xor(a1.z, mask); a1.w += __shfl_xor(a1.w, mask);
  }
  if (g == 0) {
    int cnt = e1 - s;
    float r = 1.f / (float)(cnt > 0 ? cnt : 1);
    float* hp = h + (size_t)n * HF + fl * 8;
    float4 h0 = *(const float4*)hp;
    float4 h1 = *(const float4*)(hp + 4);
    *(float4*)hp = make_float4(h0.x + a0.x * r, h0.y + a0.y * r, h0.z + a0.z * r, h0.w + a0.w * r);
    *(float4*)(hp + 4) = make_float4(h1.x + a1.x * r, h1.y + a1.y * r, h1.z + a1.z * r, h1.w + a1.w * r);
  }
}

// Fused GAT attention: one wave per node; q = h2 (fp32, score scale pre-folded into Wqk);
// kv bf16 [M][256]; software prefetch + defer-max rescale (THR=8).
__global__ __launch_bounds__(256) void att_fused(const float* __restrict__ q,
                                                 const unsigned short* __restrict__ kv,
                                                 const int* __restrict__ off_v,
                                                 const unsigned short* __restrict__ by_v,
                                                 unsigned short* __restrict__ ho16, int N) {
  int n = (blockIdx.x * blockDim.x + threadIdx.x) >> 6;
  if (n >= N) return;
  int lane = threadIdx.x & 63;
  int g = lane >> 4;
  int fl = lane & 15;
  int s0 = off_v[n], s1 = off_v[n + 1];
  const float* qp = q + (size_t)n * HF + fl * 8;
  float4 q0 = *(const float4*)qp;
  float4 q1 = *(const float4*)(qp + 4);
  float m = -INFINITY, l = 0.f;
  float4 a0 = make_float4(0.f, 0.f, 0.f, 0.f), a1 = a0;
  int j = s0 + g;
  uint4 kw = make_uint4(0, 0, 0, 0), vw = kw;
  if (j < s1) {
    const unsigned short* base = kv + (size_t)by_v[j] * 256 + fl * 8;
    kw = *(const uint4*)base;
    vw = *(const uint4*)(base + 128);
  }
  while (j < s1) {
    int jn = j + 4;
    uint4 kw2 = make_uint4(0, 0, 0, 0), vw2 = kw2;
    if (jn < s1) {
      const unsigned short* b2 = kv + (size_t)by_v[jn] * 256 + fl * 8;
      kw2 = *(const uint4*)b2;
      vw2 = *(const uint4*)(b2 + 128);
    }
    float d = q0.x * BFLO(kw.x) + q0.y * BFHI(kw.x) + q0.z * BFLO(kw.y) + q0.w * BFHI(kw.y)
            + q1.x * BFLO(kw.z) + q1.y * BFHI(kw.z) + q1.z * BFLO(kw.w) + q1.w * BFHI(kw.w);
    d += __shfl_xor(d, 1);
    d += __shfl_xor(d, 2);
    d += __shfl_xor(d, 4);
    d += __shfl_xor(d, 8);
    d = d > 0.f ? d : 0.2f * d;   // scale already folded into Wqk
    if (d > m + 8.f) {
      float sc = __expf(m - d);   // first edge: exp(-inf)=0 zeroes l,a
      l *= sc;
      a0.x *= sc; a0.y *= sc; a0.z *= sc; a0.w *= sc;
      a1.x *= sc; a1.y *= sc; a1.z *= sc; a1.w *= sc;
      m = d;
    }
    float p = __expf(d - m);
    l += p;
    a0.x += p * BFLO(vw.x); a0.y += p * BFHI(vw.x);
    a0.z += p * BFLO(vw.y); a0.w += p * BFHI(vw.y);
    a1.x += p * BFLO(vw.z); a1.y += p * BFHI(vw.z);
    a1.z += p * BFLO(vw.w); a1.w += p * BFHI(vw.w);
    kw = kw2; vw = vw2; j = jn;
  }
#pragma unroll
  for (int mask = 16; mask <= 32; mask <<= 1) {
    float m2 = __shfl_xor(m, mask);
    float l2 = __shfl_xor(l, mask);
    float b0x = __shfl_xor(a0.x, mask), b0y = __shfl_xor(a0.y, mask);
    float b0z = __shfl_xor(a0.z, mask), b0w = __shfl_xor(a0.w, mask);
    float b1x = __shfl_xor(a1.x, mask), b1y = __shfl_xor(a1.y, mask);
    float b1z = __shfl_xor(a1.z, mask), b1w = __shfl_xor(a1.w, mask);
    float mn = fmaxf(fmaxf(m, m2), -1e30f);
    float ea = __expf(m - mn), eb = __expf(m2 - mn);
    l = l * ea + l2 * eb;
    a0.x = a0.x * ea + b0x * eb; a0.y = a0.y * ea + b0y * eb;
    a0.z = a0.z * ea + b0z * eb; a0.w = a0.w * ea + b0w * eb;
    a1.x = a1.x * ea + b1x * eb; a1.y = a1.y * ea + b1y * eb;
    a1.z = a1.z * ea + b1z * eb; a1.w = a1.w * ea + b1w * eb;
    m = fmaxf(m, m2);
  }
  if (g == 0) {
    float inv = 1.f / fmaxf(l, 1e-16f);
    uint4 w = make_uint4(packbf(a0.x * inv, a0.y * inv), packbf(a0.z * inv, a0.w * inv),
                         packbf(a1.x * inv, a1.y * inv), packbf(a1.z * inv, a1.w * inv));
    *(uint4*)(ho16 + (size_t)n * HF + fl * 8) = w;
  }
}

// z[m][0:128] = segment_min(ho16[node]) (0 if empty); z[m][128:256] = xe[m]
__global__ __launch_bounds__(256) void seg_min_z(const unsigned short* __restrict__ ho16,
                                                 const int* __restrict__ off_e,
                                                 const unsigned short* __restrict__ by_h,
                                                 const float* __restrict__ xe,
                                                 float* __restrict__ z, int M) {
  int m = (blockIdx.x * blockDim.x + threadIdx.x) >> 6;
  if (m >= M) return;
  int lane = threadIdx.x & 63;
  int g = lane >> 4;
  int fl = lane & 15;
  int s = off_e[m], e1 = off_e[m + 1];
  float4 a0 = make_float4(FLT_MAX, FLT_MAX, FLT_MAX, FLT_MAX), a1 = a0;
  for (int j = s + g; j < e1; j += 4) {
    int vi = by_h[j];
    uint4 hw = *(const uint4*)(ho16 + (size_t)vi * HF + fl * 8);
    a0.x = fminf(a0.x, BFLO(hw.x)); a0.y = fminf(a0.y, BFHI(hw.x));
    a0.z = fminf(a0.z, BFLO(hw.y)); a0.w = fminf(a0.w, BFHI(hw.y));
    a1.x = fminf(a1.x, BFLO(hw.z)); a1.y = fminf(a1.y, BFHI(hw.z));
    a1.z = fminf(a1.z, BFLO(hw.w)); a1.w = fminf(a1.w, BFHI(hw.w));
  }
#pragma unroll
  for (int mask = 16; mask <= 32; mask <<= 1) {
    a0.x = fminf(a0.x, __shfl_xor(a0.x, mask)); a0.y = fminf(a0.y, __shfl_xor(a0.y, mask));
    a0.z = fminf(a0.z, __shfl_xor(a0.z, mask)); a0.w = fminf(a0.w, __shfl_xor(a0.w, mask));
    a1.x = fminf(a1.x, __shfl_xor(a1.x, mask)); a1.y = fminf(a1.y, __shfl_xor(a1.y, mask));
    a1.z = fminf(a1.z, __shfl_xor(a1.z, mask)); a1.w = fminf(a1.w, __shfl_xor(a1.w, mask));
  }
  if (g == 0) {
    bool nz = (e1 > s);
    float* op = z + (size_t)m * 256 + fl * 8;
    *(float4*)op = nz ? a0 : make_float4(0.f, 0.f, 0.f, 0.f);
    *(float4*)(op + 4) = nz ? a1 : make_float4(0.f, 0.f, 0.f, 0.f);
  } else if (g == 1) {
    const float* xp = xe + (size_t)m * HF + fl * 8;
    float* op = z + (size_t)m * 256 + 128 + fl * 8;
    *(float4*)op = *(const float4*)xp;
    *(float4*)(op + 4) = *(const float4*)(xp + 4);
  }
}

// ---------------- GraphNorm stats + scale: 1024-thr blocks, LDS row-lane reduce, last-block ticket ----------------

__global__ __launch_bounds__(1024) void colstats_mk(const float* __restrict__ z, int rows, int C,
                                                    float* __restrict__ stats,
                                                    const float* __restrict__ w,
                                                    const float* __restrict__ b,
                                                    const float* __restrict__ a, float invrows,
                                                    float* __restrict__ sc, float* __restrict__ sh,
                                                    int* __restrict__ done) {
  int tid = threadIdx.x;
  int RL = 1024 / C;
  int col = tid & (C - 1);
  int ro = tid / C;
  float s1 = 0.f, s2 = 0.f;
  for (int r = blockIdx.x * RL + ro; r < rows; r += gridDim.x * RL) {
    float v = z[(size_t)r * C + col];
    s1 += v;
    s2 += v * v;
  }
  __shared__ float l1[1024], l2[1024];
  l1[tid] = s1;
  l2[tid] = s2;
  __syncthreads();
  for (int off = 512; off >= C; off >>= 1) {
    if (tid < off) { l1[tid] += l1[tid + off]; l2[tid] += l2[tid + off]; }
    __syncthreads();
  }
  if (tid < C) {
    atomicAdd(&stats[tid], l1[tid]);
    atomicAdd(&stats[C + tid], l2[tid]);
  }
  __threadfence();
  __shared__ int lastBlk;
  __syncthreads();
  if (tid == 0) lastBlk = (atomicAdd(done, 1) == (int)gridDim.x - 1);
  __syncthreads();
  if (lastBlk) {
    __threadfence();
    if (tid < C) {
      float mu = stats[tid] * invrows;
      float ex2 = stats[C + tid] * invrows;
      float av = a[tid];
      float var = ex2 - 2.f * av * mu * mu + av * av * mu * mu;
      float s = w[tid] * rsqrtf(var + 1e-5f);
      sc[tid] = s;
      sh[tid] = b[tid] - av * mu * s;
    }
  }
}

// ---------------- fused phase kernels (horizontal block-partition fusion) ----------------
// K1: count (atomic-latency-bound) striped 1:1 with sr1 gemm128 + her1 gemm64 + prep_att
// (VALU-bound). Co-resident blocks overlap distinct pipes.

__global__ __launch_bounds__(256) void k1_fused(
    const float* __restrict__ x, const float* __restrict__ sr_W1, const float* __restrict__ sr_b1,
    float* __restrict__ h, unsigned short* __restrict__ h16, int N,
    const float* __restrict__ x_e, const float* __restrict__ her_W1, const float* __restrict__ her_b1,
    float* __restrict__ t1, int M,
    const float* __restrict__ att_Wq, const float* __restrict__ att_Wv,
    float* __restrict__ wqt, float* __restrict__ wcat,
    const int* __restrict__ nidx, const int* __restrict__ hidx, int E2,
    int* cnt_v, int* cnt_e, unsigned short* rank_h, unsigned short* rank_v,
    int nb_sr1, int nb_her1, int n_pair, int n_count) {
  int bid = blockIdx.x;
  int o = -1, c = -1;
  if (bid < 2 * n_pair) {
    if (bid & 1) c = bid >> 1; else o = bid >> 1;
  } else {
    int t = bid - n_pair;
    if (n_count > n_pair) c = t; else o = t;
  }
  if (c >= 0) {
    count_body(nidx, hidx, E2, cnt_v, cnt_e, rank_h, rank_v, c);
    return;
  }
  if (o < nb_sr1) {
    gemm128_body(x, sr_W1, sr_b1, h, N, HF, HF, 1, nullptr, nullptr, 0, 0, h16, o >> 1, o & 1);
  } else if (o < nb_sr1 + nb_her1) {
    int g = o - nb_sr1;
    gemm64_body(x_e, her_W1, her_b1, t1, M, HF, HF, 1, nullptr, nullptr, 0, HF, g >> 1, g & 1);
  } else {
    prep_att_body(att_Wq, att_Wv, wqt, wcat, o - nb_sr1 - nb_her1);
  }
}

// K2: fill (scatter/latency) striped 1:r with her2 gemm64 + wcat gemm64.
__global__ __launch_bounds__(256) void k2_fused(
    const int* __restrict__ nidx, const int* __restrict__ hidx,
    const unsigned short* __restrict__ rank_h, const unsigned short* __restrict__ rank_v,
    int E, int M, int N, const int* __restrict__ off_e, const int* __restrict__ off_v,
    unsigned short* __restrict__ by_h, unsigned short* __restrict__ by_v,
    const float* __restrict__ t1, const float* __restrict__ her_W2, const float* __restrict__ her_b2,
    float* __restrict__ xe,
    const float* __restrict__ att_Wk, const float* __restrict__ wqt, float* __restrict__ wcat,
    int nb_her2, int n_other, int n_fill, int r) {
  int bid = blockIdx.x;
  int o = -1, f = -1;
  if (bid < r * n_other) {
    if (bid % r == 0) o = bid / r; else f = bid - bid / r - 1;
  } else {
    f = bid - n_other;
  }
  if (f >= 0) {
    fill_body(nidx, hidx, rank_h, rank_v, E, M, N, off_e, off_v, by_h, by_v, f);
    return;
  }
  if (o < nb_her2) {
    gemm64_body(t1, her_W2, her_b2, xe, M, HF, HF, 0, nullptr, nullptr, 0, HF, o >> 1, o & 1);
  } else {
    int g = o - nb_her2;
    gemm64_body(att_Wk, wqt, nullptr, wcat, 128, 128, 128, 0, nullptr, nullptr, 0, 256, g >> 1, g & 1);
  }
}

// K3: seg_mean_e (gather) striped 1:r with kv projection gemm128 (bf16 out).
__global__ __launch_bounds__(256) void k3_fused(
    const unsigned short* __restrict__ h16, const int* __restrict__ off_e,
    const unsigned short* __restrict__ by_h, unsigned short* __restrict__ m_e16, int M,
    const float* __restrict__ xe, const float* __restrict__ wcat, float* __restrict__ kvout,
    int n_other, int n_sme, int r) {
  int bid = blockIdx.x;
  int o = -1, s = -1;
  if (bid < r * n_other) {
    if (bid % r == 0) o = bid / r; else s = bid - bid / r - 1;
  } else {
    s = bid - n_other;
  }
  if (s >= 0) {
    seg_mean_e_body(h16, off_e, by_h, m_e16, M, s);
    return;
  }
  gemm128_body(xe, wcat, nullptr, kvout, M, HF, 256, 0, nullptr, nullptr, 0, /*obf16=*/1,
               nullptr, o >> 2, o & 3);
}

// ---------------- launch ----------------

extern "C" void kernel_launch(void* const* d_in, const int* in_sizes, int n_in,
                              void* d_out, int out_size, void* d_ws, size_t ws_size,
                              hipStream_t stream) {
  const float* x        = (const float*)d_in[0];
  const float* x_e      = (const float*)d_in[2];
  const int*   node_idx = (const int*)d_in[3];
  const int*   hedge_idx= (const int*)d_in[4];
  const float* her_W1   = (const float*)d_in[5];
  const float* her_b1   = (const float*)d_in[6];
  const float* her_W2   = (const float*)d_in[7];
  const float* her_b2   = (const float*)d_in[8];
  const float* sr_W1    = (const float*)d_in[9];
  const float* sr_b1    = (const float*)d_in[10];
  const float* sr_W2    = (const float*)d_in[11];
  const float* sr_b2    = (const float*)d_in[12];
  const float* att_Wq   = (const float*)d_in[13];
  const float* att_Wk   = (const float*)d_in[14];
  const float* att_Wv   = (const float*)d_in[15];
  const float* ef_W     = (const float*)d_in[16];
  const float* ef_b     = (const float*)d_in[17];
  const float* gn1_w    = (const float*)d_in[18];
  const float* gn1_b    = (const float*)d_in[19];
  const float* gn1_a    = (const float*)d_in[20];
  const float* gn2_w    = (const float*)d_in[21];
  const float* gn2_b    = (const float*)d_in[22];
  const float* gn2_a    = (const float*)d_in[23];
  const float* cls_W1   = (const float*)d_in[24];
  const float* cls_b1   = (const float*)d_in[25];
  const float* cls_W2   = (const float*)d_in[26];
  const float* cls_b2   = (const float*)d_in[27];

  const int N = in_sizes[0] / HF;
  const int M = in_sizes[2] / HF;
  const int E = in_sizes[3];

  // ---- workspace layout ----
  char* wp = (char*)d_ws;
  int* cnt_e = (int*)wp; wp += (size_t)M * CE_ST * 4;
  int* cnt_v = (int*)wp; wp += (size_t)N * CV_ST * 4;
  float* stats1 = (float*)wp; wp += 512 * 4;
  float* stats2 = (float*)wp; wp += 256 * 4;
  int* done1 = (int*)wp; wp += 64;
  int* done2 = (int*)wp; wp += 64;
  size_t zero_bytes = (size_t)(wp - (char*)d_ws);
  int* off_e = (int*)wp; wp += (size_t)(M + 1) * 4;
  int* off_v = (int*)wp; wp += (size_t)(N + 1) * 4;
  unsigned short* by_h = (unsigned short*)wp; wp += ((size_t)E * 2 + 3) & ~(size_t)3;
  unsigned short* by_v = (unsigned short*)wp; wp += ((size_t)E * 2 + 3) & ~(size_t)3;
  unsigned short* rank_h = (unsigned short*)wp; wp += ((size_t)E * 2 + 3) & ~(size_t)3;
  unsigned short* rank_v = (unsigned short*)wp; wp += ((size_t)E * 2 + 3) & ~(size_t)3;
  int* part_e = (int*)wp; wp += 257 * 4;
  int* part_v = (int*)wp; wp += 257 * 4;
  float* sc1 = (float*)wp; wp += 256 * 4;
  float* sh1 = (float*)wp; wp += 256 * 4;
  float* sc2 = (float*)wp; wp += 128 * 4;
  float* sh2 = (float*)wp; wp += 128 * 4;
  wp = (char*)(((uintptr_t)wp + 255) & ~(uintptr_t)255);
  float* wqt  = (float*)wp; wp += (size_t)128 * 128 * 4;   // Wq^T * scale
  float* wcat = (float*)wp; wp += (size_t)128 * 256 * 4;   // [Wqk | Wv]
  float* h   = (float*)wp; wp += (size_t)N * HF * 4;       // sr1 out, += m_v, sr2 in; later c1
  float* h2  = (float*)wp; wp += (size_t)N * HF * 4;       // sr2 out = q; later z [M,256]
  float* xe  = (float*)wp; wp += (size_t)M * HF * 4;
  float* kvf = (float*)wp; wp += (size_t)M * 256 * 4;      // t1 fp32 alias / kv bf16
  float* z2  = (float*)wp; wp += (size_t)M * HF * 4;
  unsigned short* h16   = (unsigned short*)wp; wp += (size_t)N * HF * 2;  // sr1 bf16 shadow
  unsigned short* ho16  = (unsigned short*)wp; wp += (size_t)N * HF * 2;  // att out bf16
  unsigned short* m_e16 = (unsigned short*)wp; wp += (size_t)M * HF * 2;

  unsigned short* kv = (unsigned short*)kvf;   // [M][256] bf16
  float* t1  = kvf;                // her hidden [M,128] fp32 (dead before kv written)
  float* z   = h2;                 // [M,256] (h2 dead as q after att_fused)
  float* c1  = h;                  // [M,128] (h dead after sr2)

  hipMemsetAsync(d_ws, 0, zero_bytes, stream);

  dim3 blk(256);

  // ---- K1: count + sr1 + her1 + prep_att (striped) ----
  int E2 = 2 * E;
  int n_count = idiv(E2, 1024);              // 4 tasks/thread
  int nb_sr1  = idiv(N, 128) * 2;
  int nb_her1 = idiv(M, 64) * 2;
  int n_other1 = nb_sr1 + nb_her1 + 64;      // 64 blocks of prep_att
  int n_pair = n_other1 < n_count ? n_other1 : n_count;
  k1_fused<<<n_other1 + n_count, blk, 0, stream>>>(
      x, sr_W1, sr_b1, h, h16, N,
      x_e, her_W1, her_b1, t1, M,
      att_Wq, att_Wv, wqt, wcat,
      node_idx, hedge_idx, E2, cnt_v, cnt_e, rank_h, rank_v,
      nb_sr1, nb_her1, n_pair, n_count);

  int nbE = idiv(M, SCAN_CHUNK);
  int nbV = idiv(N, SCAN_CHUNK);
  scanA2<<<nbE + nbV, 256, 0, stream>>>(cnt_e, M, nbE, part_e, cnt_v, N, part_v);
  scanB2<<<2, 256, 0, stream>>>(part_e, nbE, part_v, nbV);
  scanC2<<<nbE + nbV, 256, 0, stream>>>(cnt_e, M, nbE, part_e, off_e, cnt_v, N, nbV, part_v, off_v);

  // ---- K2: fill + her2 + wcat-gemm (striped 1:r) ----
  int n_fill = idiv(E, FILL_CHUNK) * 8;
  int nb_her2 = idiv(M, 64) * 2;
  int n_other2 = nb_her2 + 4;                // + wcat gemm (2x2 blocks)
  int r2 = n_fill / n_other2 + 1;
  if (r2 > 8) r2 = 8;
  if (r2 < 1) r2 = 1;
  k2_fused<<<n_other2 + n_fill, blk, 0, stream>>>(
      node_idx, hedge_idx, rank_h, rank_v, E, M, N, off_e, off_v, by_h, by_v,
      t1, her_W2, her_b2, xe,
      att_Wk, wqt, wcat,
      nb_her2, n_other2, n_fill, r2);

  // ---- K3: seg_mean_e + kv projection (striped 1:r) ----
  int n_sme = idiv(M * 64, 256);
  int n_kv  = idiv(M, 128) * 4;
  int r3 = n_sme / n_kv + 1;
  if (r3 > 8) r3 = 8;
  if (r3 < 1) r3 = 1;
  k3_fused<<<n_kv + n_sme, blk, 0, stream>>>(
      h16, off_e, by_h, m_e16, M,
      xe, wcat, (float*)kv,
      n_kv, n_sme, r3);

  // ---- remaining (serial-dependency) chain unchanged ----
  seg_mean_v_add<<<idiv(N * 64, 256), blk, 0, stream>>>(h, m_e16, off_v, by_v, N);
  gemm128<<<dim3(idiv(N, 128), 2), blk, 0, stream>>>(h, sr_W2, sr_b2, h2, N, HF, HF, 1,
                                                     nullptr, nullptr, 0, 0, nullptr);
  att_fused<<<idiv(N * 64, 256), blk, 0, stream>>>(h2, kv, off_v, by_v, ho16, N);
  seg_min_z<<<idiv(M * 64, 256), blk, 0, stream>>>(ho16, off_e, by_h, xe, z, M);
  colstats_mk<<<128, 1024, 0, stream>>>(z, M, 256, stats1, gn1_w, gn1_b, gn1_a,
                                        1.f / (float)M, sc1, sh1, done1);
  gemm64<<<dim3(idiv(M, 64), 2), blk, 0, stream>>>(z, ef_W, ef_b, z2, M, 2 * HF, HF, 1,
                                                   sc1, sh1, 0, HF);
  colstats_mk<<<128, 1024, 0, stream>>>(z2, M, 128, stats2, gn2_w, gn2_b, gn2_a,
                                        1.f / (float)M, sc2, sh2, done2);
  gemm64<<<dim3(idiv(M, 64), 2), blk, 0, stream>>>(z2, cls_W1, cls_b1, c1, M, HF, HF, 1, sc2, sh2, 1, HF);
  gemm64<<<dim3(idiv(M, 64), 1), blk, 0, stream>>>(c1, cls_W2, cls_b2, (float*)d_out, M, HF, 64, 0, nullptr, nullptr, 0, 64);
}

// Round 2
// 475.631 us; speedup vs baseline: 1.4046x; 1.4046x over previous
//
#include <hip/hip_runtime.h>
#include <float.h>
#include <math.h>

#define HF 128
#define SCAN_CHUNK 4096  // 256 threads x 16 elems
#define FILL_CHUNK 2048  // edges per fill block-group (8 iters x 256)
#define CE_ST 16         // cnt_e stride (ints): 1 counter per 64B line
#define CV_ST 8          // cnt_v stride (ints): 1 counter per 32B sector

static inline int idiv(int a, int b) { return (a + b - 1) / b; }

__device__ inline unsigned short f2bf(float x) {  // RNE float->bf16
  unsigned u = __float_as_uint(x);
  return (unsigned short)((u + 0x7fffu + ((u >> 16) & 1u)) >> 16);
}
__device__ inline unsigned packbf(float a, float b) {
  return (unsigned)f2bf(a) | ((unsigned)f2bf(b) << 16);
}
#define BFLO(w) __uint_as_float((w) << 16)
#define BFHI(w) __uint_as_float((w) & 0xffff0000u)

// ---------------- CSR construction ----------------
// count: 4 edges/thread, batched independent atomics (4x in-flight atomics per
// wave at unchanged occupancy -- standalone kernel keeps VGPR tiny / LDS 0).
// Interleaved parity: even threads hit cnt_e, odd hit cnt_v (both counter
// regions active simultaneously).

__global__ void count_kernel(const int* __restrict__ nidx, const int* __restrict__ hidx,
                             int E2, int* cnt_v, int* cnt_e,
                             unsigned short* __restrict__ rank_h,
                             unsigned short* __restrict__ rank_v) {
  int tid = threadIdx.x;
  int base = blockIdx.x * 1024 + tid;
  bool odd = tid & 1;  // stride 256 keeps parity constant per thread
  int e[4], seg[4], rr[4];
  bool val[4];
#pragma unroll
  for (int i = 0; i < 4; ++i) {
    int t = base + i * 256;
    val[i] = t < E2;
    e[i] = t >> 1;
  }
#pragma unroll
  for (int i = 0; i < 4; ++i)
    if (val[i]) seg[i] = odd ? nidx[e[i]] : hidx[e[i]];
#pragma unroll
  for (int i = 0; i < 4; ++i)
    if (val[i]) rr[i] = odd ? atomicAdd(&cnt_v[seg[i] * CV_ST], 1)
                            : atomicAdd(&cnt_e[seg[i] * CE_ST], 1);
#pragma unroll
  for (int i = 0; i < 4; ++i)
    if (val[i]) {
      if (odd) rank_v[e[i]] = (unsigned short)rr[i];
      else     rank_h[e[i]] = (unsigned short)rr[i];
    }
}

// ---- fused 3-phase multi-block exclusive scan over both (strided) count arrays ----

__global__ __launch_bounds__(256) void scanA2(const int* __restrict__ inE, int nE, int nbE,
                                              int* __restrict__ partE,
                                              const int* __restrict__ inV, int nV,
                                              int* __restrict__ partV) {
  const int* in; int n, st, b; int* partials;
  if ((int)blockIdx.x < nbE) { in = inE; n = nE; st = CE_ST; b = blockIdx.x; partials = partE; }
  else { in = inV; n = nV; st = CV_ST; b = blockIdx.x - nbE; partials = partV; }
  __shared__ int lds[256];
  int tid = threadIdx.x;
  int base = b * SCAN_CHUNK + tid * 16;
  int s = 0;
#pragma unroll
  for (int i = 0; i < 16; ++i) {
    int idx = base + i;
    if (idx < n) s += in[(size_t)idx * st];
  }
  lds[tid] = s;
  __syncthreads();
  for (int off = 128; off; off >>= 1) {
    if (tid < off) lds[tid] += lds[tid + off];
    __syncthreads();
  }
  if (tid == 0) partials[b] = lds[0];
}

__global__ __launch_bounds__(256) void scanB2(int* __restrict__ partE, int nbE,
                                              int* __restrict__ partV, int nbV) {
  int* partials = (blockIdx.x == 0) ? partE : partV;
  int nb = (blockIdx.x == 0) ? nbE : nbV;
  __shared__ int lds[256];
  int tid = threadIdx.x;
  int v = (tid < nb) ? partials[tid] : 0;
  lds[tid] = v;
  __syncthreads();
  for (int off = 1; off < 256; off <<= 1) {
    int add = (tid >= off) ? lds[tid - off] : 0;
    __syncthreads();
    lds[tid] += add;
    __syncthreads();
  }
  if (tid < nb) partials[tid] = lds[tid] - v;  // exclusive
  if (tid == nb - 1) partials[nb] = lds[tid];  // total
}

__global__ __launch_bounds__(256) void scanC2(const int* __restrict__ inE, int nE, int nbE,
                                              const int* __restrict__ partE, int* __restrict__ outE,
                                              const int* __restrict__ inV, int nV, int nbV,
                                              const int* __restrict__ partV, int* __restrict__ outV) {
  const int* in; const int* partials; int* out; int n, st, b, nb;
  if ((int)blockIdx.x < nbE) { in = inE; n = nE; st = CE_ST; b = blockIdx.x; partials = partE; out = outE; nb = nbE; }
  else { in = inV; n = nV; st = CV_ST; b = blockIdx.x - nbE; partials = partV; out = outV; nb = nbV; }
  __shared__ int lds[256];
  int tid = threadIdx.x;
  int base = b * SCAN_CHUNK + tid * 16;
  int vals[16];
  int s = 0;
#pragma unroll
  for (int i = 0; i < 16; ++i) {
    int idx = base + i;
    int v = (idx < n) ? in[(size_t)idx * st] : 0;
    vals[i] = s;
    s += v;
  }
  lds[tid] = s;
  __syncthreads();
  int own = s;
  for (int off = 1; off < 256; off <<= 1) {
    int add = (tid >= off) ? lds[tid - off] : 0;
    __syncthreads();
    lds[tid] += add;
    __syncthreads();
  }
  int excl = lds[tid] - own + partials[b];
#pragma unroll
  for (int i = 0; i < 16; ++i) {
    int idx = base + i;
    if (idx < n) out[idx] = excl + vals[i];
  }
  if (b == 0 && tid == 0) out[n] = partials[nb];
}

// Atomic-free XCD-localized scatter: pos = off[seg] + rank[e]; store only.
__global__ __launch_bounds__(256) void fill_kernel(const int* __restrict__ nidx,
                                                   const int* __restrict__ hidx,
                                                   const unsigned short* __restrict__ rank_h,
                                                   const unsigned short* __restrict__ rank_v,
                                                   int E, int M, int N,
                                                   const int* __restrict__ off_e,
                                                   const int* __restrict__ off_v,
                                                   unsigned short* __restrict__ by_h,
                                                   unsigned short* __restrict__ by_v) {
  int cls = blockIdx.x & 7;
  int base = (blockIdx.x >> 3) * FILL_CHUNK + threadIdx.x;
#pragma unroll 1
  for (int i = 0; i < FILL_CHUNK / 256; ++i) {
    int e = base + i * 256;
    if (e < E) {
      int hh = hidx[e];
      int vv = nidx[e];
      if ((hh * 8) / M == cls) by_h[off_e[hh] + rank_h[e]] = (unsigned short)vv;
      if ((int)(((long long)vv * 8) / N) == cls) by_v[off_v[vv] + rank_v[e]] = (unsigned short)hh;
    }
  }
}

// wqt = Wq^T * (1/sqrt(128)) [score scale folded]; wcat[:,128:256] = Wv.
__global__ void prep_att(const float* __restrict__ Wq, const float* __restrict__ Wv,
                         float* __restrict__ wqt, float* __restrict__ wcat) {
  int i = blockIdx.x * blockDim.x + threadIdx.x;  // 128*128
  if (i >= 128 * 128) return;
  int r = i >> 7, c = i & 127;
  wqt[c * 128 + r] = Wq[i] * 0.08838834764831845f;
  wcat[r * 256 + 128 + c] = Wv[i];
}

// ---------------- GEMM A: 128x64 tile, 8x4 micro, fused input-norm / bf16-out / fp32+bf16 shadow ----------------

__global__ __launch_bounds__(256) void gemm128(const float* __restrict__ A,
                                               const float* __restrict__ W,
                                               const float* __restrict__ bias,
                                               float* __restrict__ out,
                                               int R, int K, int C, int act,
                                               const float* __restrict__ insc,
                                               const float* __restrict__ insh, int inact,
                                               int obf16,
                                               unsigned short* __restrict__ out16) {
  __shared__ __align__(16) float As[128][20];
  __shared__ __align__(16) float Bs[16][64];
  int tid = threadIdx.x;
  int tx = tid & 15;
  int ty = tid >> 4;
  int rowBase = blockIdx.x * 128;
  int colBase = blockIdx.y * 64;

  float acc[8][4] = {};

  for (int k0 = 0; k0 < K; k0 += 16) {
#pragma unroll
    for (int p = 0; p < 2; ++p) {
      int li = tid + 256 * p;
      int arow = li >> 2, ac = (li & 3) * 4;
      int gr = rowBase + arow;
      float4 av = make_float4(0.f, 0.f, 0.f, 0.f);
      if (gr < R) av = *(const float4*)(A + (size_t)gr * K + k0 + ac);
      if (insc) {
        float vv[4] = {av.x, av.y, av.z, av.w};
#pragma unroll
        for (int i = 0; i < 4; ++i) {
          float s = insc[k0 + ac + i], sh = insh[k0 + ac + i];
          float v = vv[i] * s + sh;
          if (inact) v = v > 0.f ? v : 0.01f * v;
          vv[i] = v;
        }
        av = make_float4(vv[0], vv[1], vv[2], vv[3]);
      }
      *(float4*)&As[arow][ac] = av;
    }
    {
      int bk = tid >> 4, bc = (tid & 15) * 4;
      *(float4*)&Bs[bk][bc] = *(const float4*)(W + (size_t)(k0 + bk) * C + colBase + bc);
    }
    __syncthreads();
#pragma unroll
    for (int kg = 0; kg < 16; kg += 4) {
      float af[8][4], bf[4][4];
#pragma unroll
      for (int i = 0; i < 4; ++i) {
        *(float4*)af[i]     = *(const float4*)&As[ty * 4 + i][kg];
        *(float4*)af[i + 4] = *(const float4*)&As[64 + ty * 4 + i][kg];
      }
#pragma unroll
      for (int kk = 0; kk < 4; ++kk)
        *(float4*)bf[kk] = *(const float4*)&Bs[kg + kk][tx * 4];
#pragma unroll
      for (int kk = 0; kk < 4; ++kk)
#pragma unroll
        for (int i = 0; i < 8; ++i)
#pragma unroll
          for (int j = 0; j < 4; ++j)
            acc[i][j] = fmaf(af[i][kk], bf[kk][j], acc[i][j]);
    }
    __syncthreads();
  }

#pragma unroll
  for (int i = 0; i < 8; ++i) {
    int r = rowBase + ty * 4 + (i & 3) + (i >> 2) * 64;
    if (r >= R) continue;
    float vals[4];
#pragma unroll
    for (int j = 0; j < 4; ++j) {
      float v = acc[i][j];
      if (bias) v += bias[colBase + tx * 4 + j];
      if (act) v = v > 0.f ? v : 0.01f * v;
      vals[j] = v;
    }
    if (obf16) {
      unsigned short* o16 = (unsigned short*)out;
      ushort4 w = make_ushort4(f2bf(vals[0]), f2bf(vals[1]), f2bf(vals[2]), f2bf(vals[3]));
      *(ushort4*)(o16 + (size_t)r * C + colBase + tx * 4) = w;
    } else {
      *(float4*)(out + (size_t)r * C + colBase + tx * 4) =
          make_float4(vals[0], vals[1], vals[2], vals[3]);
      if (out16) {
        uint2 w = make_uint2(packbf(vals[0], vals[1]), packbf(vals[2], vals[3]));
        *(uint2*)(out16 + (size_t)r * C + colBase + tx * 4) = w;
      }
    }
  }
}

// ---------------- GEMM A2: 64x64 tile, 4x4 micro; ldo = output row stride ----------------

__global__ __launch_bounds__(256) void gemm64(const float* __restrict__ A,
                                              const float* __restrict__ W,
                                              const float* __restrict__ bias,
                                              float* __restrict__ out,
                                              int R, int K, int C, int act,
                                              const float* __restrict__ insc,
                                              const float* __restrict__ insh, int inact,
                                              int ldo) {
  __shared__ __align__(16) float As[64][20];
  __shared__ __align__(16) float Bs[16][64];
  int tid = threadIdx.x;
  int tx = tid & 15;
  int ty = tid >> 4;
  int rowBase = blockIdx.x * 64;
  int colBase = blockIdx.y * 64;

  float acc[4][4] = {};

  for (int k0 = 0; k0 < K; k0 += 16) {
    {
      int arow = tid >> 2, ac = (tid & 3) * 4;
      int gr = rowBase + arow;
      float4 av = make_float4(0.f, 0.f, 0.f, 0.f);
      if (gr < R) av = *(const float4*)(A + (size_t)gr * K + k0 + ac);
      if (insc) {
        float vv[4] = {av.x, av.y, av.z, av.w};
#pragma unroll
        for (int i = 0; i < 4; ++i) {
          float s = insc[k0 + ac + i], sh = insh[k0 + ac + i];
          float v = vv[i] * s + sh;
          if (inact) v = v > 0.f ? v : 0.01f * v;
          vv[i] = v;
        }
        av = make_float4(vv[0], vv[1], vv[2], vv[3]);
      }
      *(float4*)&As[arow][ac] = av;
    }
    {
      int bk = tid >> 4, bc = (tid & 15) * 4;
      *(float4*)&Bs[bk][bc] = *(const float4*)(W + (size_t)(k0 + bk) * C + colBase + bc);
    }
    __syncthreads();
#pragma unroll
    for (int kg = 0; kg < 16; kg += 4) {
      float af[4][4], bf[4][4];
#pragma unroll
      for (int i = 0; i < 4; ++i)
        *(float4*)af[i] = *(const float4*)&As[ty * 4 + i][kg];
#pragma unroll
      for (int kk = 0; kk < 4; ++kk)
        *(float4*)bf[kk] = *(const float4*)&Bs[kg + kk][tx * 4];
#pragma unroll
      for (int kk = 0; kk < 4; ++kk)
#pragma unroll
        for (int i = 0; i < 4; ++i)
#pragma unroll
          for (int j = 0; j < 4; ++j)
            acc[i][j] = fmaf(af[i][kk], bf[kk][j], acc[i][j]);
    }
    __syncthreads();
  }

#pragma unroll
  for (int i = 0; i < 4; ++i) {
    int r = rowBase + ty * 4 + i;
    if (r >= R) continue;
    float vals[4];
#pragma unroll
    for (int j = 0; j < 4; ++j) {
      float v = acc[i][j];
      if (bias) v += bias[colBase + tx * 4 + j];
      if (act) v = v > 0.f ? v : 0.01f * v;
      vals[j] = v;
    }
    *(float4*)(out + (size_t)r * ldo + colBase + tx * 4) = make_float4(vals[0], vals[1], vals[2], vals[3]);
  }
}

// ---------------- segment ops: one wave per segment; 4 x 16-lane groups, 8 feats/lane ----------------

__global__ __launch_bounds__(256) void seg_mean_e(const unsigned short* __restrict__ h16,
                                                  const int* __restrict__ off_e,
                                                  const unsigned short* __restrict__ by_h,
                                                  unsigned short* __restrict__ m_e16, int M) {
  int m = (blockIdx.x * blockDim.x + threadIdx.x) >> 6;
  if (m >= M) return;
  int lane = threadIdx.x & 63;
  int g = lane >> 4;
  int fl = lane & 15;
  int s = off_e[m], e1 = off_e[m + 1];
  float4 a0 = make_float4(0.f, 0.f, 0.f, 0.f), a1 = a0;
  for (int j = s + g; j < e1; j += 4) {
    int vi = by_h[j];
    uint4 hw = *(const uint4*)(h16 + (size_t)vi * HF + fl * 8);
    a0.x += BFLO(hw.x); a0.y += BFHI(hw.x); a0.z += BFLO(hw.y); a0.w += BFHI(hw.y);
    a1.x += BFLO(hw.z); a1.y += BFHI(hw.z); a1.z += BFLO(hw.w); a1.w += BFHI(hw.w);
  }
#pragma unroll
  for (int mask = 16; mask <= 32; mask <<= 1) {
    a0.x += __shfl_xor(a0.x, mask); a0.y += __shfl_xor(a0.y, mask);
    a0.z += __shfl_xor(a0.z, mask); a0.w += __shfl_xor(a0.w, mask);
    a1.x += __shfl_xor(a1.x, mask); a1.y += __shfl_xor(a1.y, mask);
    a1.z += __shfl_xor(a1.z, mask); a1.w += __shfl_xor(a1.w, mask);
  }
  if (g == 0) {
    int cnt = e1 - s;
    float r = 1.f / (float)(cnt > 0 ? cnt : 1);
    uint4 w = make_uint4(packbf(a0.x * r, a0.y * r), packbf(a0.z * r, a0.w * r),
                         packbf(a1.x * r, a1.y * r), packbf(a1.z * r, a1.w * r));
    *(uint4*)(m_e16 + (size_t)m * HF + fl * 8) = w;
  }
}

__global__ __launch_bounds__(256) void seg_mean_v_add(float* __restrict__ h,
                                                      const unsigned short* __restrict__ m_e16,
                                                      const int* __restrict__ off_v,
                                                      const unsigned short* __restrict__ by_v,
                                                      int N) {
  int n = (blockIdx.x * blockDim.x + threadIdx.x) >> 6;
  if (n >= N) return;
  int lane = threadIdx.x & 63;
  int g = lane >> 4;
  int fl = lane & 15;
  int s = off_v[n], e1 = off_v[n + 1];
  float4 a0 = make_float4(0.f, 0.f, 0.f, 0.f), a1 = a0;
  for (int j = s + g; j < e1; j += 4) {
    int he = by_v[j];
    uint4 hw = *(const uint4*)(m_e16 + (size_t)he * HF + fl * 8);
    a0.x += BFLO(hw.x); a0.y += BFHI(hw.x); a0.z += BFLO(hw.y); a0.w += BFHI(hw.y);
    a1.x += BFLO(hw.z); a1.y += BFHI(hw.z); a1.z += BFLO(hw.w); a1.w += BFHI(hw.w);
  }
#pragma unroll
  for (int mask = 16; mask <= 32; mask <<= 1) {
    a0.x += __shfl_xor(a0.x, mask); a0.y += __shfl_xor(a0.y, mask);
    a0.z += __shfl_xor(a0.z, mask); a0.w += __shfl_xor(a0.w, mask);
    a1.x += __shfl_xor(a1.x, mask); a1.y += __shfl_xor(a1.y, mask);
    a1.z += __shfl_xor(a1.z, mask); a1.w += __shfl_xor(a1.w, mask);
  }
  if (g == 0) {
    int cnt = e1 - s;
    float r = 1.f / (float)(cnt > 0 ? cnt : 1);
    float* hp = h + (size_t)n * HF + fl * 8;
    float4 h0 = *(const float4*)hp;
    float4 h1 = *(const float4*)(hp + 4);
    *(float4*)hp = make_float4(h0.x + a0.x * r, h0.y + a0.y * r, h0.z + a0.z * r, h0.w + a0.w * r);
    *(float4*)(hp + 4) = make_float4(h1.x + a1.x * r, h1.y + a1.y * r, h1.z + a1.z * r, h1.w + a1.w * r);
  }
}

// Fused GAT attention: one wave per node; q = h2 (fp32, score scale pre-folded into Wqk);
// kv bf16 [M][256]; software prefetch + defer-max rescale (THR=8).
__global__ __launch_bounds__(256) void att_fused(const float* __restrict__ q,
                                                 const unsigned short* __restrict__ kv,
                                                 const int* __restrict__ off_v,
                                                 const unsigned short* __restrict__ by_v,
                                                 unsigned short* __restrict__ ho16, int N) {
  int n = (blockIdx.x * blockDim.x + threadIdx.x) >> 6;
  if (n >= N) return;
  int lane = threadIdx.x & 63;
  int g = lane >> 4;
  int fl = lane & 15;
  int s0 = off_v[n], s1 = off_v[n + 1];
  const float* qp = q + (size_t)n * HF + fl * 8;
  float4 q0 = *(const float4*)qp;
  float4 q1 = *(const float4*)(qp + 4);
  float m = -INFINITY, l = 0.f;
  float4 a0 = make_float4(0.f, 0.f, 0.f, 0.f), a1 = a0;
  int j = s0 + g;
  uint4 kw = make_uint4(0, 0, 0, 0), vw = kw;
  if (j < s1) {
    const unsigned short* base = kv + (size_t)by_v[j] * 256 + fl * 8;
    kw = *(const uint4*)base;
    vw = *(const uint4*)(base + 128);
  }
  while (j < s1) {
    int jn = j + 4;
    uint4 kw2 = make_uint4(0, 0, 0, 0), vw2 = kw2;
    if (jn < s1) {
      const unsigned short* b2 = kv + (size_t)by_v[jn] * 256 + fl * 8;
      kw2 = *(const uint4*)b2;
      vw2 = *(const uint4*)(b2 + 128);
    }
    float d = q0.x * BFLO(kw.x) + q0.y * BFHI(kw.x) + q0.z * BFLO(kw.y) + q0.w * BFHI(kw.y)
            + q1.x * BFLO(kw.z) + q1.y * BFHI(kw.z) + q1.z * BFLO(kw.w) + q1.w * BFHI(kw.w);
    d += __shfl_xor(d, 1);
    d += __shfl_xor(d, 2);
    d += __shfl_xor(d, 4);
    d += __shfl_xor(d, 8);
    d = d > 0.f ? d : 0.2f * d;   // scale already folded into Wqk
    if (d > m + 8.f) {
      float sc = __expf(m - d);   // first edge: exp(-inf)=0 zeroes l,a
      l *= sc;
      a0.x *= sc; a0.y *= sc; a0.z *= sc; a0.w *= sc;
      a1.x *= sc; a1.y *= sc; a1.z *= sc; a1.w *= sc;
      m = d;
    }
    float p = __expf(d - m);
    l += p;
    a0.x += p * BFLO(vw.x); a0.y += p * BFHI(vw.x);
    a0.z += p * BFLO(vw.y); a0.w += p * BFHI(vw.y);
    a1.x += p * BFLO(vw.z); a1.y += p * BFHI(vw.z);
    a1.z += p * BFLO(vw.w); a1.w += p * BFHI(vw.w);
    kw = kw2; vw = vw2; j = jn;
  }
#pragma unroll
  for (int mask = 16; mask <= 32; mask <<= 1) {
    float m2 = __shfl_xor(m, mask);
    float l2 = __shfl_xor(l, mask);
    float b0x = __shfl_xor(a0.x, mask), b0y = __shfl_xor(a0.y, mask);
    float b0z = __shfl_xor(a0.z, mask), b0w = __shfl_xor(a0.w, mask);
    float b1x = __shfl_xor(a1.x, mask), b1y = __shfl_xor(a1.y, mask);
    float b1z = __shfl_xor(a1.z, mask), b1w = __shfl_xor(a1.w, mask);
    float mn = fmaxf(fmaxf(m, m2), -1e30f);
    float ea = __expf(m - mn), eb = __expf(m2 - mn);
    l = l * ea + l2 * eb;
    a0.x = a0.x * ea + b0x * eb; a0.y = a0.y * ea + b0y * eb;
    a0.z = a0.z * ea + b0z * eb; a0.w = a0.w * ea + b0w * eb;
    a1.x = a1.x * ea + b1x * eb; a1.y = a1.y * ea + b1y * eb;
    a1.z = a1.z * ea + b1z * eb; a1.w = a1.w * ea + b1w * eb;
    m = fmaxf(m, m2);
  }
  if (g == 0) {
    float inv = 1.f / fmaxf(l, 1e-16f);
    uint4 w = make_uint4(packbf(a0.x * inv, a0.y * inv), packbf(a0.z * inv, a0.w * inv),
                         packbf(a1.x * inv, a1.y * inv), packbf(a1.z * inv, a1.w * inv));
    *(uint4*)(ho16 + (size_t)n * HF + fl * 8) = w;
  }
}

// z[m][0:128] = segment_min(ho16[node]) (0 if empty); z[m][128:256] = xe[m]
__global__ __launch_bounds__(256) void seg_min_z(const unsigned short* __restrict__ ho16,
                                                 const int* __restrict__ off_e,
                                                 const unsigned short* __restrict__ by_h,
                                                 const float* __restrict__ xe,
                                                 float* __restrict__ z, int M) {
  int m = (blockIdx.x * blockDim.x + threadIdx.x) >> 6;
  if (m >= M) return;
  int lane = threadIdx.x & 63;
  int g = lane >> 4;
  int fl = lane & 15;
  int s = off_e[m], e1 = off_e[m + 1];
  float4 a0 = make_float4(FLT_MAX, FLT_MAX, FLT_MAX, FLT_MAX), a1 = a0;
  for (int j = s + g; j < e1; j += 4) {
    int vi = by_h[j];
    uint4 hw = *(const uint4*)(ho16 + (size_t)vi * HF + fl * 8);
    a0.x = fminf(a0.x, BFLO(hw.x)); a0.y = fminf(a0.y, BFHI(hw.x));
    a0.z = fminf(a0.z, BFLO(hw.y)); a0.w = fminf(a0.w, BFHI(hw.y));
    a1.x = fminf(a1.x, BFLO(hw.z)); a1.y = fminf(a1.y, BFHI(hw.z));
    a1.z = fminf(a1.z, BFLO(hw.w)); a1.w = fminf(a1.w, BFHI(hw.w));
  }
#pragma unroll
  for (int mask = 16; mask <= 32; mask <<= 1) {
    a0.x = fminf(a0.x, __shfl_xor(a0.x, mask)); a0.y = fminf(a0.y, __shfl_xor(a0.y, mask));
    a0.z = fminf(a0.z, __shfl_xor(a0.z, mask)); a0.w = fminf(a0.w, __shfl_xor(a0.w, mask));
    a1.x = fminf(a1.x, __shfl_xor(a1.x, mask)); a1.y = fminf(a1.y, __shfl_xor(a1.y, mask));
    a1.z = fminf(a1.z, __shfl_xor(a1.z, mask)); a1.w = fminf(a1.w, __shfl_xor(a1.w, mask));
  }
  if (g == 0) {
    bool nz = (e1 > s);
    float* op = z + (size_t)m * 256 + fl * 8;
    *(float4*)op = nz ? a0 : make_float4(0.f, 0.f, 0.f, 0.f);
    *(float4*)(op + 4) = nz ? a1 : make_float4(0.f, 0.f, 0.f, 0.f);
  } else if (g == 1) {
    const float* xp = xe + (size_t)m * HF + fl * 8;
    float* op = z + (size_t)m * 256 + 128 + fl * 8;
    *(float4*)op = *(const float4*)xp;
    *(float4*)(op + 4) = *(const float4*)(xp + 4);
  }
}

// ---------------- GraphNorm stats + scale: 1024-thr blocks, LDS row-lane reduce, last-block ticket ----------------

__global__ __launch_bounds__(1024) void colstats_mk(const float* __restrict__ z, int rows, int C,
                                                    float* __restrict__ stats,
                                                    const float* __restrict__ w,
                                                    const float* __restrict__ b,
                                                    const float* __restrict__ a, float invrows,
                                                    float* __restrict__ sc, float* __restrict__ sh,
                                                    int* __restrict__ done) {
  int tid = threadIdx.x;
  int RL = 1024 / C;
  int col = tid & (C - 1);
  int ro = tid / C;
  float s1 = 0.f, s2 = 0.f;
  for (int r = blockIdx.x * RL + ro; r < rows; r += gridDim.x * RL) {
    float v = z[(size_t)r * C + col];
    s1 += v;
    s2 += v * v;
  }
  __shared__ float l1[1024], l2[1024];
  l1[tid] = s1;
  l2[tid] = s2;
  __syncthreads();
  for (int off = 512; off >= C; off >>= 1) {
    if (tid < off) { l1[tid] += l1[tid + off]; l2[tid] += l2[tid + off]; }
    __syncthreads();
  }
  if (tid < C) {
    atomicAdd(&stats[tid], l1[tid]);
    atomicAdd(&stats[C + tid], l2[tid]);
  }
  __threadfence();
  __shared__ int lastBlk;
  __syncthreads();
  if (tid == 0) lastBlk = (atomicAdd(done, 1) == (int)gridDim.x - 1);
  __syncthreads();
  if (lastBlk) {
    __threadfence();
    if (tid < C) {
      float mu = stats[tid] * invrows;
      float ex2 = stats[C + tid] * invrows;
      float av = a[tid];
      float var = ex2 - 2.f * av * mu * mu + av * av * mu * mu;
      float s = w[tid] * rsqrtf(var + 1e-5f);
      sc[tid] = s;
      sh[tid] = b[tid] - av * mu * s;
    }
  }
}

// ---------------- launch ----------------

extern "C" void kernel_launch(void* const* d_in, const int* in_sizes, int n_in,
                              void* d_out, int out_size, void* d_ws, size_t ws_size,
                              hipStream_t stream) {
  const float* x        = (const float*)d_in[0];
  const float* x_e      = (const float*)d_in[2];
  const int*   node_idx = (const int*)d_in[3];
  const int*   hedge_idx= (const int*)d_in[4];
  const float* her_W1   = (const float*)d_in[5];
  const float* her_b1   = (const float*)d_in[6];
  const float* her_W2   = (const float*)d_in[7];
  const float* her_b2   = (const float*)d_in[8];
  const float* sr_W1    = (const float*)d_in[9];
  const float* sr_b1    = (const float*)d_in[10];
  const float* sr_W2    = (const float*)d_in[11];
  const float* sr_b2    = (const float*)d_in[12];
  const float* att_Wq   = (const float*)d_in[13];
  const float* att_Wk   = (const float*)d_in[14];
  const float* att_Wv   = (const float*)d_in[15];
  const float* ef_W     = (const float*)d_in[16];
  const float* ef_b     = (const float*)d_in[17];
  const float* gn1_w    = (const float*)d_in[18];
  const float* gn1_b    = (const float*)d_in[19];
  const float* gn1_a    = (const float*)d_in[20];
  const float* gn2_w    = (const float*)d_in[21];
  const float* gn2_b    = (const float*)d_in[22];
  const float* gn2_a    = (const float*)d_in[23];
  const float* cls_W1   = (const float*)d_in[24];
  const float* cls_b1   = (const float*)d_in[25];
  const float* cls_W2   = (const float*)d_in[26];
  const float* cls_b2   = (const float*)d_in[27];

  const int N = in_sizes[0] / HF;
  const int M = in_sizes[2] / HF;
  const int E = in_sizes[3];

  // ---- workspace layout ----
  char* wp = (char*)d_ws;
  int* cnt_e = (int*)wp; wp += (size_t)M * CE_ST * 4;
  int* cnt_v = (int*)wp; wp += (size_t)N * CV_ST * 4;
  float* stats1 = (float*)wp; wp += 512 * 4;
  float* stats2 = (float*)wp; wp += 256 * 4;
  int* done1 = (int*)wp; wp += 64;
  int* done2 = (int*)wp; wp += 64;
  size_t zero_bytes = (size_t)(wp - (char*)d_ws);
  int* off_e = (int*)wp; wp += (size_t)(M + 1) * 4;
  int* off_v = (int*)wp; wp += (size_t)(N + 1) * 4;
  unsigned short* by_h = (unsigned short*)wp; wp += ((size_t)E * 2 + 3) & ~(size_t)3;
  unsigned short* by_v = (unsigned short*)wp; wp += ((size_t)E * 2 + 3) & ~(size_t)3;
  unsigned short* rank_h = (unsigned short*)wp; wp += ((size_t)E * 2 + 3) & ~(size_t)3;
  unsigned short* rank_v = (unsigned short*)wp; wp += ((size_t)E * 2 + 3) & ~(size_t)3;
  int* part_e = (int*)wp; wp += 257 * 4;
  int* part_v = (int*)wp; wp += 257 * 4;
  float* sc1 = (float*)wp; wp += 256 * 4;
  float* sh1 = (float*)wp; wp += 256 * 4;
  float* sc2 = (float*)wp; wp += 128 * 4;
  float* sh2 = (float*)wp; wp += 128 * 4;
  wp = (char*)(((uintptr_t)wp + 255) & ~(uintptr_t)255);
  float* wqt  = (float*)wp; wp += (size_t)128 * 128 * 4;   // Wq^T * scale
  float* wcat = (float*)wp; wp += (size_t)128 * 256 * 4;   // [Wqk | Wv]
  float* h   = (float*)wp; wp += (size_t)N * HF * 4;       // sr1 out, += m_v, sr2 in; later c1
  float* h2  = (float*)wp; wp += (size_t)N * HF * 4;       // sr2 out = q; later z [M,256]
  float* xe  = (float*)wp; wp += (size_t)M * HF * 4;
  float* kvf = (float*)wp; wp += (size_t)M * 256 * 4;      // t1 fp32 alias / kv bf16
  float* z2  = (float*)wp; wp += (size_t)M * HF * 4;
  unsigned short* h16   = (unsigned short*)wp; wp += (size_t)N * HF * 2;  // sr1 bf16 shadow
  unsigned short* ho16  = (unsigned short*)wp; wp += (size_t)N * HF * 2;  // att out bf16
  unsigned short* m_e16 = (unsigned short*)wp; wp += (size_t)M * HF * 2;

  unsigned short* kv = (unsigned short*)kvf;   // [M][256] bf16
  float* t1  = kvf;                // her hidden [M,128] fp32 (dead before kv written)
  float* z   = h2;                 // [M,256] (h2 dead as q after att_fused)
  float* c1  = h;                  // [M,128] (h dead after sr2)

  hipMemsetAsync(d_ws, 0, zero_bytes, stream);

  // CSR build (count: 4 edges/thread batched atomics)
  count_kernel<<<idiv(2 * E, 1024), 256, 0, stream>>>(node_idx, hedge_idx, 2 * E, cnt_v, cnt_e,
                                                      rank_h, rank_v);
  int nbE = idiv(M, SCAN_CHUNK);
  int nbV = idiv(N, SCAN_CHUNK);
  scanA2<<<nbE + nbV, 256, 0, stream>>>(cnt_e, M, nbE, part_e, cnt_v, N, part_v);
  scanB2<<<2, 256, 0, stream>>>(part_e, nbE, part_v, nbV);
  scanC2<<<nbE + nbV, 256, 0, stream>>>(cnt_e, M, nbE, part_e, off_e, cnt_v, N, nbV, part_v, off_v);
  fill_kernel<<<idiv(E, FILL_CHUNK) * 8, 256, 0, stream>>>(node_idx, hedge_idx, rank_h, rank_v,
                                                           E, M, N, off_e, off_v, by_h, by_v);
  // wqt = Wq^T*scale, wcat right = Wv; then wcat left = Wk @ wqt
  prep_att<<<64, 256, 0, stream>>>(att_Wq, att_Wv, wqt, wcat);
  gemm64<<<dim3(2, 2), 256, 0, stream>>>(att_Wk, wqt, nullptr, wcat, 128, 128, 128, 0,
                                         nullptr, nullptr, 0, 256);

  dim3 blk(256);
  // her MLP: xe
  gemm64<<<dim3(idiv(M, 64), 2), blk, 0, stream>>>(x_e, her_W1, her_b1, t1, M, HF, HF, 1, nullptr, nullptr, 0, HF);
  gemm64<<<dim3(idiv(M, 64), 2), blk, 0, stream>>>(t1, her_W2, her_b2, xe, M, HF, HF, 0, nullptr, nullptr, 0, HF);
  // sr layer1 (fp32 + bf16 shadow), 128x64 tiles -> 782 blocks
  gemm128<<<dim3(idiv(N, 128), 2), blk, 0, stream>>>(x, sr_W1, sr_b1, h, N, HF, HF, 1,
                                                     nullptr, nullptr, 0, 0, h16);
  // message passing means (bf16 gathers)
  seg_mean_e<<<idiv(M * 64, 256), blk, 0, stream>>>(h16, off_e, by_h, m_e16, M);
  seg_mean_v_add<<<idiv(N * 64, 256), blk, 0, stream>>>(h, m_e16, off_v, by_v, N);
  // sr layer2 -> h2 (doubles as q)
  gemm128<<<dim3(idiv(N, 128), 2), blk, 0, stream>>>(h, sr_W2, sr_b2, h2, N, HF, HF, 1,
                                                     nullptr, nullptr, 0, 0, nullptr);
  // kv projection: [xe@Wqk | xe@Wv] in bf16
  gemm128<<<dim3(idiv(M, 128), 4), blk, 0, stream>>>(xe, wcat, nullptr, (float*)kv, M, HF, 256, 0,
                                                     nullptr, nullptr, 0, /*obf16=*/1, nullptr);
  // fused attention (q = h2)
  att_fused<<<idiv(N * 64, 256), blk, 0, stream>>>(h2, kv, off_v, by_v, ho16, N);
  // min aggregation + concat (z overwrites h2)
  seg_min_z<<<idiv(M * 64, 256), blk, 0, stream>>>(ho16, off_e, by_h, xe, z, M);
  // gn1 stats+scale (fused, 1024-thr) -> ef linear(+act) -> gn2 stats+scale
  colstats_mk<<<128, 1024, 0, stream>>>(z, M, 256, stats1, gn1_w, gn1_b, gn1_a,
                                        1.f / (float)M, sc1, sh1, done1);
  gemm64<<<dim3(idiv(M, 64), 2), blk, 0, stream>>>(z, ef_W, ef_b, z2, M, 2 * HF, HF, 1,
                                                   sc1, sh1, 0, HF);
  colstats_mk<<<128, 1024, 0, stream>>>(z2, M, 128, stats2, gn2_w, gn2_b, gn2_a,
                                        1.f / (float)M, sc2, sh2, done2);
  // classifier
  gemm64<<<dim3(idiv(M, 64), 2), blk, 0, stream>>>(z2, cls_W1, cls_b1, c1, M, HF, HF, 1, sc2, sh2, 1, HF);
  gemm64<<<dim3(idiv(M, 64), 1), blk, 0, stream>>>(c1, cls_W2, cls_b2, (float*)d_out, M, HF, 64, 0, nullptr, nullptr, 0, 64);
}

// Round 3
// 449.961 us; speedup vs baseline: 1.4848x; 1.0570x over previous
//
#include <hip/hip_runtime.h>
#include <float.h>
#include <math.h>

#define HF 128
#define SCAN_CHUNK 4096  // 256 threads x 16 elems
#define NB_CSR 128       // chunks for counting-sort CSR build
#define VPACK 12500      // packed (2-per-int) node bins per range: 25000 nodes / range
#define VRANGE (2 * VPACK)

static inline int idiv(int a, int b) { return (a + b - 1) / b; }

__device__ inline unsigned short f2bf(float x) {  // RNE float->bf16
  unsigned u = __float_as_uint(x);
  return (unsigned short)((u + 0x7fffu + ((u >> 16) & 1u)) >> 16);
}
__device__ inline unsigned packbf(float a, float b) {
  return (unsigned)f2bf(a) | ((unsigned)f2bf(b) << 16);
}
#define BFLO(w) __uint_as_float((w) << 16)
#define BFHI(w) __uint_as_float((w) & 0xffff0000u)

// ---------------- CSR build: LDS-histogram counting sort (ZERO device-scope atomics) ----------------
// Round-2 evidence: 1.2M global atomics = 24.7 G/s RMW wall (48.5us, invariant to
// occupancy/batching). Replaced by per-chunk LDS histograms + column scan + scatter.
// y==0: hyperedge side (M bins, int). y>=1: node side range (y-1), 25000 nodes
// packed 2-per-int (counts < 2^16, no cross-field carry).

__global__ __launch_bounds__(512) void csr_hist(const int* __restrict__ nidx,
                                                const int* __restrict__ hidx,
                                                int E, int M,
                                                int* __restrict__ HE,
                                                int* __restrict__ HV) {
  __shared__ int bins[VPACK];
  int b = blockIdx.x, y = blockIdx.y, tid = threadIdx.x;
  int chunk = (E + NB_CSR - 1) / NB_CSR;
  int e0 = b * chunk;
  int e1 = e0 + chunk; if (e1 > E) e1 = E;
  if (y == 0) {
    for (int s = tid; s < M; s += 512) bins[s] = 0;
    __syncthreads();
    for (int e = e0 + tid; e < e1; e += 512) atomicAdd(&bins[hidx[e]], 1);
    __syncthreads();
    for (int s = tid; s < M; s += 512) HE[(size_t)b * M + s] = bins[s];
  } else {
    int R = (y - 1) * VRANGE;
    int* HVr = HV + ((size_t)(y - 1) * NB_CSR + b) * VPACK;
    for (int q = tid; q < VPACK; q += 512) bins[q] = 0;
    __syncthreads();
    for (int e = e0 + tid; e < e1; e += 512) {
      int v = nidx[e] - R;
      if ((unsigned)v < (unsigned)VRANGE) atomicAdd(&bins[v >> 1], (v & 1) ? 0x10000 : 1);
    }
    __syncthreads();
    for (int q = tid; q < VPACK; q += 512) HVr[q] = bins[q];
  }
}

// Per-segment exclusive scan over the NB_CSR chunks (in place) + dense counts.
__global__ __launch_bounds__(256) void csr_colscan(int* __restrict__ HE,
                                                   int* __restrict__ HV,
                                                   int M, int N, int NVR,
                                                   int* __restrict__ cnt_e,
                                                   int* __restrict__ cnt_v) {
  int col = blockIdx.x * 256 + threadIdx.x;
  if (col < M) {
    int run = 0;
    for (int b = 0; b < NB_CSR; ++b) {
      size_t i = (size_t)b * M + col;
      int t = HE[i]; HE[i] = run; run += t;
    }
    cnt_e[col] = run;
  } else if (col < M + NVR * VPACK) {
    int c = col - M;
    int r = c / VPACK, q = c - r * VPACK;
    int* HVr = HV + (size_t)r * NB_CSR * VPACK;
    int run = 0;
    for (int b = 0; b < NB_CSR; ++b) {
      size_t i = (size_t)b * VPACK + q;
      int t = HVr[i]; HVr[i] = run; run += t;
    }
    int node = r * VRANGE + 2 * q;
    if (node < N) cnt_v[node] = run & 0xffff;
    if (node + 1 < N) cnt_v[node + 1] = run >> 16;
  }
}

// Scatter: preload LDS bins with global base (off + chunk-exclusive), LDS-atomic rank.
__global__ __launch_bounds__(512) void csr_scatter(const int* __restrict__ nidx,
                                                   const int* __restrict__ hidx,
                                                   int E, int M,
                                                   const int* __restrict__ HE,
                                                   const int* __restrict__ HV,
                                                   const int* __restrict__ off_e,
                                                   const int* __restrict__ off_v,
                                                   unsigned short* __restrict__ by_h,
                                                   unsigned short* __restrict__ by_v) {
  __shared__ int bins[VPACK];
  int b = blockIdx.x, y = blockIdx.y, tid = threadIdx.x;
  int chunk = (E + NB_CSR - 1) / NB_CSR;
  int e0 = b * chunk;
  int e1 = e0 + chunk; if (e1 > E) e1 = E;
  if (y == 0) {
    for (int s = tid; s < M; s += 512) bins[s] = off_e[s] + HE[(size_t)b * M + s];
    __syncthreads();
    for (int e = e0 + tid; e < e1; e += 512) {
      int pos = atomicAdd(&bins[hidx[e]], 1);
      by_h[pos] = (unsigned short)nidx[e];
    }
  } else {
    int R = (y - 1) * VRANGE;
    const int* HVr = HV + ((size_t)(y - 1) * NB_CSR + b) * VPACK;
    for (int q = tid; q < VPACK; q += 512) bins[q] = HVr[q];
    __syncthreads();
    for (int e = e0 + tid; e < e1; e += 512) {
      int v = nidx[e];
      int vr = v - R;
      if ((unsigned)vr < (unsigned)VRANGE) {
        int old = atomicAdd(&bins[vr >> 1], (vr & 1) ? 0x10000 : 1);
        int rank = (vr & 1) ? (old >> 16) : (old & 0xffff);
        by_v[off_v[v] + rank] = (unsigned short)hidx[e];
      }
    }
  }
}

// ---- fused 3-phase multi-block exclusive scan over both dense count arrays ----

__global__ __launch_bounds__(256) void scanA2(const int* __restrict__ inE, int nE, int nbE,
                                              int* __restrict__ partE,
                                              const int* __restrict__ inV, int nV,
                                              int* __restrict__ partV) {
  const int* in; int n, b; int* partials;
  if ((int)blockIdx.x < nbE) { in = inE; n = nE; b = blockIdx.x; partials = partE; }
  else { in = inV; n = nV; b = blockIdx.x - nbE; partials = partV; }
  __shared__ int lds[256];
  int tid = threadIdx.x;
  int base = b * SCAN_CHUNK + tid * 16;
  int s = 0;
#pragma unroll
  for (int i = 0; i < 16; ++i) {
    int idx = base + i;
    if (idx < n) s += in[idx];
  }
  lds[tid] = s;
  __syncthreads();
  for (int off = 128; off; off >>= 1) {
    if (tid < off) lds[tid] += lds[tid + off];
    __syncthreads();
  }
  if (tid == 0) partials[b] = lds[0];
}

__global__ __launch_bounds__(256) void scanB2(int* __restrict__ partE, int nbE,
                                              int* __restrict__ partV, int nbV) {
  int* partials = (blockIdx.x == 0) ? partE : partV;
  int nb = (blockIdx.x == 0) ? nbE : nbV;
  __shared__ int lds[256];
  int tid = threadIdx.x;
  int v = (tid < nb) ? partials[tid] : 0;
  lds[tid] = v;
  __syncthreads();
  for (int off = 1; off < 256; off <<= 1) {
    int add = (tid >= off) ? lds[tid - off] : 0;
    __syncthreads();
    lds[tid] += add;
    __syncthreads();
  }
  if (tid < nb) partials[tid] = lds[tid] - v;  // exclusive
  if (tid == nb - 1) partials[nb] = lds[tid];  // total
}

__global__ __launch_bounds__(256) void scanC2(const int* __restrict__ inE, int nE, int nbE,
                                              const int* __restrict__ partE, int* __restrict__ outE,
                                              const int* __restrict__ inV, int nV, int nbV,
                                              const int* __restrict__ partV, int* __restrict__ outV) {
  const int* in; const int* partials; int* out; int n, b, nb;
  if ((int)blockIdx.x < nbE) { in = inE; n = nE; b = blockIdx.x; partials = partE; out = outE; nb = nbE; }
  else { in = inV; n = nV; b = blockIdx.x - nbE; partials = partV; out = outV; nb = nbV; }
  __shared__ int lds[256];
  int tid = threadIdx.x;
  int base = b * SCAN_CHUNK + tid * 16;
  int vals[16];
  int s = 0;
#pragma unroll
  for (int i = 0; i < 16; ++i) {
    int idx = base + i;
    int v = (idx < n) ? in[idx] : 0;
    vals[i] = s;
    s += v;
  }
  lds[tid] = s;
  __syncthreads();
  int own = s;
  for (int off = 1; off < 256; off <<= 1) {
    int add = (tid >= off) ? lds[tid - off] : 0;
    __syncthreads();
    lds[tid] += add;
    __syncthreads();
  }
  int excl = lds[tid] - own + partials[b];
#pragma unroll
  for (int i = 0; i < 16; ++i) {
    int idx = base + i;
    if (idx < n) out[idx] = excl + vals[i];
  }
  if (b == 0 && tid == 0) out[n] = partials[nb];
}

// wqt = Wq^T * (1/sqrt(128)) [score scale folded]; wcat[:,128:256] = Wv.
__global__ void prep_att(const float* __restrict__ Wq, const float* __restrict__ Wv,
                         float* __restrict__ wqt, float* __restrict__ wcat) {
  int i = blockIdx.x * blockDim.x + threadIdx.x;  // 128*128
  if (i >= 128 * 128) return;
  int r = i >> 7, c = i & 127;
  wqt[c * 128 + r] = Wq[i] * 0.08838834764831845f;
  wcat[r * 256 + 128 + c] = Wv[i];
}

// ---------------- GEMM A: 128x64 tile, 8x4 micro, fused input-norm / bf16-out / fp32+bf16 shadow ----------------

__global__ __launch_bounds__(256) void gemm128(const float* __restrict__ A,
                                               const float* __restrict__ W,
                                               const float* __restrict__ bias,
                                               float* __restrict__ out,
                                               int R, int K, int C, int act,
                                               const float* __restrict__ insc,
                                               const float* __restrict__ insh, int inact,
                                               int obf16,
                                               unsigned short* __restrict__ out16) {
  __shared__ __align__(16) float As[128][20];
  __shared__ __align__(16) float Bs[16][64];
  int tid = threadIdx.x;
  int tx = tid & 15;
  int ty = tid >> 4;
  int rowBase = blockIdx.x * 128;
  int colBase = blockIdx.y * 64;

  float acc[8][4] = {};

  for (int k0 = 0; k0 < K; k0 += 16) {
#pragma unroll
    for (int p = 0; p < 2; ++p) {
      int li = tid + 256 * p;
      int arow = li >> 2, ac = (li & 3) * 4;
      int gr = rowBase + arow;
      float4 av = make_float4(0.f, 0.f, 0.f, 0.f);
      if (gr < R) av = *(const float4*)(A + (size_t)gr * K + k0 + ac);
      if (insc) {
        float vv[4] = {av.x, av.y, av.z, av.w};
#pragma unroll
        for (int i = 0; i < 4; ++i) {
          float s = insc[k0 + ac + i], sh = insh[k0 + ac + i];
          float v = vv[i] * s + sh;
          if (inact) v = v > 0.f ? v : 0.01f * v;
          vv[i] = v;
        }
        av = make_float4(vv[0], vv[1], vv[2], vv[3]);
      }
      *(float4*)&As[arow][ac] = av;
    }
    {
      int bk = tid >> 4, bc = (tid & 15) * 4;
      *(float4*)&Bs[bk][bc] = *(const float4*)(W + (size_t)(k0 + bk) * C + colBase + bc);
    }
    __syncthreads();
#pragma unroll
    for (int kg = 0; kg < 16; kg += 4) {
      float af[8][4], bf[4][4];
#pragma unroll
      for (int i = 0; i < 4; ++i) {
        *(float4*)af[i]     = *(const float4*)&As[ty * 4 + i][kg];
        *(float4*)af[i + 4] = *(const float4*)&As[64 + ty * 4 + i][kg];
      }
#pragma unroll
      for (int kk = 0; kk < 4; ++kk)
        *(float4*)bf[kk] = *(const float4*)&Bs[kg + kk][tx * 4];
#pragma unroll
      for (int kk = 0; kk < 4; ++kk)
#pragma unroll
        for (int i = 0; i < 8; ++i)
#pragma unroll
          for (int j = 0; j < 4; ++j)
            acc[i][j] = fmaf(af[i][kk], bf[kk][j], acc[i][j]);
    }
    __syncthreads();
  }

#pragma unroll
  for (int i = 0; i < 8; ++i) {
    int r = rowBase + ty * 4 + (i & 3) + (i >> 2) * 64;
    if (r >= R) continue;
    float vals[4];
#pragma unroll
    for (int j = 0; j < 4; ++j) {
      float v = acc[i][j];
      if (bias) v += bias[colBase + tx * 4 + j];
      if (act) v = v > 0.f ? v : 0.01f * v;
      vals[j] = v;
    }
    if (obf16) {
      unsigned short* o16 = (unsigned short*)out;
      ushort4 w = make_ushort4(f2bf(vals[0]), f2bf(vals[1]), f2bf(vals[2]), f2bf(vals[3]));
      *(ushort4*)(o16 + (size_t)r * C + colBase + tx * 4) = w;
    } else {
      *(float4*)(out + (size_t)r * C + colBase + tx * 4) =
          make_float4(vals[0], vals[1], vals[2], vals[3]);
      if (out16) {
        uint2 w = make_uint2(packbf(vals[0], vals[1]), packbf(vals[2], vals[3]));
        *(uint2*)(out16 + (size_t)r * C + colBase + tx * 4) = w;
      }
    }
  }
}

// ---------------- GEMM A2: 64x64 tile, 4x4 micro; ldo = output row stride ----------------

__global__ __launch_bounds__(256) void gemm64(const float* __restrict__ A,
                                              const float* __restrict__ W,
                                              const float* __restrict__ bias,
                                              float* __restrict__ out,
                                              int R, int K, int C, int act,
                                              const float* __restrict__ insc,
                                              const float* __restrict__ insh, int inact,
                                              int ldo) {
  __shared__ __align__(16) float As[64][20];
  __shared__ __align__(16) float Bs[16][64];
  int tid = threadIdx.x;
  int tx = tid & 15;
  int ty = tid >> 4;
  int rowBase = blockIdx.x * 64;
  int colBase = blockIdx.y * 64;

  float acc[4][4] = {};

  for (int k0 = 0; k0 < K; k0 += 16) {
    {
      int arow = tid >> 2, ac = (tid & 3) * 4;
      int gr = rowBase + arow;
      float4 av = make_float4(0.f, 0.f, 0.f, 0.f);
      if (gr < R) av = *(const float4*)(A + (size_t)gr * K + k0 + ac);
      if (insc) {
        float vv[4] = {av.x, av.y, av.z, av.w};
#pragma unroll
        for (int i = 0; i < 4; ++i) {
          float s = insc[k0 + ac + i], sh = insh[k0 + ac + i];
          float v = vv[i] * s + sh;
          if (inact) v = v > 0.f ? v : 0.01f * v;
          vv[i] = v;
        }
        av = make_float4(vv[0], vv[1], vv[2], vv[3]);
      }
      *(float4*)&As[arow][ac] = av;
    }
    {
      int bk = tid >> 4, bc = (tid & 15) * 4;
      *(float4*)&Bs[bk][bc] = *(const float4*)(W + (size_t)(k0 + bk) * C + colBase + bc);
    }
    __syncthreads();
#pragma unroll
    for (int kg = 0; kg < 16; kg += 4) {
      float af[4][4], bf[4][4];
#pragma unroll
      for (int i = 0; i < 4; ++i)
        *(float4*)af[i] = *(const float4*)&As[ty * 4 + i][kg];
#pragma unroll
      for (int kk = 0; kk < 4; ++kk)
        *(float4*)bf[kk] = *(const float4*)&Bs[kg + kk][tx * 4];
#pragma unroll
      for (int kk = 0; kk < 4; ++kk)
#pragma unroll
        for (int i = 0; i < 4; ++i)
#pragma unroll
          for (int j = 0; j < 4; ++j)
            acc[i][j] = fmaf(af[i][kk], bf[kk][j], acc[i][j]);
    }
    __syncthreads();
  }

#pragma unroll
  for (int i = 0; i < 4; ++i) {
    int r = rowBase + ty * 4 + i;
    if (r >= R) continue;
    float vals[4];
#pragma unroll
    for (int j = 0; j < 4; ++j) {
      float v = acc[i][j];
      if (bias) v += bias[colBase + tx * 4 + j];
      if (act) v = v > 0.f ? v : 0.01f * v;
      vals[j] = v;
    }
    *(float4*)(out + (size_t)r * ldo + colBase + tx * 4) = make_float4(vals[0], vals[1], vals[2], vals[3]);
  }
}

// ---------------- segment ops: one wave per segment; 4 x 16-lane groups, 8 feats/lane ----------------

__global__ __launch_bounds__(256) void seg_mean_e(const unsigned short* __restrict__ h16,
                                                  const int* __restrict__ off_e,
                                                  const unsigned short* __restrict__ by_h,
                                                  unsigned short* __restrict__ m_e16, int M) {
  int m = (blockIdx.x * blockDim.x + threadIdx.x) >> 6;
  if (m >= M) return;
  int lane = threadIdx.x & 63;
  int g = lane >> 4;
  int fl = lane & 15;
  int s = off_e[m], e1 = off_e[m + 1];
  float4 a0 = make_float4(0.f, 0.f, 0.f, 0.f), a1 = a0;
  for (int j = s + g; j < e1; j += 4) {
    int vi = by_h[j];
    uint4 hw = *(const uint4*)(h16 + (size_t)vi * HF + fl * 8);
    a0.x += BFLO(hw.x); a0.y += BFHI(hw.x); a0.z += BFLO(hw.y); a0.w += BFHI(hw.y);
    a1.x += BFLO(hw.z); a1.y += BFHI(hw.z); a1.z += BFLO(hw.w); a1.w += BFHI(hw.w);
  }
#pragma unroll
  for (int mask = 16; mask <= 32; mask <<= 1) {
    a0.x += __shfl_xor(a0.x, mask); a0.y += __shfl_xor(a0.y, mask);
    a0.z += __shfl_xor(a0.z, mask); a0.w += __shfl_xor(a0.w, mask);
    a1.x += __shfl_xor(a1.x, mask); a1.y += __shfl_xor(a1.y, mask);
    a1.z += __shfl_xor(a1.z, mask); a1.w += __shfl_xor(a1.w, mask);
  }
  if (g == 0) {
    int cnt = e1 - s;
    float r = 1.f / (float)(cnt > 0 ? cnt : 1);
    uint4 w = make_uint4(packbf(a0.x * r, a0.y * r), packbf(a0.z * r, a0.w * r),
                         packbf(a1.x * r, a1.y * r), packbf(a1.z * r, a1.w * r));
    *(uint4*)(m_e16 + (size_t)m * HF + fl * 8) = w;
  }
}

__global__ __launch_bounds__(256) void seg_mean_v_add(float* __restrict__ h,
                                                      const unsigned short* __restrict__ m_e16,
                                                      const int* __restrict__ off_v,
                                                      const unsigned short* __restrict__ by_v,
                                                      int N) {
  int n = (blockIdx.x * blockDim.x + threadIdx.x) >> 6;
  if (n >= N) return;
  int lane = threadIdx.x & 63;
  int g = lane >> 4;
  int fl = lane & 15;
  int s = off_v[n], e1 = off_v[n + 1];
  float4 a0 = make_float4(0.f, 0.f, 0.f, 0.f), a1 = a0;
  for (int j = s + g; j < e1; j += 4) {
    int he = by_v[j];
    uint4 hw = *(const uint4*)(m_e16 + (size_t)he * HF + fl * 8);
    a0.x += BFLO(hw.x); a0.y += BFHI(hw.x); a0.z += BFLO(hw.y); a0.w += BFHI(hw.y);
    a1.x += BFLO(hw.z); a1.y += BFHI(hw.z); a1.z += BFLO(hw.w); a1.w += BFHI(hw.w);
  }
#pragma unroll
  for (int mask = 16; mask <= 32; mask <<= 1) {
    a0.x += __shfl_xor(a0.x, mask); a0.y += __shfl_xor(a0.y, mask);
    a0.z += __shfl_xor(a0.z, mask); a0.w += __shfl_xor(a0.w, mask);
    a1.x += __shfl_xor(a1.x, mask); a1.y += __shfl_xor(a1.y, mask);
    a1.z += __shfl_xor(a1.z, mask); a1.w += __shfl_xor(a1.w, mask);
  }
  if (g == 0) {
    int cnt = e1 - s;
    float r = 1.f / (float)(cnt > 0 ? cnt : 1);
    float* hp = h + (size_t)n * HF + fl * 8;
    float4 h0 = *(const float4*)hp;
    float4 h1 = *(const float4*)(hp + 4);
    *(float4*)hp = make_float4(h0.x + a0.x * r, h0.y + a0.y * r, h0.z + a0.z * r, h0.w + a0.w * r);
    *(float4*)(hp + 4) = make_float4(h1.x + a1.x * r, h1.y + a1.y * r, h1.z + a1.z * r, h1.w + a1.w * r);
  }
}

// Fused GAT attention: one wave per node; q = h2 (fp32, score scale pre-folded into Wqk);
// kv bf16 [M][256]; software prefetch + defer-max rescale (THR=8).
__global__ __launch_bounds__(256) void att_fused(const float* __restrict__ q,
                                                 const unsigned short* __restrict__ kv,
                                                 const int* __restrict__ off_v,
                                                 const unsigned short* __restrict__ by_v,
                                                 unsigned short* __restrict__ ho16, int N) {
  int n = (blockIdx.x * blockDim.x + threadIdx.x) >> 6;
  if (n >= N) return;
  int lane = threadIdx.x & 63;
  int g = lane >> 4;
  int fl = lane & 15;
  int s0 = off_v[n], s1 = off_v[n + 1];
  const float* qp = q + (size_t)n * HF + fl * 8;
  float4 q0 = *(const float4*)qp;
  float4 q1 = *(const float4*)(qp + 4);
  float m = -INFINITY, l = 0.f;
  float4 a0 = make_float4(0.f, 0.f, 0.f, 0.f), a1 = a0;
  int j = s0 + g;
  uint4 kw = make_uint4(0, 0, 0, 0), vw = kw;
  if (j < s1) {
    const unsigned short* base = kv + (size_t)by_v[j] * 256 + fl * 8;
    kw = *(const uint4*)base;
    vw = *(const uint4*)(base + 128);
  }
  while (j < s1) {
    int jn = j + 4;
    uint4 kw2 = make_uint4(0, 0, 0, 0), vw2 = kw2;
    if (jn < s1) {
      const unsigned short* b2 = kv + (size_t)by_v[jn] * 256 + fl * 8;
      kw2 = *(const uint4*)b2;
      vw2 = *(const uint4*)(b2 + 128);
    }
    float d = q0.x * BFLO(kw.x) + q0.y * BFHI(kw.x) + q0.z * BFLO(kw.y) + q0.w * BFHI(kw.y)
            + q1.x * BFLO(kw.z) + q1.y * BFHI(kw.z) + q1.z * BFLO(kw.w) + q1.w * BFHI(kw.w);
    d += __shfl_xor(d, 1);
    d += __shfl_xor(d, 2);
    d += __shfl_xor(d, 4);
    d += __shfl_xor(d, 8);
    d = d > 0.f ? d : 0.2f * d;   // scale already folded into Wqk
    if (d > m + 8.f) {
      float sc = __expf(m - d);   // first edge: exp(-inf)=0 zeroes l,a
      l *= sc;
      a0.x *= sc; a0.y *= sc; a0.z *= sc; a0.w *= sc;
      a1.x *= sc; a1.y *= sc; a1.z *= sc; a1.w *= sc;
      m = d;
    }
    float p = __expf(d - m);
    l += p;
    a0.x += p * BFLO(vw.x); a0.y += p * BFHI(vw.x);
    a0.z += p * BFLO(vw.y); a0.w += p * BFHI(vw.y);
    a1.x += p * BFLO(vw.z); a1.y += p * BFHI(vw.z);
    a1.z += p * BFLO(vw.w); a1.w += p * BFHI(vw.w);
    kw = kw2; vw = vw2; j = jn;
  }
#pragma unroll
  for (int mask = 16; mask <= 32; mask <<= 1) {
    float m2 = __shfl_xor(m, mask);
    float l2 = __shfl_xor(l, mask);
    float b0x = __shfl_xor(a0.x, mask), b0y = __shfl_xor(a0.y, mask);
    float b0z = __shfl_xor(a0.z, mask), b0w = __shfl_xor(a0.w, mask);
    float b1x = __shfl_xor(a1.x, mask), b1y = __shfl_xor(a1.y, mask);
    float b1z = __shfl_xor(a1.z, mask), b1w = __shfl_xor(a1.w, mask);
    float mn = fmaxf(fmaxf(m, m2), -1e30f);
    float ea = __expf(m - mn), eb = __expf(m2 - mn);
    l = l * ea + l2 * eb;
    a0.x = a0.x * ea + b0x * eb; a0.y = a0.y * ea + b0y * eb;
    a0.z = a0.z * ea + b0z * eb; a0.w = a0.w * ea + b0w * eb;
    a1.x = a1.x * ea + b1x * eb; a1.y = a1.y * ea + b1y * eb;
    a1.z = a1.z * ea + b1z * eb; a1.w = a1.w * ea + b1w * eb;
    m = fmaxf(m, m2);
  }
  if (g == 0) {
    float inv = 1.f / fmaxf(l, 1e-16f);
    uint4 w = make_uint4(packbf(a0.x * inv, a0.y * inv), packbf(a0.z * inv, a0.w * inv),
                         packbf(a1.x * inv, a1.y * inv), packbf(a1.z * inv, a1.w * inv));
    *(uint4*)(ho16 + (size_t)n * HF + fl * 8) = w;
  }
}

// z[m][0:128] = segment_min(ho16[node]) (0 if empty); z[m][128:256] = xe[m]
__global__ __launch_bounds__(256) void seg_min_z(const unsigned short* __restrict__ ho16,
                                                 const int* __restrict__ off_e,
                                                 const unsigned short* __restrict__ by_h,
                                                 const float* __restrict__ xe,
                                                 float* __restrict__ z, int M) {
  int m = (blockIdx.x * blockDim.x + threadIdx.x) >> 6;
  if (m >= M) return;
  int lane = threadIdx.x & 63;
  int g = lane >> 4;
  int fl = lane & 15;
  int s = off_e[m], e1 = off_e[m + 1];
  float4 a0 = make_float4(FLT_MAX, FLT_MAX, FLT_MAX, FLT_MAX), a1 = a0;
  for (int j = s + g; j < e1; j += 4) {
    int vi = by_h[j];
    uint4 hw = *(const uint4*)(ho16 + (size_t)vi * HF + fl * 8);
    a0.x = fminf(a0.x, BFLO(hw.x)); a0.y = fminf(a0.y, BFHI(hw.x));
    a0.z = fminf(a0.z, BFLO(hw.y)); a0.w = fminf(a0.w, BFHI(hw.y));
    a1.x = fminf(a1.x, BFLO(hw.z)); a1.y = fminf(a1.y, BFHI(hw.z));
    a1.z = fminf(a1.z, BFLO(hw.w)); a1.w = fminf(a1.w, BFHI(hw.w));
  }
#pragma unroll
  for (int mask = 16; mask <= 32; mask <<= 1) {
    a0.x = fminf(a0.x, __shfl_xor(a0.x, mask)); a0.y = fminf(a0.y, __shfl_xor(a0.y, mask));
    a0.z = fminf(a0.z, __shfl_xor(a0.z, mask)); a0.w = fminf(a0.w, __shfl_xor(a0.w, mask));
    a1.x = fminf(a1.x, __shfl_xor(a1.x, mask)); a1.y = fminf(a1.y, __shfl_xor(a1.y, mask));
    a1.z = fminf(a1.z, __shfl_xor(a1.z, mask)); a1.w = fminf(a1.w, __shfl_xor(a1.w, mask));
  }
  if (g == 0) {
    bool nz = (e1 > s);
    float* op = z + (size_t)m * 256 + fl * 8;
    *(float4*)op = nz ? a0 : make_float4(0.f, 0.f, 0.f, 0.f);
    *(float4*)(op + 4) = nz ? a1 : make_float4(0.f, 0.f, 0.f, 0.f);
  } else if (g == 1) {
    const float* xp = xe + (size_t)m * HF + fl * 8;
    float* op = z + (size_t)m * 256 + 128 + fl * 8;
    *(float4*)op = *(const float4*)xp;
    *(float4*)(op + 4) = *(const float4*)(xp + 4);
  }
}

// ---------------- GraphNorm stats + scale: 1024-thr blocks, LDS row-lane reduce, last-block ticket ----------------

__global__ __launch_bounds__(1024) void colstats_mk(const float* __restrict__ z, int rows, int C,
                                                    float* __restrict__ stats,
                                                    const float* __restrict__ w,
                                                    const float* __restrict__ b,
                                                    const float* __restrict__ a, float invrows,
                                                    float* __restrict__ sc, float* __restrict__ sh,
                                                    int* __restrict__ done) {
  int tid = threadIdx.x;
  int RL = 1024 / C;
  int col = tid & (C - 1);
  int ro = tid / C;
  float s1 = 0.f, s2 = 0.f;
  for (int r = blockIdx.x * RL + ro; r < rows; r += gridDim.x * RL) {
    float v = z[(size_t)r * C + col];
    s1 += v;
    s2 += v * v;
  }
  __shared__ float l1[1024], l2[1024];
  l1[tid] = s1;
  l2[tid] = s2;
  __syncthreads();
  for (int off = 512; off >= C; off >>= 1) {
    if (tid < off) { l1[tid] += l1[tid + off]; l2[tid] += l2[tid + off]; }
    __syncthreads();
  }
  if (tid < C) {
    atomicAdd(&stats[tid], l1[tid]);
    atomicAdd(&stats[C + tid], l2[tid]);
  }
  __threadfence();
  __shared__ int lastBlk;
  __syncthreads();
  if (tid == 0) lastBlk = (atomicAdd(done, 1) == (int)gridDim.x - 1);
  __syncthreads();
  if (lastBlk) {
    __threadfence();
    if (tid < C) {
      float mu = stats[tid] * invrows;
      float ex2 = stats[C + tid] * invrows;
      float av = a[tid];
      float var = ex2 - 2.f * av * mu * mu + av * av * mu * mu;
      float s = w[tid] * rsqrtf(var + 1e-5f);
      sc[tid] = s;
      sh[tid] = b[tid] - av * mu * s;
    }
  }
}

// ---------------- launch ----------------

extern "C" void kernel_launch(void* const* d_in, const int* in_sizes, int n_in,
                              void* d_out, int out_size, void* d_ws, size_t ws_size,
                              hipStream_t stream) {
  const float* x        = (const float*)d_in[0];
  const float* x_e      = (const float*)d_in[2];
  const int*   node_idx = (const int*)d_in[3];
  const int*   hedge_idx= (const int*)d_in[4];
  const float* her_W1   = (const float*)d_in[5];
  const float* her_b1   = (const float*)d_in[6];
  const float* her_W2   = (const float*)d_in[7];
  const float* her_b2   = (const float*)d_in[8];
  const float* sr_W1    = (const float*)d_in[9];
  const float* sr_b1    = (const float*)d_in[10];
  const float* sr_W2    = (const float*)d_in[11];
  const float* sr_b2    = (const float*)d_in[12];
  const float* att_Wq   = (const float*)d_in[13];
  const float* att_Wk   = (const float*)d_in[14];
  const float* att_Wv   = (const float*)d_in[15];
  const float* ef_W     = (const float*)d_in[16];
  const float* ef_b     = (const float*)d_in[17];
  const float* gn1_w    = (const float*)d_in[18];
  const float* gn1_b    = (const float*)d_in[19];
  const float* gn1_a    = (const float*)d_in[20];
  const float* gn2_w    = (const float*)d_in[21];
  const float* gn2_b    = (const float*)d_in[22];
  const float* gn2_a    = (const float*)d_in[23];
  const float* cls_W1   = (const float*)d_in[24];
  const float* cls_b1   = (const float*)d_in[25];
  const float* cls_W2   = (const float*)d_in[26];
  const float* cls_b2   = (const float*)d_in[27];

  const int N = in_sizes[0] / HF;
  const int M = in_sizes[2] / HF;
  const int E = in_sizes[3];
  const int NVR = idiv(N, VRANGE);  // node range count (2 for N=50000)

  // ---- workspace layout ----
  char* wp = (char*)d_ws;
  float* stats1 = (float*)wp; wp += 512 * 4;
  float* stats2 = (float*)wp; wp += 256 * 4;
  int* done1 = (int*)wp; wp += 64;
  int* done2 = (int*)wp; wp += 64;
  size_t zero_bytes = (size_t)(wp - (char*)d_ws);
  int* cnt_e = (int*)wp; wp += (size_t)M * 4;
  int* cnt_v = (int*)wp; wp += (size_t)N * 4;
  int* off_e = (int*)wp; wp += (size_t)(M + 1) * 4;
  int* off_v = (int*)wp; wp += (size_t)(N + 1) * 4;
  unsigned short* by_h = (unsigned short*)wp; wp += ((size_t)E * 2 + 3) & ~(size_t)3;
  unsigned short* by_v = (unsigned short*)wp; wp += ((size_t)E * 2 + 3) & ~(size_t)3;
  int* part_e = (int*)wp; wp += 257 * 4;
  int* part_v = (int*)wp; wp += 257 * 4;
  float* sc1 = (float*)wp; wp += 256 * 4;
  float* sh1 = (float*)wp; wp += 256 * 4;
  float* sc2 = (float*)wp; wp += 128 * 4;
  float* sh2 = (float*)wp; wp += 128 * 4;
  wp = (char*)(((uintptr_t)wp + 255) & ~(uintptr_t)255);
  float* wqt  = (float*)wp; wp += (size_t)128 * 128 * 4;   // Wq^T * scale
  float* wcat = (float*)wp; wp += (size_t)128 * 256 * 4;   // [Wqk | Wv]
  float* h   = (float*)wp; wp += (size_t)N * HF * 4;       // sr1 out, += m_v, sr2 in; later c1
  float* h2  = (float*)wp; wp += (size_t)N * HF * 4;       // sr2 out = q; later z [M,256]
  float* xe  = (float*)wp; wp += (size_t)M * HF * 4;
  float* kvf = (float*)wp; wp += (size_t)M * 256 * 4;      // t1 fp32 alias / kv bf16
  float* z2  = (float*)wp; wp += (size_t)M * HF * 4;
  unsigned short* h16   = (unsigned short*)wp; wp += (size_t)N * HF * 2;  // sr1 bf16 shadow
  unsigned short* ho16  = (unsigned short*)wp; wp += (size_t)N * HF * 2;  // att out bf16
  unsigned short* m_e16 = (unsigned short*)wp; wp += (size_t)M * HF * 2;

  unsigned short* kv = (unsigned short*)kvf;   // [M][256] bf16
  float* t1  = kvf;                // her hidden [M,128] fp32 (dead before kv written)
  float* z   = h2;                 // [M,256] (h2 dead as q after att_fused)
  float* c1  = h;                  // [M,128] (h dead after sr2)

  // Histogram matrices alias h (dead until sr1): NB*M + NVR*NB*VPACK ints = 17.9MB < 25.6MB
  int* HE = (int*)h;
  int* HV = HE + (size_t)NB_CSR * M;

  hipMemsetAsync(d_ws, 0, zero_bytes, stream);

  // ---- CSR build: counting sort, zero device-scope atomics ----
  csr_hist<<<dim3(NB_CSR, 1 + NVR), 512, 0, stream>>>(node_idx, hedge_idx, E, M, HE, HV);
  csr_colscan<<<idiv(M + NVR * VPACK, 256), 256, 0, stream>>>(HE, HV, M, N, NVR, cnt_e, cnt_v);
  int nbE = idiv(M, SCAN_CHUNK);
  int nbV = idiv(N, SCAN_CHUNK);
  scanA2<<<nbE + nbV, 256, 0, stream>>>(cnt_e, M, nbE, part_e, cnt_v, N, part_v);
  scanB2<<<2, 256, 0, stream>>>(part_e, nbE, part_v, nbV);
  scanC2<<<nbE + nbV, 256, 0, stream>>>(cnt_e, M, nbE, part_e, off_e, cnt_v, N, nbV, part_v, off_v);
  csr_scatter<<<dim3(NB_CSR, 1 + NVR), 512, 0, stream>>>(node_idx, hedge_idx, E, M, HE, HV,
                                                         off_e, off_v, by_h, by_v);

  // wqt = Wq^T*scale, wcat right = Wv; then wcat left = Wk @ wqt
  prep_att<<<64, 256, 0, stream>>>(att_Wq, att_Wv, wqt, wcat);
  gemm64<<<dim3(2, 2), 256, 0, stream>>>(att_Wk, wqt, nullptr, wcat, 128, 128, 128, 0,
                                         nullptr, nullptr, 0, 256);

  dim3 blk(256);
  // her MLP: xe
  gemm64<<<dim3(idiv(M, 64), 2), blk, 0, stream>>>(x_e, her_W1, her_b1, t1, M, HF, HF, 1, nullptr, nullptr, 0, HF);
  gemm64<<<dim3(idiv(M, 64), 2), blk, 0, stream>>>(t1, her_W2, her_b2, xe, M, HF, HF, 0, nullptr, nullptr, 0, HF);
  // sr layer1 (fp32 + bf16 shadow), 128x64 tiles (overwrites HE/HV — CSR matrices dead now)
  gemm128<<<dim3(idiv(N, 128), 2), blk, 0, stream>>>(x, sr_W1, sr_b1, h, N, HF, HF, 1,
                                                     nullptr, nullptr, 0, 0, h16);
  // message passing means (bf16 gathers)
  seg_mean_e<<<idiv(M * 64, 256), blk, 0, stream>>>(h16, off_e, by_h, m_e16, M);
  seg_mean_v_add<<<idiv(N * 64, 256), blk, 0, stream>>>(h, m_e16, off_v, by_v, N);
  // sr layer2 -> h2 (doubles as q)
  gemm128<<<dim3(idiv(N, 128), 2), blk, 0, stream>>>(h, sr_W2, sr_b2, h2, N, HF, HF, 1,
                                                     nullptr, nullptr, 0, 0, nullptr);
  // kv projection: [xe@Wqk | xe@Wv] in bf16
  gemm128<<<dim3(idiv(M, 128), 4), blk, 0, stream>>>(xe, wcat, nullptr, (float*)kv, M, HF, 256, 0,
                                                     nullptr, nullptr, 0, /*obf16=*/1, nullptr);
  // fused attention (q = h2)
  att_fused<<<idiv(N * 64, 256), blk, 0, stream>>>(h2, kv, off_v, by_v, ho16, N);
  // min aggregation + concat (z overwrites h2)
  seg_min_z<<<idiv(M * 64, 256), blk, 0, stream>>>(ho16, off_e, by_h, xe, z, M);
  // gn1 stats+scale (fused, 1024-thr) -> ef linear(+act) -> gn2 stats+scale
  colstats_mk<<<128, 1024, 0, stream>>>(z, M, 256, stats1, gn1_w, gn1_b, gn1_a,
                                        1.f / (float)M, sc1, sh1, done1);
  gemm64<<<dim3(idiv(M, 64), 2), blk, 0, stream>>>(z, ef_W, ef_b, z2, M, 2 * HF, HF, 1,
                                                   sc1, sh1, 0, HF);
  colstats_mk<<<128, 1024, 0, stream>>>(z2, M, 128, stats2, gn2_w, gn2_b, gn2_a,
                                        1.f / (float)M, sc2, sh2, done2);
  // classifier
  gemm64<<<dim3(idiv(M, 64), 2), blk, 0, stream>>>(z2, cls_W1, cls_b1, c1, M, HF, HF, 1, sc2, sh2, 1, HF);
  gemm64<<<dim3(idiv(M, 64), 1), blk, 0, stream>>>(c1, cls_W2, cls_b2, (float*)d_out, M, HF, 64, 0, nullptr, nullptr, 0, 64);
}

// Round 4
// 437.558 us; speedup vs baseline: 1.5269x; 1.0283x over previous
//
#include <hip/hip_runtime.h>
#include <float.h>
#include <math.h>

#define HF 128
#define SCAN_CHUNK 4096  // 256 threads x 16 elems
#define NB_CSR 128       // chunks for counting-sort CSR build
#define VPACK 12500      // packed (2-per-int) node bins per range: 25000 nodes / range
#define VRANGE (2 * VPACK)

static inline int idiv(int a, int b) { return (a + b - 1) / b; }

__device__ inline unsigned short f2bf(float x) {  // RNE float->bf16
  unsigned u = __float_as_uint(x);
  return (unsigned short)((u + 0x7fffu + ((u >> 16) & 1u)) >> 16);
}
__device__ inline unsigned packbf(float a, float b) {
  return (unsigned)f2bf(a) | ((unsigned)f2bf(b) << 16);
}
#define BFLO(w) __uint_as_float((w) << 16)
#define BFHI(w) __uint_as_float((w) & 0xffff0000u)

// ---------------- CSR build: LDS-histogram counting sort (ZERO device-scope atomics) ----------------
// Round-2 evidence: 1.2M global atomics = 24.7 G/s RMW wall (48.5us, invariant to
// occupancy/batching). Replaced by per-chunk LDS histograms + column scan + scatter.

__global__ __launch_bounds__(512) void csr_hist(const int* __restrict__ nidx,
                                                const int* __restrict__ hidx,
                                                int E, int M,
                                                int* __restrict__ HE,
                                                int* __restrict__ HV) {
  __shared__ int bins[VPACK];
  int b = blockIdx.x, y = blockIdx.y, tid = threadIdx.x;
  int chunk = (E + NB_CSR - 1) / NB_CSR;
  int e0 = b * chunk;
  int e1 = e0 + chunk; if (e1 > E) e1 = E;
  if (y == 0) {
    for (int s = tid; s < M; s += 512) bins[s] = 0;
    __syncthreads();
    for (int e = e0 + tid; e < e1; e += 512) atomicAdd(&bins[hidx[e]], 1);
    __syncthreads();
    for (int s = tid; s < M; s += 512) HE[(size_t)b * M + s] = bins[s];
  } else {
    int R = (y - 1) * VRANGE;
    int* HVr = HV + ((size_t)(y - 1) * NB_CSR + b) * VPACK;
    for (int q = tid; q < VPACK; q += 512) bins[q] = 0;
    __syncthreads();
    for (int e = e0 + tid; e < e1; e += 512) {
      int v = nidx[e] - R;
      if ((unsigned)v < (unsigned)VRANGE) atomicAdd(&bins[v >> 1], (v & 1) ? 0x10000 : 1);
    }
    __syncthreads();
    for (int q = tid; q < VPACK; q += 512) HVr[q] = bins[q];
  }
}

// Per-segment exclusive scan over the NB_CSR chunks (in place) + dense counts.
__global__ __launch_bounds__(256) void csr_colscan(int* __restrict__ HE,
                                                   int* __restrict__ HV,
                                                   int M, int N, int NVR,
                                                   int* __restrict__ cnt_e,
                                                   int* __restrict__ cnt_v) {
  int col = blockIdx.x * 256 + threadIdx.x;
  if (col < M) {
    int run = 0;
    for (int b = 0; b < NB_CSR; ++b) {
      size_t i = (size_t)b * M + col;
      int t = HE[i]; HE[i] = run; run += t;
    }
    cnt_e[col] = run;
  } else if (col < M + NVR * VPACK) {
    int c = col - M;
    int r = c / VPACK, q = c - r * VPACK;
    int* HVr = HV + (size_t)r * NB_CSR * VPACK;
    int run = 0;
    for (int b = 0; b < NB_CSR; ++b) {
      size_t i = (size_t)b * VPACK + q;
      int t = HVr[i]; HVr[i] = run; run += t;
    }
    int node = r * VRANGE + 2 * q;
    if (node < N) cnt_v[node] = run & 0xffff;
    if (node + 1 < N) cnt_v[node + 1] = run >> 16;
  }
}

// Scatter: preload LDS bins with global base (off + chunk-exclusive), LDS-atomic rank.
__global__ __launch_bounds__(512) void csr_scatter(const int* __restrict__ nidx,
                                                   const int* __restrict__ hidx,
                                                   int E, int M,
                                                   const int* __restrict__ HE,
                                                   const int* __restrict__ HV,
                                                   const int* __restrict__ off_e,
                                                   const int* __restrict__ off_v,
                                                   unsigned short* __restrict__ by_h,
                                                   unsigned short* __restrict__ by_v) {
  __shared__ int bins[VPACK];
  int b = blockIdx.x, y = blockIdx.y, tid = threadIdx.x;
  int chunk = (E + NB_CSR - 1) / NB_CSR;
  int e0 = b * chunk;
  int e1 = e0 + chunk; if (e1 > E) e1 = E;
  if (y == 0) {
    for (int s = tid; s < M; s += 512) bins[s] = off_e[s] + HE[(size_t)b * M + s];
    __syncthreads();
    for (int e = e0 + tid; e < e1; e += 512) {
      int pos = atomicAdd(&bins[hidx[e]], 1);
      by_h[pos] = (unsigned short)nidx[e];
    }
  } else {
    int R = (y - 1) * VRANGE;
    const int* HVr = HV + ((size_t)(y - 1) * NB_CSR + b) * VPACK;
    for (int q = tid; q < VPACK; q += 512) bins[q] = HVr[q];
    __syncthreads();
    for (int e = e0 + tid; e < e1; e += 512) {
      int v = nidx[e];
      int vr = v - R;
      if ((unsigned)vr < (unsigned)VRANGE) {
        int old = atomicAdd(&bins[vr >> 1], (vr & 1) ? 0x10000 : 1);
        int rank = (vr & 1) ? (old >> 16) : (old & 0xffff);
        by_v[off_v[v] + rank] = (unsigned short)hidx[e];
      }
    }
  }
}

// ---- fused 3-phase multi-block exclusive scan over both dense count arrays ----

__global__ __launch_bounds__(256) void scanA2(const int* __restrict__ inE, int nE, int nbE,
                                              int* __restrict__ partE,
                                              const int* __restrict__ inV, int nV,
                                              int* __restrict__ partV) {
  const int* in; int n, b; int* partials;
  if ((int)blockIdx.x < nbE) { in = inE; n = nE; b = blockIdx.x; partials = partE; }
  else { in = inV; n = nV; b = blockIdx.x - nbE; partials = partV; }
  __shared__ int lds[256];
  int tid = threadIdx.x;
  int base = b * SCAN_CHUNK + tid * 16;
  int s = 0;
#pragma unroll
  for (int i = 0; i < 16; ++i) {
    int idx = base + i;
    if (idx < n) s += in[idx];
  }
  lds[tid] = s;
  __syncthreads();
  for (int off = 128; off; off >>= 1) {
    if (tid < off) lds[tid] += lds[tid + off];
    __syncthreads();
  }
  if (tid == 0) partials[b] = lds[0];
}

__global__ __launch_bounds__(256) void scanB2(int* __restrict__ partE, int nbE,
                                              int* __restrict__ partV, int nbV) {
  int* partials = (blockIdx.x == 0) ? partE : partV;
  int nb = (blockIdx.x == 0) ? nbE : nbV;
  __shared__ int lds[256];
  int tid = threadIdx.x;
  int v = (tid < nb) ? partials[tid] : 0;
  lds[tid] = v;
  __syncthreads();
  for (int off = 1; off < 256; off <<= 1) {
    int add = (tid >= off) ? lds[tid - off] : 0;
    __syncthreads();
    lds[tid] += add;
    __syncthreads();
  }
  if (tid < nb) partials[tid] = lds[tid] - v;  // exclusive
  if (tid == nb - 1) partials[nb] = lds[tid];  // total
}

__global__ __launch_bounds__(256) void scanC2(const int* __restrict__ inE, int nE, int nbE,
                                              const int* __restrict__ partE, int* __restrict__ outE,
                                              const int* __restrict__ inV, int nV, int nbV,
                                              const int* __restrict__ partV, int* __restrict__ outV) {
  const int* in; const int* partials; int* out; int n, b, nb;
  if ((int)blockIdx.x < nbE) { in = inE; n = nE; b = blockIdx.x; partials = partE; out = outE; nb = nbE; }
  else { in = inV; n = nV; b = blockIdx.x - nbE; partials = partV; out = outV; nb = nbV; }
  __shared__ int lds[256];
  int tid = threadIdx.x;
  int base = b * SCAN_CHUNK + tid * 16;
  int vals[16];
  int s = 0;
#pragma unroll
  for (int i = 0; i < 16; ++i) {
    int idx = base + i;
    int v = (idx < n) ? in[idx] : 0;
    vals[i] = s;
    s += v;
  }
  lds[tid] = s;
  __syncthreads();
  int own = s;
  for (int off = 1; off < 256; off <<= 1) {
    int add = (tid >= off) ? lds[tid - off] : 0;
    __syncthreads();
    lds[tid] += add;
    __syncthreads();
  }
  int excl = lds[tid] - own + partials[b];
#pragma unroll
  for (int i = 0; i < 16; ++i) {
    int idx = base + i;
    if (idx < n) out[idx] = excl + vals[i];
  }
  if (b == 0 && tid == 0) out[n] = partials[nb];
}

// wqt = Wq^T * (1/sqrt(128)) [score scale folded]; wcat[:,128:256] = Wv.
__global__ void prep_att(const float* __restrict__ Wq, const float* __restrict__ Wv,
                         float* __restrict__ wqt, float* __restrict__ wcat) {
  int i = blockIdx.x * blockDim.x + threadIdx.x;  // 128*128
  if (i >= 128 * 128) return;
  int r = i >> 7, c = i & 127;
  wqt[c * 128 + r] = Wq[i] * 0.08838834764831845f;
  wcat[r * 256 + 128 + c] = Wv[i];
}

// ---------------- GEMM: 64x64 tile, 4x4 micro; fused input-norm / act / bf16-out / fp32+bf16 shadow ----------------
// Round-3 evidence: 128x64 tiles gave only 782 blocks (3/CU, 21% occ, VALU 33%).
// 64x64 doubles the grid; k-accumulation order identical -> bit-identical results.

__global__ __launch_bounds__(256) void gemm64(const float* __restrict__ A,
                                              const float* __restrict__ W,
                                              const float* __restrict__ bias,
                                              float* __restrict__ out,
                                              int R, int K, int C, int act,
                                              const float* __restrict__ insc,
                                              const float* __restrict__ insh, int inact,
                                              int ldo, int obf16,
                                              unsigned short* __restrict__ out16) {
  __shared__ __align__(16) float As[64][20];
  __shared__ __align__(16) float Bs[16][64];
  int tid = threadIdx.x;
  int tx = tid & 15;
  int ty = tid >> 4;
  int rowBase = blockIdx.x * 64;
  int colBase = blockIdx.y * 64;

  float acc[4][4] = {};

  for (int k0 = 0; k0 < K; k0 += 16) {
    {
      int arow = tid >> 2, ac = (tid & 3) * 4;
      int gr = rowBase + arow;
      float4 av = make_float4(0.f, 0.f, 0.f, 0.f);
      if (gr < R) av = *(const float4*)(A + (size_t)gr * K + k0 + ac);
      if (insc) {
        float vv[4] = {av.x, av.y, av.z, av.w};
#pragma unroll
        for (int i = 0; i < 4; ++i) {
          float s = insc[k0 + ac + i], sh = insh[k0 + ac + i];
          float v = vv[i] * s + sh;
          if (inact) v = v > 0.f ? v : 0.01f * v;
          vv[i] = v;
        }
        av = make_float4(vv[0], vv[1], vv[2], vv[3]);
      }
      *(float4*)&As[arow][ac] = av;
    }
    {
      int bk = tid >> 4, bc = (tid & 15) * 4;
      *(float4*)&Bs[bk][bc] = *(const float4*)(W + (size_t)(k0 + bk) * C + colBase + bc);
    }
    __syncthreads();
#pragma unroll
    for (int kg = 0; kg < 16; kg += 4) {
      float af[4][4], bf[4][4];
#pragma unroll
      for (int i = 0; i < 4; ++i)
        *(float4*)af[i] = *(const float4*)&As[ty * 4 + i][kg];
#pragma unroll
      for (int kk = 0; kk < 4; ++kk)
        *(float4*)bf[kk] = *(const float4*)&Bs[kg + kk][tx * 4];
#pragma unroll
      for (int kk = 0; kk < 4; ++kk)
#pragma unroll
        for (int i = 0; i < 4; ++i)
#pragma unroll
          for (int j = 0; j < 4; ++j)
            acc[i][j] = fmaf(af[i][kk], bf[kk][j], acc[i][j]);
    }
    __syncthreads();
  }

#pragma unroll
  for (int i = 0; i < 4; ++i) {
    int r = rowBase + ty * 4 + i;
    if (r >= R) continue;
    float vals[4];
#pragma unroll
    for (int j = 0; j < 4; ++j) {
      float v = acc[i][j];
      if (bias) v += bias[colBase + tx * 4 + j];
      if (act) v = v > 0.f ? v : 0.01f * v;
      vals[j] = v;
    }
    if (obf16) {
      unsigned short* o16 = (unsigned short*)out;
      ushort4 w = make_ushort4(f2bf(vals[0]), f2bf(vals[1]), f2bf(vals[2]), f2bf(vals[3]));
      *(ushort4*)(o16 + (size_t)r * ldo + colBase + tx * 4) = w;
    } else {
      *(float4*)(out + (size_t)r * ldo + colBase + tx * 4) =
          make_float4(vals[0], vals[1], vals[2], vals[3]);
      if (out16) {
        uint2 w = make_uint2(packbf(vals[0], vals[1]), packbf(vals[2], vals[3]));
        *(uint2*)(out16 + (size_t)r * ldo + colBase + tx * 4) = w;
      }
    }
  }
}

// ---------------- segment ops: one wave per segment; 4 x 16-lane groups, 8 feats/lane ----------------

__global__ __launch_bounds__(256) void seg_mean_e(const unsigned short* __restrict__ h16,
                                                  const int* __restrict__ off_e,
                                                  const unsigned short* __restrict__ by_h,
                                                  unsigned short* __restrict__ m_e16, int M) {
  int m = (blockIdx.x * blockDim.x + threadIdx.x) >> 6;
  if (m >= M) return;
  int lane = threadIdx.x & 63;
  int g = lane >> 4;
  int fl = lane & 15;
  int s = off_e[m], e1 = off_e[m + 1];
  float4 a0 = make_float4(0.f, 0.f, 0.f, 0.f), a1 = a0;
  for (int j = s + g; j < e1; j += 4) {
    int vi = by_h[j];
    uint4 hw = *(const uint4*)(h16 + (size_t)vi * HF + fl * 8);
    a0.x += BFLO(hw.x); a0.y += BFHI(hw.x); a0.z += BFLO(hw.y); a0.w += BFHI(hw.y);
    a1.x += BFLO(hw.z); a1.y += BFHI(hw.z); a1.z += BFLO(hw.w); a1.w += BFHI(hw.w);
  }
#pragma unroll
  for (int mask = 16; mask <= 32; mask <<= 1) {
    a0.x += __shfl_xor(a0.x, mask); a0.y += __shfl_xor(a0.y, mask);
    a0.z += __shfl_xor(a0.z, mask); a0.w += __shfl_xor(a0.w, mask);
    a1.x += __shfl_xor(a1.x, mask); a1.y += __shfl_xor(a1.y, mask);
    a1.z += __shfl_xor(a1.z, mask); a1.w += __shfl_xor(a1.w, mask);
  }
  if (g == 0) {
    int cnt = e1 - s;
    float r = 1.f / (float)(cnt > 0 ? cnt : 1);
    uint4 w = make_uint4(packbf(a0.x * r, a0.y * r), packbf(a0.z * r, a0.w * r),
                         packbf(a1.x * r, a1.y * r), packbf(a1.z * r, a1.w * r));
    *(uint4*)(m_e16 + (size_t)m * HF + fl * 8) = w;
  }
}

__global__ __launch_bounds__(256) void seg_mean_v_add(float* __restrict__ h,
                                                      const unsigned short* __restrict__ m_e16,
                                                      const int* __restrict__ off_v,
                                                      const unsigned short* __restrict__ by_v,
                                                      int N) {
  int n = (blockIdx.x * blockDim.x + threadIdx.x) >> 6;
  if (n >= N) return;
  int lane = threadIdx.x & 63;
  int g = lane >> 4;
  int fl = lane & 15;
  int s = off_v[n], e1 = off_v[n + 1];
  float4 a0 = make_float4(0.f, 0.f, 0.f, 0.f), a1 = a0;
  for (int j = s + g; j < e1; j += 4) {
    int he = by_v[j];
    uint4 hw = *(const uint4*)(m_e16 + (size_t)he * HF + fl * 8);
    a0.x += BFLO(hw.x); a0.y += BFHI(hw.x); a0.z += BFLO(hw.y); a0.w += BFHI(hw.y);
    a1.x += BFLO(hw.z); a1.y += BFHI(hw.z); a1.z += BFLO(hw.w); a1.w += BFHI(hw.w);
  }
#pragma unroll
  for (int mask = 16; mask <= 32; mask <<= 1) {
    a0.x += __shfl_xor(a0.x, mask); a0.y += __shfl_xor(a0.y, mask);
    a0.z += __shfl_xor(a0.z, mask); a0.w += __shfl_xor(a0.w, mask);
    a1.x += __shfl_xor(a1.x, mask); a1.y += __shfl_xor(a1.y, mask);
    a1.z += __shfl_xor(a1.z, mask); a1.w += __shfl_xor(a1.w, mask);
  }
  if (g == 0) {
    int cnt = e1 - s;
    float r = 1.f / (float)(cnt > 0 ? cnt : 1);
    float* hp = h + (size_t)n * HF + fl * 8;
    float4 h0 = *(const float4*)hp;
    float4 h1 = *(const float4*)(hp + 4);
    *(float4*)hp = make_float4(h0.x + a0.x * r, h0.y + a0.y * r, h0.z + a0.z * r, h0.w + a0.w * r);
    *(float4*)(hp + 4) = make_float4(h1.x + a1.x * r, h1.y + a1.y * r, h1.z + a1.z * r, h1.w + a1.w * r);
  }
}

// Fused GAT attention: one wave per node; q = h2 (fp32, score scale pre-folded into Wqk);
// kv bf16 [M][256]; software prefetch + defer-max rescale (THR=8).
__global__ __launch_bounds__(256) void att_fused(const float* __restrict__ q,
                                                 const unsigned short* __restrict__ kv,
                                                 const int* __restrict__ off_v,
                                                 const unsigned short* __restrict__ by_v,
                                                 unsigned short* __restrict__ ho16, int N) {
  int n = (blockIdx.x * blockDim.x + threadIdx.x) >> 6;
  if (n >= N) return;
  int lane = threadIdx.x & 63;
  int g = lane >> 4;
  int fl = lane & 15;
  int s0 = off_v[n], s1 = off_v[n + 1];
  const float* qp = q + (size_t)n * HF + fl * 8;
  float4 q0 = *(const float4*)qp;
  float4 q1 = *(const float4*)(qp + 4);
  float m = -INFINITY, l = 0.f;
  float4 a0 = make_float4(0.f, 0.f, 0.f, 0.f), a1 = a0;
  int j = s0 + g;
  uint4 kw = make_uint4(0, 0, 0, 0), vw = kw;
  if (j < s1) {
    const unsigned short* base = kv + (size_t)by_v[j] * 256 + fl * 8;
    kw = *(const uint4*)base;
    vw = *(const uint4*)(base + 128);
  }
  while (j < s1) {
    int jn = j + 4;
    uint4 kw2 = make_uint4(0, 0, 0, 0), vw2 = kw2;
    if (jn < s1) {
      const unsigned short* b2 = kv + (size_t)by_v[jn] * 256 + fl * 8;
      kw2 = *(const uint4*)b2;
      vw2 = *(const uint4*)(b2 + 128);
    }
    float d = q0.x * BFLO(kw.x) + q0.y * BFHI(kw.x) + q0.z * BFLO(kw.y) + q0.w * BFHI(kw.y)
            + q1.x * BFLO(kw.z) + q1.y * BFHI(kw.z) + q1.z * BFLO(kw.w) + q1.w * BFHI(kw.w);
    d += __shfl_xor(d, 1);
    d += __shfl_xor(d, 2);
    d += __shfl_xor(d, 4);
    d += __shfl_xor(d, 8);
    d = d > 0.f ? d : 0.2f * d;   // scale already folded into Wqk
    if (d > m + 8.f) {
      float sc = __expf(m - d);   // first edge: exp(-inf)=0 zeroes l,a
      l *= sc;
      a0.x *= sc; a0.y *= sc; a0.z *= sc; a0.w *= sc;
      a1.x *= sc; a1.y *= sc; a1.z *= sc; a1.w *= sc;
      m = d;
    }
    float p = __expf(d - m);
    l += p;
    a0.x += p * BFLO(vw.x); a0.y += p * BFHI(vw.x);
    a0.z += p * BFLO(vw.y); a0.w += p * BFHI(vw.y);
    a1.x += p * BFLO(vw.z); a1.y += p * BFHI(vw.z);
    a1.z += p * BFLO(vw.w); a1.w += p * BFHI(vw.w);
    kw = kw2; vw = vw2; j = jn;
  }
#pragma unroll
  for (int mask = 16; mask <= 32; mask <<= 1) {
    float m2 = __shfl_xor(m, mask);
    float l2 = __shfl_xor(l, mask);
    float b0x = __shfl_xor(a0.x, mask), b0y = __shfl_xor(a0.y, mask);
    float b0z = __shfl_xor(a0.z, mask), b0w = __shfl_xor(a0.w, mask);
    float b1x = __shfl_xor(a1.x, mask), b1y = __shfl_xor(a1.y, mask);
    float b1z = __shfl_xor(a1.z, mask), b1w = __shfl_xor(a1.w, mask);
    float mn = fmaxf(fmaxf(m, m2), -1e30f);
    float ea = __expf(m - mn), eb = __expf(m2 - mn);
    l = l * ea + l2 * eb;
    a0.x = a0.x * ea + b0x * eb; a0.y = a0.y * ea + b0y * eb;
    a0.z = a0.z * ea + b0z * eb; a0.w = a0.w * ea + b0w * eb;
    a1.x = a1.x * ea + b1x * eb; a1.y = a1.y * ea + b1y * eb;
    a1.z = a1.z * ea + b1z * eb; a1.w = a1.w * ea + b1w * eb;
    m = fmaxf(m, m2);
  }
  if (g == 0) {
    float inv = 1.f / fmaxf(l, 1e-16f);
    uint4 w = make_uint4(packbf(a0.x * inv, a0.y * inv), packbf(a0.z * inv, a0.w * inv),
                         packbf(a1.x * inv, a1.y * inv), packbf(a1.z * inv, a1.w * inv));
    *(uint4*)(ho16 + (size_t)n * HF + fl * 8) = w;
  }
}

// z[m][0:128] = segment_min(ho16[node]) (0 if empty); z[m][128:256] = xe[m]
__global__ __launch_bounds__(256) void seg_min_z(const unsigned short* __restrict__ ho16,
                                                 const int* __restrict__ off_e,
                                                 const unsigned short* __restrict__ by_h,
                                                 const float* __restrict__ xe,
                                                 float* __restrict__ z, int M) {
  int m = (blockIdx.x * blockDim.x + threadIdx.x) >> 6;
  if (m >= M) return;
  int lane = threadIdx.x & 63;
  int g = lane >> 4;
  int fl = lane & 15;
  int s = off_e[m], e1 = off_e[m + 1];
  float4 a0 = make_float4(FLT_MAX, FLT_MAX, FLT_MAX, FLT_MAX), a1 = a0;
  for (int j = s + g; j < e1; j += 4) {
    int vi = by_h[j];
    uint4 hw = *(const uint4*)(ho16 + (size_t)vi * HF + fl * 8);
    a0.x = fminf(a0.x, BFLO(hw.x)); a0.y = fminf(a0.y, BFHI(hw.x));
    a0.z = fminf(a0.z, BFLO(hw.y)); a0.w = fminf(a0.w, BFHI(hw.y));
    a1.x = fminf(a1.x, BFLO(hw.z)); a1.y = fminf(a1.y, BFHI(hw.z));
    a1.z = fminf(a1.z, BFLO(hw.w)); a1.w = fminf(a1.w, BFHI(hw.w));
  }
#pragma unroll
  for (int mask = 16; mask <= 32; mask <<= 1) {
    a0.x = fminf(a0.x, __shfl_xor(a0.x, mask)); a0.y = fminf(a0.y, __shfl_xor(a0.y, mask));
    a0.z = fminf(a0.z, __shfl_xor(a0.z, mask)); a0.w = fminf(a0.w, __shfl_xor(a0.w, mask));
    a1.x = fminf(a1.x, __shfl_xor(a1.x, mask)); a1.y = fminf(a1.y, __shfl_xor(a1.y, mask));
    a1.z = fminf(a1.z, __shfl_xor(a1.z, mask)); a1.w = fminf(a1.w, __shfl_xor(a1.w, mask));
  }
  if (g == 0) {
    bool nz = (e1 > s);
    float* op = z + (size_t)m * 256 + fl * 8;
    *(float4*)op = nz ? a0 : make_float4(0.f, 0.f, 0.f, 0.f);
    *(float4*)(op + 4) = nz ? a1 : make_float4(0.f, 0.f, 0.f, 0.f);
  } else if (g == 1) {
    const float* xp = xe + (size_t)m * HF + fl * 8;
    float* op = z + (size_t)m * 256 + 128 + fl * 8;
    *(float4*)op = *(const float4*)xp;
    *(float4*)(op + 4) = *(const float4*)(xp + 4);
  }
}

// ---------------- GraphNorm stats + scale: 1024-thr blocks, LDS row-lane reduce, last-block ticket ----------------

__global__ __launch_bounds__(1024) void colstats_mk(const float* __restrict__ z, int rows, int C,
                                                    float* __restrict__ stats,
                                                    const float* __restrict__ w,
                                                    const float* __restrict__ b,
                                                    const float* __restrict__ a, float invrows,
                                                    float* __restrict__ sc, float* __restrict__ sh,
                                                    int* __restrict__ done) {
  int tid = threadIdx.x;
  int RL = 1024 / C;
  int col = tid & (C - 1);
  int ro = tid / C;
  float s1 = 0.f, s2 = 0.f;
  for (int r = blockIdx.x * RL + ro; r < rows; r += gridDim.x * RL) {
    float v = z[(size_t)r * C + col];
    s1 += v;
    s2 += v * v;
  }
  __shared__ float l1[1024], l2[1024];
  l1[tid] = s1;
  l2[tid] = s2;
  __syncthreads();
  for (int off = 512; off >= C; off >>= 1) {
    if (tid < off) { l1[tid] += l1[tid + off]; l2[tid] += l2[tid + off]; }
    __syncthreads();
  }
  if (tid < C) {
    atomicAdd(&stats[tid], l1[tid]);
    atomicAdd(&stats[C + tid], l2[tid]);
  }
  __threadfence();
  __shared__ int lastBlk;
  __syncthreads();
  if (tid == 0) lastBlk = (atomicAdd(done, 1) == (int)gridDim.x - 1);
  __syncthreads();
  if (lastBlk) {
    __threadfence();
    if (tid < C) {
      float mu = stats[tid] * invrows;
      float ex2 = stats[C + tid] * invrows;
      float av = a[tid];
      float var = ex2 - 2.f * av * mu * mu + av * av * mu * mu;
      float s = w[tid] * rsqrtf(var + 1e-5f);
      sc[tid] = s;
      sh[tid] = b[tid] - av * mu * s;
    }
  }
}

// ---------------- launch ----------------

extern "C" void kernel_launch(void* const* d_in, const int* in_sizes, int n_in,
                              void* d_out, int out_size, void* d_ws, size_t ws_size,
                              hipStream_t stream) {
  const float* x        = (const float*)d_in[0];
  const float* x_e      = (const float*)d_in[2];
  const int*   node_idx = (const int*)d_in[3];
  const int*   hedge_idx= (const int*)d_in[4];
  const float* her_W1   = (const float*)d_in[5];
  const float* her_b1   = (const float*)d_in[6];
  const float* her_W2   = (const float*)d_in[7];
  const float* her_b2   = (const float*)d_in[8];
  const float* sr_W1    = (const float*)d_in[9];
  const float* sr_b1    = (const float*)d_in[10];
  const float* sr_W2    = (const float*)d_in[11];
  const float* sr_b2    = (const float*)d_in[12];
  const float* att_Wq   = (const float*)d_in[13];
  const float* att_Wk   = (const float*)d_in[14];
  const float* att_Wv   = (const float*)d_in[15];
  const float* ef_W     = (const float*)d_in[16];
  const float* ef_b     = (const float*)d_in[17];
  const float* gn1_w    = (const float*)d_in[18];
  const float* gn1_b    = (const float*)d_in[19];
  const float* gn1_a    = (const float*)d_in[20];
  const float* gn2_w    = (const float*)d_in[21];
  const float* gn2_b    = (const float*)d_in[22];
  const float* gn2_a    = (const float*)d_in[23];
  const float* cls_W1   = (const float*)d_in[24];
  const float* cls_b1   = (const float*)d_in[25];
  const float* cls_W2   = (const float*)d_in[26];
  const float* cls_b2   = (const float*)d_in[27];

  const int N = in_sizes[0] / HF;
  const int M = in_sizes[2] / HF;
  const int E = in_sizes[3];
  const int NVR = idiv(N, VRANGE);  // node range count (2 for N=50000)

  // ---- workspace layout ----
  char* wp = (char*)d_ws;
  float* stats1 = (float*)wp; wp += 512 * 4;
  float* stats2 = (float*)wp; wp += 256 * 4;
  int* done1 = (int*)wp; wp += 64;
  int* done2 = (int*)wp; wp += 64;
  size_t zero_bytes = (size_t)(wp - (char*)d_ws);
  int* cnt_e = (int*)wp; wp += (size_t)M * 4;
  int* cnt_v = (int*)wp; wp += (size_t)N * 4;
  int* off_e = (int*)wp; wp += (size_t)(M + 1) * 4;
  int* off_v = (int*)wp; wp += (size_t)(N + 1) * 4;
  unsigned short* by_h = (unsigned short*)wp; wp += ((size_t)E * 2 + 3) & ~(size_t)3;
  unsigned short* by_v = (unsigned short*)wp; wp += ((size_t)E * 2 + 3) & ~(size_t)3;
  int* part_e = (int*)wp; wp += 257 * 4;
  int* part_v = (int*)wp; wp += 257 * 4;
  float* sc1 = (float*)wp; wp += 256 * 4;
  float* sh1 = (float*)wp; wp += 256 * 4;
  float* sc2 = (float*)wp; wp += 128 * 4;
  float* sh2 = (float*)wp; wp += 128 * 4;
  wp = (char*)(((uintptr_t)wp + 255) & ~(uintptr_t)255);
  float* wqt  = (float*)wp; wp += (size_t)128 * 128 * 4;   // Wq^T * scale
  float* wcat = (float*)wp; wp += (size_t)128 * 256 * 4;   // [Wqk | Wv]
  float* h   = (float*)wp; wp += (size_t)N * HF * 4;       // sr1 out, += m_v, sr2 in; later c1
  float* h2  = (float*)wp; wp += (size_t)N * HF * 4;       // sr2 out = q; later z [M,256]
  float* xe  = (float*)wp; wp += (size_t)M * HF * 4;
  float* kvf = (float*)wp; wp += (size_t)M * 256 * 4;      // t1 fp32 alias / kv bf16
  float* z2  = (float*)wp; wp += (size_t)M * HF * 4;
  unsigned short* h16   = (unsigned short*)wp; wp += (size_t)N * HF * 2;  // sr1 bf16 shadow
  unsigned short* ho16  = (unsigned short*)wp; wp += (size_t)N * HF * 2;  // att out bf16
  unsigned short* m_e16 = (unsigned short*)wp; wp += (size_t)M * HF * 2;

  unsigned short* kv = (unsigned short*)kvf;   // [M][256] bf16
  float* t1  = kvf;                // her hidden [M,128] fp32 (dead before kv written)
  float* z   = h2;                 // [M,256] (h2 dead as q after att_fused)
  float* c1  = h;                  // [M,128] (h dead after sr2)

  // Histogram matrices alias h (dead until sr1): NB*M + NVR*NB*VPACK ints = 17.9MB < 25.6MB
  int* HE = (int*)h;
  int* HV = HE + (size_t)NB_CSR * M;

  hipMemsetAsync(d_ws, 0, zero_bytes, stream);

  // ---- CSR build: counting sort, zero device-scope atomics ----
  csr_hist<<<dim3(NB_CSR, 1 + NVR), 512, 0, stream>>>(node_idx, hedge_idx, E, M, HE, HV);
  csr_colscan<<<idiv(M + NVR * VPACK, 256), 256, 0, stream>>>(HE, HV, M, N, NVR, cnt_e, cnt_v);
  int nbE = idiv(M, SCAN_CHUNK);
  int nbV = idiv(N, SCAN_CHUNK);
  scanA2<<<nbE + nbV, 256, 0, stream>>>(cnt_e, M, nbE, part_e, cnt_v, N, part_v);
  scanB2<<<2, 256, 0, stream>>>(part_e, nbE, part_v, nbV);
  scanC2<<<nbE + nbV, 256, 0, stream>>>(cnt_e, M, nbE, part_e, off_e, cnt_v, N, nbV, part_v, off_v);
  csr_scatter<<<dim3(NB_CSR, 1 + NVR), 512, 0, stream>>>(node_idx, hedge_idx, E, M, HE, HV,
                                                         off_e, off_v, by_h, by_v);

  // wqt = Wq^T*scale, wcat right = Wv; then wcat left = Wk @ wqt
  prep_att<<<64, 256, 0, stream>>>(att_Wq, att_Wv, wqt, wcat);
  gemm64<<<dim3(2, 2), 256, 0, stream>>>(att_Wk, wqt, nullptr, wcat, 128, 128, 128, 0,
                                         nullptr, nullptr, 0, 256, 0, nullptr);

  dim3 blk(256);
  // her MLP: xe
  gemm64<<<dim3(idiv(M, 64), 2), blk, 0, stream>>>(x_e, her_W1, her_b1, t1, M, HF, HF, 1,
                                                   nullptr, nullptr, 0, HF, 0, nullptr);
  gemm64<<<dim3(idiv(M, 64), 2), blk, 0, stream>>>(t1, her_W2, her_b2, xe, M, HF, HF, 0,
                                                   nullptr, nullptr, 0, HF, 0, nullptr);
  // sr layer1 (fp32 + bf16 shadow), 64x64 tiles -> 1564 blocks (overwrites HE/HV)
  gemm64<<<dim3(idiv(N, 64), 2), blk, 0, stream>>>(x, sr_W1, sr_b1, h, N, HF, HF, 1,
                                                   nullptr, nullptr, 0, HF, 0, h16);
  // message passing means (bf16 gathers)
  seg_mean_e<<<idiv(M * 64, 256), blk, 0, stream>>>(h16, off_e, by_h, m_e16, M);
  seg_mean_v_add<<<idiv(N * 64, 256), blk, 0, stream>>>(h, m_e16, off_v, by_v, N);
  // sr layer2 -> h2 (doubles as q)
  gemm64<<<dim3(idiv(N, 64), 2), blk, 0, stream>>>(h, sr_W2, sr_b2, h2, N, HF, HF, 1,
                                                   nullptr, nullptr, 0, HF, 0, nullptr);
  // kv projection: [xe@Wqk | xe@Wv] in bf16
  gemm64<<<dim3(idiv(M, 64), 4), blk, 0, stream>>>(xe, wcat, nullptr, (float*)kv, M, HF, 256, 0,
                                                   nullptr, nullptr, 0, 256, 1, nullptr);
  // fused attention (q = h2)
  att_fused<<<idiv(N * 64, 256), blk, 0, stream>>>(h2, kv, off_v, by_v, ho16, N);
  // min aggregation + concat (z overwrites h2)
  seg_min_z<<<idiv(M * 64, 256), blk, 0, stream>>>(ho16, off_e, by_h, xe, z, M);
  // gn1 stats+scale (fused, 1024-thr) -> ef linear(+act) -> gn2 stats+scale
  colstats_mk<<<128, 1024, 0, stream>>>(z, M, 256, stats1, gn1_w, gn1_b, gn1_a,
                                        1.f / (float)M, sc1, sh1, done1);
  gemm64<<<dim3(idiv(M, 64), 2), blk, 0, stream>>>(z, ef_W, ef_b, z2, M, 2 * HF, HF, 1,
                                                   sc1, sh1, 0, HF, 0, nullptr);
  colstats_mk<<<128, 1024, 0, stream>>>(z2, M, 128, stats2, gn2_w, gn2_b, gn2_a,
                                        1.f / (float)M, sc2, sh2, done2);
  // classifier
  gemm64<<<dim3(idiv(M, 64), 2), blk, 0, stream>>>(z2, cls_W1, cls_b1, c1, M, HF, HF, 1,
                                                   sc2, sh2, 1, HF, 0, nullptr);
  gemm64<<<dim3(idiv(M, 64), 1), blk, 0, stream>>>(c1, cls_W2, cls_b2, (float*)d_out, M, HF, 64, 0,
                                                   nullptr, nullptr, 0, 64, 0, nullptr);
}

// Round 5
// 415.556 us; speedup vs baseline: 1.6077x; 1.0529x over previous
//
#include <hip/hip_runtime.h>
#include <float.h>
#include <math.h>

#define HF 128
#define SCAN_CHUNK 4096  // 256 threads x 16 elems
#define NB_CSR 128       // chunks for counting-sort CSR build
#define VPACK 12500      // packed (2-per-int) node bins per range: 25000 nodes / range
#define VRANGE (2 * VPACK)
#define ST_PAD 32        // stats stride (floats): 1 counter per 128B line (atomic chain fix)
#define CS_GRID 64       // colstats grid: 64 atomics/line chain depth

static inline int idiv(int a, int b) { return (a + b - 1) / b; }

__device__ inline unsigned short f2bf(float x) {  // RNE float->bf16
  unsigned u = __float_as_uint(x);
  return (unsigned short)((u + 0x7fffu + ((u >> 16) & 1u)) >> 16);
}
__device__ inline unsigned packbf(float a, float b) {
  return (unsigned)f2bf(a) | ((unsigned)f2bf(b) << 16);
}
#define BFLO(w) __uint_as_float((w) << 16)
#define BFHI(w) __uint_as_float((w) & 0xffff0000u)

// ---------------- CSR build: LDS-histogram counting sort (ZERO device-scope atomics) ----------------
// Round-2 evidence: 1.2M global atomics = 24.7 G/s RMW wall (48.5us, invariant to
// occupancy/batching). Replaced by per-chunk LDS histograms + column scan + scatter.

__global__ __launch_bounds__(512) void csr_hist(const int* __restrict__ nidx,
                                                const int* __restrict__ hidx,
                                                int E, int M,
                                                int* __restrict__ HE,
                                                int* __restrict__ HV) {
  __shared__ int bins[VPACK];
  int b = blockIdx.x, y = blockIdx.y, tid = threadIdx.x;
  int chunk = (E + NB_CSR - 1) / NB_CSR;
  int e0 = b * chunk;
  int e1 = e0 + chunk; if (e1 > E) e1 = E;
  if (y == 0) {
    for (int s = tid; s < M; s += 512) bins[s] = 0;
    __syncthreads();
    for (int e = e0 + tid; e < e1; e += 512) atomicAdd(&bins[hidx[e]], 1);
    __syncthreads();
    for (int s = tid; s < M; s += 512) HE[(size_t)b * M + s] = bins[s];
  } else {
    int R = (y - 1) * VRANGE;
    int* HVr = HV + ((size_t)(y - 1) * NB_CSR + b) * VPACK;
    for (int q = tid; q < VPACK; q += 512) bins[q] = 0;
    __syncthreads();
    for (int e = e0 + tid; e < e1; e += 512) {
      int v = nidx[e] - R;
      if ((unsigned)v < (unsigned)VRANGE) atomicAdd(&bins[v >> 1], (v & 1) ? 0x10000 : 1);
    }
    __syncthreads();
    for (int q = tid; q < VPACK; q += 512) HVr[q] = bins[q];
  }
}

// Per-segment exclusive scan over the NB_CSR chunks (in place) + dense counts.
__global__ __launch_bounds__(256) void csr_colscan(int* __restrict__ HE,
                                                   int* __restrict__ HV,
                                                   int M, int N, int NVR,
                                                   int* __restrict__ cnt_e,
                                                   int* __restrict__ cnt_v) {
  int col = blockIdx.x * 256 + threadIdx.x;
  if (col < M) {
    int run = 0;
    for (int b = 0; b < NB_CSR; ++b) {
      size_t i = (size_t)b * M + col;
      int t = HE[i]; HE[i] = run; run += t;
    }
    cnt_e[col] = run;
  } else if (col < M + NVR * VPACK) {
    int c = col - M;
    int r = c / VPACK, q = c - r * VPACK;
    int* HVr = HV + (size_t)r * NB_CSR * VPACK;
    int run = 0;
    for (int b = 0; b < NB_CSR; ++b) {
      size_t i = (size_t)b * VPACK + q;
      int t = HVr[i]; HVr[i] = run; run += t;
    }
    int node = r * VRANGE + 2 * q;
    if (node < N) cnt_v[node] = run & 0xffff;
    if (node + 1 < N) cnt_v[node + 1] = run >> 16;
  }
}

// Scatter: preload LDS bins with global base (off + chunk-exclusive), LDS-atomic rank.
__global__ __launch_bounds__(512) void csr_scatter(const int* __restrict__ nidx,
                                                   const int* __restrict__ hidx,
                                                   int E, int M,
                                                   const int* __restrict__ HE,
                                                   const int* __restrict__ HV,
                                                   const int* __restrict__ off_e,
                                                   const int* __restrict__ off_v,
                                                   unsigned short* __restrict__ by_h,
                                                   unsigned short* __restrict__ by_v) {
  __shared__ int bins[VPACK];
  int b = blockIdx.x, y = blockIdx.y, tid = threadIdx.x;
  int chunk = (E + NB_CSR - 1) / NB_CSR;
  int e0 = b * chunk;
  int e1 = e0 + chunk; if (e1 > E) e1 = E;
  if (y == 0) {
    for (int s = tid; s < M; s += 512) bins[s] = off_e[s] + HE[(size_t)b * M + s];
    __syncthreads();
    for (int e = e0 + tid; e < e1; e += 512) {
      int pos = atomicAdd(&bins[hidx[e]], 1);
      by_h[pos] = (unsigned short)nidx[e];
    }
  } else {
    int R = (y - 1) * VRANGE;
    const int* HVr = HV + ((size_t)(y - 1) * NB_CSR + b) * VPACK;
    for (int q = tid; q < VPACK; q += 512) bins[q] = HVr[q];
    __syncthreads();
    for (int e = e0 + tid; e < e1; e += 512) {
      int v = nidx[e];
      int vr = v - R;
      if ((unsigned)vr < (unsigned)VRANGE) {
        int old = atomicAdd(&bins[vr >> 1], (vr & 1) ? 0x10000 : 1);
        int rank = (vr & 1) ? (old >> 16) : (old & 0xffff);
        by_v[off_v[v] + rank] = (unsigned short)hidx[e];
      }
    }
  }
}

// ---- fused 3-phase multi-block exclusive scan over both dense count arrays ----

__global__ __launch_bounds__(256) void scanA2(const int* __restrict__ inE, int nE, int nbE,
                                              int* __restrict__ partE,
                                              const int* __restrict__ inV, int nV,
                                              int* __restrict__ partV) {
  const int* in; int n, b; int* partials;
  if ((int)blockIdx.x < nbE) { in = inE; n = nE; b = blockIdx.x; partials = partE; }
  else { in = inV; n = nV; b = blockIdx.x - nbE; partials = partV; }
  __shared__ int lds[256];
  int tid = threadIdx.x;
  int base = b * SCAN_CHUNK + tid * 16;
  int s = 0;
#pragma unroll
  for (int i = 0; i < 16; ++i) {
    int idx = base + i;
    if (idx < n) s += in[idx];
  }
  lds[tid] = s;
  __syncthreads();
  for (int off = 128; off; off >>= 1) {
    if (tid < off) lds[tid] += lds[tid + off];
    __syncthreads();
  }
  if (tid == 0) partials[b] = lds[0];
}

__global__ __launch_bounds__(256) void scanB2(int* __restrict__ partE, int nbE,
                                              int* __restrict__ partV, int nbV) {
  int* partials = (blockIdx.x == 0) ? partE : partV;
  int nb = (blockIdx.x == 0) ? nbE : nbV;
  __shared__ int lds[256];
  int tid = threadIdx.x;
  int v = (tid < nb) ? partials[tid] : 0;
  lds[tid] = v;
  __syncthreads();
  for (int off = 1; off < 256; off <<= 1) {
    int add = (tid >= off) ? lds[tid - off] : 0;
    __syncthreads();
    lds[tid] += add;
    __syncthreads();
  }
  if (tid < nb) partials[tid] = lds[tid] - v;  // exclusive
  if (tid == nb - 1) partials[nb] = lds[tid];  // total
}

__global__ __launch_bounds__(256) void scanC2(const int* __restrict__ inE, int nE, int nbE,
                                              const int* __restrict__ partE, int* __restrict__ outE,
                                              const int* __restrict__ inV, int nV, int nbV,
                                              const int* __restrict__ partV, int* __restrict__ outV) {
  const int* in; const int* partials; int* out; int n, b, nb;
  if ((int)blockIdx.x < nbE) { in = inE; n = nE; b = blockIdx.x; partials = partE; out = outE; nb = nbE; }
  else { in = inV; n = nV; b = blockIdx.x - nbE; partials = partV; out = outV; nb = nbV; }
  __shared__ int lds[256];
  int tid = threadIdx.x;
  int base = b * SCAN_CHUNK + tid * 16;
  int vals[16];
  int s = 0;
#pragma unroll
  for (int i = 0; i < 16; ++i) {
    int idx = base + i;
    int v = (idx < n) ? in[idx] : 0;
    vals[i] = s;
    s += v;
  }
  lds[tid] = s;
  __syncthreads();
  int own = s;
  for (int off = 1; off < 256; off <<= 1) {
    int add = (tid >= off) ? lds[tid - off] : 0;
    __syncthreads();
    lds[tid] += add;
    __syncthreads();
  }
  int excl = lds[tid] - own + partials[b];
#pragma unroll
  for (int i = 0; i < 16; ++i) {
    int idx = base + i;
    if (idx < n) out[idx] = excl + vals[i];
  }
  if (b == 0 && tid == 0) out[n] = partials[nb];
}

// wqt = Wq^T * (1/sqrt(128)) [score scale folded]; wcat[:,128:256] = Wv.
__global__ void prep_att(const float* __restrict__ Wq, const float* __restrict__ Wv,
                         float* __restrict__ wqt, float* __restrict__ wcat) {
  int i = blockIdx.x * blockDim.x + threadIdx.x;  // 128*128
  if (i >= 128 * 128) return;
  int r = i >> 7, c = i & 127;
  wqt[c * 128 + r] = Wq[i] * 0.08838834764831845f;
  wcat[r * 256 + 128 + c] = Wv[i];
}

// ---------------- GEMM: 64x64 tile, 4x4 micro; fused input-norm / act / bf16-out / fp32+bf16 shadow ----------------

__global__ __launch_bounds__(256) void gemm64(const float* __restrict__ A,
                                              const float* __restrict__ W,
                                              const float* __restrict__ bias,
                                              float* __restrict__ out,
                                              int R, int K, int C, int act,
                                              const float* __restrict__ insc,
                                              const float* __restrict__ insh, int inact,
                                              int ldo, int obf16,
                                              unsigned short* __restrict__ out16) {
  __shared__ __align__(16) float As[64][20];
  __shared__ __align__(16) float Bs[16][64];
  int tid = threadIdx.x;
  int tx = tid & 15;
  int ty = tid >> 4;
  int rowBase = blockIdx.x * 64;
  int colBase = blockIdx.y * 64;

  float acc[4][4] = {};

  for (int k0 = 0; k0 < K; k0 += 16) {
    {
      int arow = tid >> 2, ac = (tid & 3) * 4;
      int gr = rowBase + arow;
      float4 av = make_float4(0.f, 0.f, 0.f, 0.f);
      if (gr < R) av = *(const float4*)(A + (size_t)gr * K + k0 + ac);
      if (insc) {
        float vv[4] = {av.x, av.y, av.z, av.w};
#pragma unroll
        for (int i = 0; i < 4; ++i) {
          float s = insc[k0 + ac + i], sh = insh[k0 + ac + i];
          float v = vv[i] * s + sh;
          if (inact) v = v > 0.f ? v : 0.01f * v;
          vv[i] = v;
        }
        av = make_float4(vv[0], vv[1], vv[2], vv[3]);
      }
      *(float4*)&As[arow][ac] = av;
    }
    {
      int bk = tid >> 4, bc = (tid & 15) * 4;
      *(float4*)&Bs[bk][bc] = *(const float4*)(W + (size_t)(k0 + bk) * C + colBase + bc);
    }
    __syncthreads();
#pragma unroll
    for (int kg = 0; kg < 16; kg += 4) {
      float af[4][4], bf[4][4];
#pragma unroll
      for (int i = 0; i < 4; ++i)
        *(float4*)af[i] = *(const float4*)&As[ty * 4 + i][kg];
#pragma unroll
      for (int kk = 0; kk < 4; ++kk)
        *(float4*)bf[kk] = *(const float4*)&Bs[kg + kk][tx * 4];
#pragma unroll
      for (int kk = 0; kk < 4; ++kk)
#pragma unroll
        for (int i = 0; i < 4; ++i)
#pragma unroll
          for (int j = 0; j < 4; ++j)
            acc[i][j] = fmaf(af[i][kk], bf[kk][j], acc[i][j]);
    }
    __syncthreads();
  }

#pragma unroll
  for (int i = 0; i < 4; ++i) {
    int r = rowBase + ty * 4 + i;
    if (r >= R) continue;
    float vals[4];
#pragma unroll
    for (int j = 0; j < 4; ++j) {
      float v = acc[i][j];
      if (bias) v += bias[colBase + tx * 4 + j];
      if (act) v = v > 0.f ? v : 0.01f * v;
      vals[j] = v;
    }
    if (obf16) {
      unsigned short* o16 = (unsigned short*)out;
      ushort4 w = make_ushort4(f2bf(vals[0]), f2bf(vals[1]), f2bf(vals[2]), f2bf(vals[3]));
      *(ushort4*)(o16 + (size_t)r * ldo + colBase + tx * 4) = w;
    } else {
      *(float4*)(out + (size_t)r * ldo + colBase + tx * 4) =
          make_float4(vals[0], vals[1], vals[2], vals[3]);
      if (out16) {
        uint2 w = make_uint2(packbf(vals[0], vals[1]), packbf(vals[2], vals[3]));
        *(uint2*)(out16 + (size_t)r * ldo + colBase + tx * 4) = w;
      }
    }
  }
}

// ---------------- segment ops: one wave per segment; 4 x 16-lane groups, 8 feats/lane ----------------

__global__ __launch_bounds__(256) void seg_mean_e(const unsigned short* __restrict__ h16,
                                                  const int* __restrict__ off_e,
                                                  const unsigned short* __restrict__ by_h,
                                                  unsigned short* __restrict__ m_e16, int M) {
  int m = (blockIdx.x * blockDim.x + threadIdx.x) >> 6;
  if (m >= M) return;
  int lane = threadIdx.x & 63;
  int g = lane >> 4;
  int fl = lane & 15;
  int s = off_e[m], e1 = off_e[m + 1];
  float4 a0 = make_float4(0.f, 0.f, 0.f, 0.f), a1 = a0;
  for (int j = s + g; j < e1; j += 4) {
    int vi = by_h[j];
    uint4 hw = *(const uint4*)(h16 + (size_t)vi * HF + fl * 8);
    a0.x += BFLO(hw.x); a0.y += BFHI(hw.x); a0.z += BFLO(hw.y); a0.w += BFHI(hw.y);
    a1.x += BFLO(hw.z); a1.y += BFHI(hw.z); a1.z += BFLO(hw.w); a1.w += BFHI(hw.w);
  }
#pragma unroll
  for (int mask = 16; mask <= 32; mask <<= 1) {
    a0.x += __shfl_xor(a0.x, mask); a0.y += __shfl_xor(a0.y, mask);
    a0.z += __shfl_xor(a0.z, mask); a0.w += __shfl_xor(a0.w, mask);
    a1.x += __shfl_xor(a1.x, mask); a1.y += __shfl_xor(a1.y, mask);
    a1.z += __shfl_xor(a1.z, mask); a1.w += __shfl_xor(a1.w, mask);
  }
  if (g == 0) {
    int cnt = e1 - s;
    float r = 1.f / (float)(cnt > 0 ? cnt : 1);
    uint4 w = make_uint4(packbf(a0.x * r, a0.y * r), packbf(a0.z * r, a0.w * r),
                         packbf(a1.x * r, a1.y * r), packbf(a1.z * r, a1.w * r));
    *(uint4*)(m_e16 + (size_t)m * HF + fl * 8) = w;
  }
}

__global__ __launch_bounds__(256) void seg_mean_v_add(float* __restrict__ h,
                                                      const unsigned short* __restrict__ m_e16,
                                                      const int* __restrict__ off_v,
                                                      const unsigned short* __restrict__ by_v,
                                                      int N) {
  int n = (blockIdx.x * blockDim.x + threadIdx.x) >> 6;
  if (n >= N) return;
  int lane = threadIdx.x & 63;
  int g = lane >> 4;
  int fl = lane & 15;
  int s = off_v[n], e1 = off_v[n + 1];
  float4 a0 = make_float4(0.f, 0.f, 0.f, 0.f), a1 = a0;
  for (int j = s + g; j < e1; j += 4) {
    int he = by_v[j];
    uint4 hw = *(const uint4*)(m_e16 + (size_t)he * HF + fl * 8);
    a0.x += BFLO(hw.x); a0.y += BFHI(hw.x); a0.z += BFLO(hw.y); a0.w += BFHI(hw.y);
    a1.x += BFLO(hw.z); a1.y += BFHI(hw.z); a1.z += BFLO(hw.w); a1.w += BFHI(hw.w);
  }
#pragma unroll
  for (int mask = 16; mask <= 32; mask <<= 1) {
    a0.x += __shfl_xor(a0.x, mask); a0.y += __shfl_xor(a0.y, mask);
    a0.z += __shfl_xor(a0.z, mask); a0.w += __shfl_xor(a0.w, mask);
    a1.x += __shfl_xor(a1.x, mask); a1.y += __shfl_xor(a1.y, mask);
    a1.z += __shfl_xor(a1.z, mask); a1.w += __shfl_xor(a1.w, mask);
  }
  if (g == 0) {
    int cnt = e1 - s;
    float r = 1.f / (float)(cnt > 0 ? cnt : 1);
    float* hp = h + (size_t)n * HF + fl * 8;
    float4 h0 = *(const float4*)hp;
    float4 h1 = *(const float4*)(hp + 4);
    *(float4*)hp = make_float4(h0.x + a0.x * r, h0.y + a0.y * r, h0.z + a0.z * r, h0.w + a0.w * r);
    *(float4*)(hp + 4) = make_float4(h1.x + a1.x * r, h1.y + a1.y * r, h1.z + a1.z * r, h1.w + a1.w * r);
  }
}

// Fused GAT attention: one wave per node; q = h2 (fp32, score scale pre-folded into Wqk);
// kv bf16 [M][256]; software prefetch + defer-max rescale (THR=8).
__global__ __launch_bounds__(256) void att_fused(const float* __restrict__ q,
                                                 const unsigned short* __restrict__ kv,
                                                 const int* __restrict__ off_v,
                                                 const unsigned short* __restrict__ by_v,
                                                 unsigned short* __restrict__ ho16, int N) {
  int n = (blockIdx.x * blockDim.x + threadIdx.x) >> 6;
  if (n >= N) return;
  int lane = threadIdx.x & 63;
  int g = lane >> 4;
  int fl = lane & 15;
  int s0 = off_v[n], s1 = off_v[n + 1];
  const float* qp = q + (size_t)n * HF + fl * 8;
  float4 q0 = *(const float4*)qp;
  float4 q1 = *(const float4*)(qp + 4);
  float m = -INFINITY, l = 0.f;
  float4 a0 = make_float4(0.f, 0.f, 0.f, 0.f), a1 = a0;
  int j = s0 + g;
  uint4 kw = make_uint4(0, 0, 0, 0), vw = kw;
  if (j < s1) {
    const unsigned short* base = kv + (size_t)by_v[j] * 256 + fl * 8;
    kw = *(const uint4*)base;
    vw = *(const uint4*)(base + 128);
  }
  while (j < s1) {
    int jn = j + 4;
    uint4 kw2 = make_uint4(0, 0, 0, 0), vw2 = kw2;
    if (jn < s1) {
      const unsigned short* b2 = kv + (size_t)by_v[jn] * 256 + fl * 8;
      kw2 = *(const uint4*)b2;
      vw2 = *(const uint4*)(b2 + 128);
    }
    float d = q0.x * BFLO(kw.x) + q0.y * BFHI(kw.x) + q0.z * BFLO(kw.y) + q0.w * BFHI(kw.y)
            + q1.x * BFLO(kw.z) + q1.y * BFHI(kw.z) + q1.z * BFLO(kw.w) + q1.w * BFHI(kw.w);
    d += __shfl_xor(d, 1);
    d += __shfl_xor(d, 2);
    d += __shfl_xor(d, 4);
    d += __shfl_xor(d, 8);
    d = d > 0.f ? d : 0.2f * d;   // scale already folded into Wqk
    if (d > m + 8.f) {
      float sc = __expf(m - d);   // first edge: exp(-inf)=0 zeroes l,a
      l *= sc;
      a0.x *= sc; a0.y *= sc; a0.z *= sc; a0.w *= sc;
      a1.x *= sc; a1.y *= sc; a1.z *= sc; a1.w *= sc;
      m = d;
    }
    float p = __expf(d - m);
    l += p;
    a0.x += p * BFLO(vw.x); a0.y += p * BFHI(vw.x);
    a0.z += p * BFLO(vw.y); a0.w += p * BFHI(vw.y);
    a1.x += p * BFLO(vw.z); a1.y += p * BFHI(vw.z);
    a1.z += p * BFLO(vw.w); a1.w += p * BFHI(vw.w);
    kw = kw2; vw = vw2; j = jn;
  }
#pragma unroll
  for (int mask = 16; mask <= 32; mask <<= 1) {
    float m2 = __shfl_xor(m, mask);
    float l2 = __shfl_xor(l, mask);
    float b0x = __shfl_xor(a0.x, mask), b0y = __shfl_xor(a0.y, mask);
    float b0z = __shfl_xor(a0.z, mask), b0w = __shfl_xor(a0.w, mask);
    float b1x = __shfl_xor(a1.x, mask), b1y = __shfl_xor(a1.y, mask);
    float b1z = __shfl_xor(a1.z, mask), b1w = __shfl_xor(a1.w, mask);
    float mn = fmaxf(fmaxf(m, m2), -1e30f);
    float ea = __expf(m - mn), eb = __expf(m2 - mn);
    l = l * ea + l2 * eb;
    a0.x = a0.x * ea + b0x * eb; a0.y = a0.y * ea + b0y * eb;
    a0.z = a0.z * ea + b0z * eb; a0.w = a0.w * ea + b0w * eb;
    a1.x = a1.x * ea + b1x * eb; a1.y = a1.y * ea + b1y * eb;
    a1.z = a1.z * ea + b1z * eb; a1.w = a1.w * ea + b1w * eb;
    m = fmaxf(m, m2);
  }
  if (g == 0) {
    float inv = 1.f / fmaxf(l, 1e-16f);
    uint4 w = make_uint4(packbf(a0.x * inv, a0.y * inv), packbf(a0.z * inv, a0.w * inv),
                         packbf(a1.x * inv, a1.y * inv), packbf(a1.z * inv, a1.w * inv));
    *(uint4*)(ho16 + (size_t)n * HF + fl * 8) = w;
  }
}

// z[m][0:128] = segment_min(ho16[node]) (0 if empty); z[m][128:256] = xe[m]
__global__ __launch_bounds__(256) void seg_min_z(const unsigned short* __restrict__ ho16,
                                                 const int* __restrict__ off_e,
                                                 const unsigned short* __restrict__ by_h,
                                                 const float* __restrict__ xe,
                                                 float* __restrict__ z, int M) {
  int m = (blockIdx.x * blockDim.x + threadIdx.x) >> 6;
  if (m >= M) return;
  int lane = threadIdx.x & 63;
  int g = lane >> 4;
  int fl = lane & 15;
  int s = off_e[m], e1 = off_e[m + 1];
  float4 a0 = make_float4(FLT_MAX, FLT_MAX, FLT_MAX, FLT_MAX), a1 = a0;
  for (int j = s + g; j < e1; j += 4) {
    int vi = by_h[j];
    uint4 hw = *(const uint4*)(ho16 + (size_t)vi * HF + fl * 8);
    a0.x = fminf(a0.x, BFLO(hw.x)); a0.y = fminf(a0.y, BFHI(hw.x));
    a0.z = fminf(a0.z, BFLO(hw.y)); a0.w = fminf(a0.w, BFHI(hw.y));
    a1.x = fminf(a1.x, BFLO(hw.z)); a1.y = fminf(a1.y, BFHI(hw.z));
    a1.z = fminf(a1.z, BFLO(hw.w)); a1.w = fminf(a1.w, BFHI(hw.w));
  }
#pragma unroll
  for (int mask = 16; mask <= 32; mask <<= 1) {
    a0.x = fminf(a0.x, __shfl_xor(a0.x, mask)); a0.y = fminf(a0.y, __shfl_xor(a0.y, mask));
    a0.z = fminf(a0.z, __shfl_xor(a0.z, mask)); a0.w = fminf(a0.w, __shfl_xor(a0.w, mask));
    a1.x = fminf(a1.x, __shfl_xor(a1.x, mask)); a1.y = fminf(a1.y, __shfl_xor(a1.y, mask));
    a1.z = fminf(a1.z, __shfl_xor(a1.z, mask)); a1.w = fminf(a1.w, __shfl_xor(a1.w, mask));
  }
  if (g == 0) {
    bool nz = (e1 > s);
    float* op = z + (size_t)m * 256 + fl * 8;
    *(float4*)op = nz ? a0 : make_float4(0.f, 0.f, 0.f, 0.f);
    *(float4*)(op + 4) = nz ? a1 : make_float4(0.f, 0.f, 0.f, 0.f);
  } else if (g == 1) {
    const float* xp = xe + (size_t)m * HF + fl * 8;
    float* op = z + (size_t)m * 256 + 128 + fl * 8;
    *(float4*)op = *(const float4*)xp;
    *(float4*)(op + 4) = *(const float4*)(xp + 4);
  }
}

// ---------------- GraphNorm stats + scale ----------------
// Round-4 evidence: 41.7us at VALU 1%, HBM 130 GB/s — same-line atomic chain wall
// (65536 atomics / 16 lines = 4096/line x ~24cyc = 41us; C=128 case identical).
// Fix: 1 counter per 128B line (ST_PAD) + CS_GRID=64 blocks -> 64 atomics/line.

__global__ __launch_bounds__(1024) void colstats_mk(const float* __restrict__ z, int rows, int C,
                                                    float* __restrict__ stats,
                                                    const float* __restrict__ w,
                                                    const float* __restrict__ b,
                                                    const float* __restrict__ a, float invrows,
                                                    float* __restrict__ sc, float* __restrict__ sh,
                                                    int* __restrict__ done) {
  int tid = threadIdx.x;
  int RL = 1024 / C;
  int col = tid & (C - 1);
  int ro = tid / C;
  float s1 = 0.f, s2 = 0.f;
  for (int r = blockIdx.x * RL + ro; r < rows; r += gridDim.x * RL) {
    float v = z[(size_t)r * C + col];
    s1 += v;
    s2 += v * v;
  }
  __shared__ float l1[1024], l2[1024];
  l1[tid] = s1;
  l2[tid] = s2;
  __syncthreads();
  for (int off = 512; off >= C; off >>= 1) {
    if (tid < off) { l1[tid] += l1[tid + off]; l2[tid] += l2[tid + off]; }
    __syncthreads();
  }
  if (tid < C) {
    atomicAdd(&stats[(size_t)tid * ST_PAD], l1[tid]);
    atomicAdd(&stats[(size_t)(C + tid) * ST_PAD], l2[tid]);
  }
  __threadfence();
  __shared__ int lastBlk;
  __syncthreads();
  if (tid == 0) lastBlk = (atomicAdd(done, 1) == (int)gridDim.x - 1);
  __syncthreads();
  if (lastBlk) {
    __threadfence();
    if (tid < C) {
      float mu = stats[(size_t)tid * ST_PAD] * invrows;
      float ex2 = stats[(size_t)(C + tid) * ST_PAD] * invrows;
      float av = a[tid];
      float var = ex2 - 2.f * av * mu * mu + av * av * mu * mu;
      float s = w[tid] * rsqrtf(var + 1e-5f);
      sc[tid] = s;
      sh[tid] = b[tid] - av * mu * s;
    }
  }
}

// ---------------- launch ----------------

extern "C" void kernel_launch(void* const* d_in, const int* in_sizes, int n_in,
                              void* d_out, int out_size, void* d_ws, size_t ws_size,
                              hipStream_t stream) {
  const float* x        = (const float*)d_in[0];
  const float* x_e      = (const float*)d_in[2];
  const int*   node_idx = (const int*)d_in[3];
  const int*   hedge_idx= (const int*)d_in[4];
  const float* her_W1   = (const float*)d_in[5];
  const float* her_b1   = (const float*)d_in[6];
  const float* her_W2   = (const float*)d_in[7];
  const float* her_b2   = (const float*)d_in[8];
  const float* sr_W1    = (const float*)d_in[9];
  const float* sr_b1    = (const float*)d_in[10];
  const float* sr_W2    = (const float*)d_in[11];
  const float* sr_b2    = (const float*)d_in[12];
  const float* att_Wq   = (const float*)d_in[13];
  const float* att_Wk   = (const float*)d_in[14];
  const float* att_Wv   = (const float*)d_in[15];
  const float* ef_W     = (const float*)d_in[16];
  const float* ef_b     = (const float*)d_in[17];
  const float* gn1_w    = (const float*)d_in[18];
  const float* gn1_b    = (const float*)d_in[19];
  const float* gn1_a    = (const float*)d_in[20];
  const float* gn2_w    = (const float*)d_in[21];
  const float* gn2_b    = (const float*)d_in[22];
  const float* gn2_a    = (const float*)d_in[23];
  const float* cls_W1   = (const float*)d_in[24];
  const float* cls_b1   = (const float*)d_in[25];
  const float* cls_W2   = (const float*)d_in[26];
  const float* cls_b2   = (const float*)d_in[27];

  const int N = in_sizes[0] / HF;
  const int M = in_sizes[2] / HF;
  const int E = in_sizes[3];
  const int NVR = idiv(N, VRANGE);  // node range count (2 for N=50000)

  // ---- workspace layout ----
  char* wp = (char*)d_ws;
  float* stats1 = (float*)wp; wp += (size_t)512 * ST_PAD * 4;
  float* stats2 = (float*)wp; wp += (size_t)256 * ST_PAD * 4;
  int* done1 = (int*)wp; wp += 64;
  int* done2 = (int*)wp; wp += 64;
  size_t zero_bytes = (size_t)(wp - (char*)d_ws);
  int* cnt_e = (int*)wp; wp += (size_t)M * 4;
  int* cnt_v = (int*)wp; wp += (size_t)N * 4;
  int* off_e = (int*)wp; wp += (size_t)(M + 1) * 4;
  int* off_v = (int*)wp; wp += (size_t)(N + 1) * 4;
  unsigned short* by_h = (unsigned short*)wp; wp += ((size_t)E * 2 + 3) & ~(size_t)3;
  unsigned short* by_v = (unsigned short*)wp; wp += ((size_t)E * 2 + 3) & ~(size_t)3;
  int* part_e = (int*)wp; wp += 257 * 4;
  int* part_v = (int*)wp; wp += 257 * 4;
  float* sc1 = (float*)wp; wp += 256 * 4;
  float* sh1 = (float*)wp; wp += 256 * 4;
  float* sc2 = (float*)wp; wp += 128 * 4;
  float* sh2 = (float*)wp; wp += 128 * 4;
  wp = (char*)(((uintptr_t)wp + 255) & ~(uintptr_t)255);
  float* wqt  = (float*)wp; wp += (size_t)128 * 128 * 4;   // Wq^T * scale
  float* wcat = (float*)wp; wp += (size_t)128 * 256 * 4;   // [Wqk | Wv]
  float* h   = (float*)wp; wp += (size_t)N * HF * 4;       // sr1 out, += m_v, sr2 in; later c1
  float* h2  = (float*)wp; wp += (size_t)N * HF * 4;       // sr2 out = q; later z [M,256]
  float* xe  = (float*)wp; wp += (size_t)M * HF * 4;
  float* kvf = (float*)wp; wp += (size_t)M * 256 * 4;      // t1 fp32 alias / kv bf16
  float* z2  = (float*)wp; wp += (size_t)M * HF * 4;
  unsigned short* h16   = (unsigned short*)wp; wp += (size_t)N * HF * 2;  // sr1 bf16 shadow
  unsigned short* ho16  = (unsigned short*)wp; wp += (size_t)N * HF * 2;  // att out bf16
  unsigned short* m_e16 = (unsigned short*)wp; wp += (size_t)M * HF * 2;

  unsigned short* kv = (unsigned short*)kvf;   // [M][256] bf16
  float* t1  = kvf;                // her hidden [M,128] fp32 (dead before kv written)
  float* z   = h2;                 // [M,256] (h2 dead as q after att_fused)
  float* c1  = h;                  // [M,128] (h dead after sr2)

  // Histogram matrices alias h (dead until sr1): NB*M + NVR*NB*VPACK ints = 17.9MB < 25.6MB
  int* HE = (int*)h;
  int* HV = HE + (size_t)NB_CSR * M;

  hipMemsetAsync(d_ws, 0, zero_bytes, stream);

  // ---- CSR build: counting sort, zero device-scope atomics ----
  csr_hist<<<dim3(NB_CSR, 1 + NVR), 512, 0, stream>>>(node_idx, hedge_idx, E, M, HE, HV);
  csr_colscan<<<idiv(M + NVR * VPACK, 256), 256, 0, stream>>>(HE, HV, M, N, NVR, cnt_e, cnt_v);
  int nbE = idiv(M, SCAN_CHUNK);
  int nbV = idiv(N, SCAN_CHUNK);
  scanA2<<<nbE + nbV, 256, 0, stream>>>(cnt_e, M, nbE, part_e, cnt_v, N, part_v);
  scanB2<<<2, 256, 0, stream>>>(part_e, nbE, part_v, nbV);
  scanC2<<<nbE + nbV, 256, 0, stream>>>(cnt_e, M, nbE, part_e, off_e, cnt_v, N, nbV, part_v, off_v);
  csr_scatter<<<dim3(NB_CSR, 1 + NVR), 512, 0, stream>>>(node_idx, hedge_idx, E, M, HE, HV,
                                                         off_e, off_v, by_h, by_v);

  // wqt = Wq^T*scale, wcat right = Wv; then wcat left = Wk @ wqt
  prep_att<<<64, 256, 0, stream>>>(att_Wq, att_Wv, wqt, wcat);
  gemm64<<<dim3(2, 2), 256, 0, stream>>>(att_Wk, wqt, nullptr, wcat, 128, 128, 128, 0,
                                         nullptr, nullptr, 0, 256, 0, nullptr);

  dim3 blk(256);
  // her MLP: xe
  gemm64<<<dim3(idiv(M, 64), 2), blk, 0, stream>>>(x_e, her_W1, her_b1, t1, M, HF, HF, 1,
                                                   nullptr, nullptr, 0, HF, 0, nullptr);
  gemm64<<<dim3(idiv(M, 64), 2), blk, 0, stream>>>(t1, her_W2, her_b2, xe, M, HF, HF, 0,
                                                   nullptr, nullptr, 0, HF, 0, nullptr);
  // sr layer1 (fp32 + bf16 shadow), 64x64 tiles -> 1564 blocks (overwrites HE/HV)
  gemm64<<<dim3(idiv(N, 64), 2), blk, 0, stream>>>(x, sr_W1, sr_b1, h, N, HF, HF, 1,
                                                   nullptr, nullptr, 0, HF, 0, h16);
  // message passing means (bf16 gathers)
  seg_mean_e<<<idiv(M * 64, 256), blk, 0, stream>>>(h16, off_e, by_h, m_e16, M);
  seg_mean_v_add<<<idiv(N * 64, 256), blk, 0, stream>>>(h, m_e16, off_v, by_v, N);
  // sr layer2 -> h2 (doubles as q)
  gemm64<<<dim3(idiv(N, 64), 2), blk, 0, stream>>>(h, sr_W2, sr_b2, h2, N, HF, HF, 1,
                                                   nullptr, nullptr, 0, HF, 0, nullptr);
  // kv projection: [xe@Wqk | xe@Wv] in bf16
  gemm64<<<dim3(idiv(M, 64), 4), blk, 0, stream>>>(xe, wcat, nullptr, (float*)kv, M, HF, 256, 0,
                                                   nullptr, nullptr, 0, 256, 1, nullptr);
  // fused attention (q = h2)
  att_fused<<<idiv(N * 64, 256), blk, 0, stream>>>(h2, kv, off_v, by_v, ho16, N);
  // min aggregation + concat (z overwrites h2)
  seg_min_z<<<idiv(M * 64, 256), blk, 0, stream>>>(ho16, off_e, by_h, xe, z, M);
  // gn1 stats+scale (line-padded atomics) -> ef linear(+act) -> gn2 stats+scale
  colstats_mk<<<CS_GRID, 1024, 0, stream>>>(z, M, 256, stats1, gn1_w, gn1_b, gn1_a,
                                            1.f / (float)M, sc1, sh1, done1);
  gemm64<<<dim3(idiv(M, 64), 2), blk, 0, stream>>>(z, ef_W, ef_b, z2, M, 2 * HF, HF, 1,
                                                   sc1, sh1, 0, HF, 0, nullptr);
  colstats_mk<<<CS_GRID, 1024, 0, stream>>>(z2, M, 128, stats2, gn2_w, gn2_b, gn2_a,
                                            1.f / (float)M, sc2, sh2, done2);
  // classifier
  gemm64<<<dim3(idiv(M, 64), 2), blk, 0, stream>>>(z2, cls_W1, cls_b1, c1, M, HF, HF, 1,
                                                   sc2, sh2, 1, HF, 0, nullptr);
  gemm64<<<dim3(idiv(M, 64), 1), blk, 0, stream>>>(c1, cls_W2, cls_b2, (float*)d_out, M, HF, 64, 0,
                                                   nullptr, nullptr, 0, 64, 0, nullptr);
}

// Round 6
// 390.321 us; speedup vs baseline: 1.7116x; 1.0647x over previous
//
#include <hip/hip_runtime.h>
#include <float.h>
#include <math.h>

#define HF 128
#define SCAN_CHUNK 4096  // 256 threads x 16 elems
#define NB_CSR 128       // chunks for counting-sort CSR build
#define VPACK 12500      // packed (2-per-int) node bins per range: 25000 nodes / range
#define VRANGE (2 * VPACK)
#define CS_GRID 256      // colstats_part grid (per-block partials, no atomics)

static inline int idiv(int a, int b) { return (a + b - 1) / b; }

__device__ inline unsigned short f2bf(float x) {  // RNE float->bf16
  unsigned u = __float_as_uint(x);
  return (unsigned short)((u + 0x7fffu + ((u >> 16) & 1u)) >> 16);
}
__device__ inline unsigned packbf(float a, float b) {
  return (unsigned)f2bf(a) | ((unsigned)f2bf(b) << 16);
}
#define BFLO(w) __uint_as_float((w) << 16)
#define BFHI(w) __uint_as_float((w) & 0xffff0000u)

// ---------------- CSR build: LDS-histogram counting sort (ZERO device-scope atomics) ----------------
// Round-2 evidence: 1.2M global atomics = 24.7 G/s RMW wall (48.5us, invariant to
// occupancy/batching). Replaced by per-chunk LDS histograms + column scan + scatter.

__global__ __launch_bounds__(512) void csr_hist(const int* __restrict__ nidx,
                                                const int* __restrict__ hidx,
                                                int E, int M,
                                                int* __restrict__ HE,
                                                int* __restrict__ HV) {
  __shared__ int bins[VPACK];
  int b = blockIdx.x, y = blockIdx.y, tid = threadIdx.x;
  int chunk = (E + NB_CSR - 1) / NB_CSR;
  int e0 = b * chunk;
  int e1 = e0 + chunk; if (e1 > E) e1 = E;
  if (y == 0) {
    for (int s = tid; s < M; s += 512) bins[s] = 0;
    __syncthreads();
    for (int e = e0 + tid; e < e1; e += 512) atomicAdd(&bins[hidx[e]], 1);
    __syncthreads();
    for (int s = tid; s < M; s += 512) HE[(size_t)b * M + s] = bins[s];
  } else {
    int R = (y - 1) * VRANGE;
    int* HVr = HV + ((size_t)(y - 1) * NB_CSR + b) * VPACK;
    for (int q = tid; q < VPACK; q += 512) bins[q] = 0;
    __syncthreads();
    for (int e = e0 + tid; e < e1; e += 512) {
      int v = nidx[e] - R;
      if ((unsigned)v < (unsigned)VRANGE) atomicAdd(&bins[v >> 1], (v & 1) ? 0x10000 : 1);
    }
    __syncthreads();
    for (int q = tid; q < VPACK; q += 512) HVr[q] = bins[q];
  }
}

// Per-segment exclusive scan over the NB_CSR chunks (in place) + dense counts.
__global__ __launch_bounds__(256) void csr_colscan(int* __restrict__ HE,
                                                   int* __restrict__ HV,
                                                   int M, int N, int NVR,
                                                   int* __restrict__ cnt_e,
                                                   int* __restrict__ cnt_v) {
  int col = blockIdx.x * 256 + threadIdx.x;
  if (col < M) {
    int run = 0;
    for (int b = 0; b < NB_CSR; ++b) {
      size_t i = (size_t)b * M + col;
      int t = HE[i]; HE[i] = run; run += t;
    }
    cnt_e[col] = run;
  } else if (col < M + NVR * VPACK) {
    int c = col - M;
    int r = c / VPACK, q = c - r * VPACK;
    int* HVr = HV + (size_t)r * NB_CSR * VPACK;
    int run = 0;
    for (int b = 0; b < NB_CSR; ++b) {
      size_t i = (size_t)b * VPACK + q;
      int t = HVr[i]; HVr[i] = run; run += t;
    }
    int node = r * VRANGE + 2 * q;
    if (node < N) cnt_v[node] = run & 0xffff;
    if (node + 1 < N) cnt_v[node + 1] = run >> 16;
  }
}

// Scatter: preload LDS bins with global base (off + chunk-exclusive), LDS-atomic rank.
__global__ __launch_bounds__(512) void csr_scatter(const int* __restrict__ nidx,
                                                   const int* __restrict__ hidx,
                                                   int E, int M,
                                                   const int* __restrict__ HE,
                                                   const int* __restrict__ HV,
                                                   const int* __restrict__ off_e,
                                                   const int* __restrict__ off_v,
                                                   unsigned short* __restrict__ by_h,
                                                   unsigned short* __restrict__ by_v) {
  __shared__ int bins[VPACK];
  int b = blockIdx.x, y = blockIdx.y, tid = threadIdx.x;
  int chunk = (E + NB_CSR - 1) / NB_CSR;
  int e0 = b * chunk;
  int e1 = e0 + chunk; if (e1 > E) e1 = E;
  if (y == 0) {
    for (int s = tid; s < M; s += 512) bins[s] = off_e[s] + HE[(size_t)b * M + s];
    __syncthreads();
    for (int e = e0 + tid; e < e1; e += 512) {
      int pos = atomicAdd(&bins[hidx[e]], 1);
      by_h[pos] = (unsigned short)nidx[e];
    }
  } else {
    int R = (y - 1) * VRANGE;
    const int* HVr = HV + ((size_t)(y - 1) * NB_CSR + b) * VPACK;
    for (int q = tid; q < VPACK; q += 512) bins[q] = HVr[q];
    __syncthreads();
    for (int e = e0 + tid; e < e1; e += 512) {
      int v = nidx[e];
      int vr = v - R;
      if ((unsigned)vr < (unsigned)VRANGE) {
        int old = atomicAdd(&bins[vr >> 1], (vr & 1) ? 0x10000 : 1);
        int rank = (vr & 1) ? (old >> 16) : (old & 0xffff);
        by_v[off_v[v] + rank] = (unsigned short)hidx[e];
      }
    }
  }
}

// ---- fused 3-phase multi-block exclusive scan over both dense count arrays ----

__global__ __launch_bounds__(256) void scanA2(const int* __restrict__ inE, int nE, int nbE,
                                              int* __restrict__ partE,
                                              const int* __restrict__ inV, int nV,
                                              int* __restrict__ partV) {
  const int* in; int n, b; int* partials;
  if ((int)blockIdx.x < nbE) { in = inE; n = nE; b = blockIdx.x; partials = partE; }
  else { in = inV; n = nV; b = blockIdx.x - nbE; partials = partV; }
  __shared__ int lds[256];
  int tid = threadIdx.x;
  int base = b * SCAN_CHUNK + tid * 16;
  int s = 0;
#pragma unroll
  for (int i = 0; i < 16; ++i) {
    int idx = base + i;
    if (idx < n) s += in[idx];
  }
  lds[tid] = s;
  __syncthreads();
  for (int off = 128; off; off >>= 1) {
    if (tid < off) lds[tid] += lds[tid + off];
    __syncthreads();
  }
  if (tid == 0) partials[b] = lds[0];
}

__global__ __launch_bounds__(256) void scanB2(int* __restrict__ partE, int nbE,
                                              int* __restrict__ partV, int nbV) {
  int* partials = (blockIdx.x == 0) ? partE : partV;
  int nb = (blockIdx.x == 0) ? nbE : nbV;
  __shared__ int lds[256];
  int tid = threadIdx.x;
  int v = (tid < nb) ? partials[tid] : 0;
  lds[tid] = v;
  __syncthreads();
  for (int off = 1; off < 256; off <<= 1) {
    int add = (tid >= off) ? lds[tid - off] : 0;
    __syncthreads();
    lds[tid] += add;
    __syncthreads();
  }
  if (tid < nb) partials[tid] = lds[tid] - v;  // exclusive
  if (tid == nb - 1) partials[nb] = lds[tid];  // total
}

__global__ __launch_bounds__(256) void scanC2(const int* __restrict__ inE, int nE, int nbE,
                                              const int* __restrict__ partE, int* __restrict__ outE,
                                              const int* __restrict__ inV, int nV, int nbV,
                                              const int* __restrict__ partV, int* __restrict__ outV) {
  const int* in; const int* partials; int* out; int n, b, nb;
  if ((int)blockIdx.x < nbE) { in = inE; n = nE; b = blockIdx.x; partials = partE; out = outE; nb = nbE; }
  else { in = inV; n = nV; b = blockIdx.x - nbE; partials = partV; out = outV; nb = nbV; }
  __shared__ int lds[256];
  int tid = threadIdx.x;
  int base = b * SCAN_CHUNK + tid * 16;
  int vals[16];
  int s = 0;
#pragma unroll
  for (int i = 0; i < 16; ++i) {
    int idx = base + i;
    int v = (idx < n) ? in[idx] : 0;
    vals[i] = s;
    s += v;
  }
  lds[tid] = s;
  __syncthreads();
  int own = s;
  for (int off = 1; off < 256; off <<= 1) {
    int add = (tid >= off) ? lds[tid - off] : 0;
    __syncthreads();
    lds[tid] += add;
    __syncthreads();
  }
  int excl = lds[tid] - own + partials[b];
#pragma unroll
  for (int i = 0; i < 16; ++i) {
    int idx = base + i;
    if (idx < n) out[idx] = excl + vals[i];
  }
  if (b == 0 && tid == 0) out[n] = partials[nb];
}

// wqt = Wq^T * (1/sqrt(128)) [score scale folded]; wcat[:,128:256] = Wv.
__global__ void prep_att(const float* __restrict__ Wq, const float* __restrict__ Wv,
                         float* __restrict__ wqt, float* __restrict__ wcat) {
  int i = blockIdx.x * blockDim.x + threadIdx.x;  // 128*128
  if (i >= 128 * 128) return;
  int r = i >> 7, c = i & 127;
  wqt[c * 128 + r] = Wq[i] * 0.08838834764831845f;
  wcat[r * 256 + 128 + c] = Wv[i];
}

// ---------------- GEMM: 64x64 tile, 4x4 micro; fused input-norm / act / bf16-out / fp32+bf16 shadow ----------------

__global__ __launch_bounds__(256) void gemm64(const float* __restrict__ A,
                                              const float* __restrict__ W,
                                              const float* __restrict__ bias,
                                              float* __restrict__ out,
                                              int R, int K, int C, int act,
                                              const float* __restrict__ insc,
                                              const float* __restrict__ insh, int inact,
                                              int ldo, int obf16,
                                              unsigned short* __restrict__ out16) {
  __shared__ __align__(16) float As[64][20];
  __shared__ __align__(16) float Bs[16][64];
  int tid = threadIdx.x;
  int tx = tid & 15;
  int ty = tid >> 4;
  int rowBase = blockIdx.x * 64;
  int colBase = blockIdx.y * 64;

  float acc[4][4] = {};

  for (int k0 = 0; k0 < K; k0 += 16) {
    {
      int arow = tid >> 2, ac = (tid & 3) * 4;
      int gr = rowBase + arow;
      float4 av = make_float4(0.f, 0.f, 0.f, 0.f);
      if (gr < R) av = *(const float4*)(A + (size_t)gr * K + k0 + ac);
      if (insc) {
        float vv[4] = {av.x, av.y, av.z, av.w};
#pragma unroll
        for (int i = 0; i < 4; ++i) {
          float s = insc[k0 + ac + i], sh = insh[k0 + ac + i];
          float v = vv[i] * s + sh;
          if (inact) v = v > 0.f ? v : 0.01f * v;
          vv[i] = v;
        }
        av = make_float4(vv[0], vv[1], vv[2], vv[3]);
      }
      *(float4*)&As[arow][ac] = av;
    }
    {
      int bk = tid >> 4, bc = (tid & 15) * 4;
      *(float4*)&Bs[bk][bc] = *(const float4*)(W + (size_t)(k0 + bk) * C + colBase + bc);
    }
    __syncthreads();
#pragma unroll
    for (int kg = 0; kg < 16; kg += 4) {
      float af[4][4], bf[4][4];
#pragma unroll
      for (int i = 0; i < 4; ++i)
        *(float4*)af[i] = *(const float4*)&As[ty * 4 + i][kg];
#pragma unroll
      for (int kk = 0; kk < 4; ++kk)
        *(float4*)bf[kk] = *(const float4*)&Bs[kg + kk][tx * 4];
#pragma unroll
      for (int kk = 0; kk < 4; ++kk)
#pragma unroll
        for (int i = 0; i < 4; ++i)
#pragma unroll
          for (int j = 0; j < 4; ++j)
            acc[i][j] = fmaf(af[i][kk], bf[kk][j], acc[i][j]);
    }
    __syncthreads();
  }

#pragma unroll
  for (int i = 0; i < 4; ++i) {
    int r = rowBase + ty * 4 + i;
    if (r >= R) continue;
    float vals[4];
#pragma unroll
    for (int j = 0; j < 4; ++j) {
      float v = acc[i][j];
      if (bias) v += bias[colBase + tx * 4 + j];
      if (act) v = v > 0.f ? v : 0.01f * v;
      vals[j] = v;
    }
    if (obf16) {
      unsigned short* o16 = (unsigned short*)out;
      ushort4 w = make_ushort4(f2bf(vals[0]), f2bf(vals[1]), f2bf(vals[2]), f2bf(vals[3]));
      *(ushort4*)(o16 + (size_t)r * ldo + colBase + tx * 4) = w;
    } else {
      *(float4*)(out + (size_t)r * ldo + colBase + tx * 4) =
          make_float4(vals[0], vals[1], vals[2], vals[3]);
      if (out16) {
        uint2 w = make_uint2(packbf(vals[0], vals[1]), packbf(vals[2], vals[3]));
        *(uint2*)(out16 + (size_t)r * ldo + colBase + tx * 4) = w;
      }
    }
  }
}

// ---------------- segment ops: one wave per segment; 4 x 16-lane groups, 8 feats/lane ----------------

__global__ __launch_bounds__(256) void seg_mean_e(const unsigned short* __restrict__ h16,
                                                  const int* __restrict__ off_e,
                                                  const unsigned short* __restrict__ by_h,
                                                  unsigned short* __restrict__ m_e16, int M) {
  int m = (blockIdx.x * blockDim.x + threadIdx.x) >> 6;
  if (m >= M) return;
  int lane = threadIdx.x & 63;
  int g = lane >> 4;
  int fl = lane & 15;
  int s = off_e[m], e1 = off_e[m + 1];
  float4 a0 = make_float4(0.f, 0.f, 0.f, 0.f), a1 = a0;
  for (int j = s + g; j < e1; j += 4) {
    int vi = by_h[j];
    uint4 hw = *(const uint4*)(h16 + (size_t)vi * HF + fl * 8);
    a0.x += BFLO(hw.x); a0.y += BFHI(hw.x); a0.z += BFLO(hw.y); a0.w += BFHI(hw.y);
    a1.x += BFLO(hw.z); a1.y += BFHI(hw.z); a1.z += BFLO(hw.w); a1.w += BFHI(hw.w);
  }
#pragma unroll
  for (int mask = 16; mask <= 32; mask <<= 1) {
    a0.x += __shfl_xor(a0.x, mask); a0.y += __shfl_xor(a0.y, mask);
    a0.z += __shfl_xor(a0.z, mask); a0.w += __shfl_xor(a0.w, mask);
    a1.x += __shfl_xor(a1.x, mask); a1.y += __shfl_xor(a1.y, mask);
    a1.z += __shfl_xor(a1.z, mask); a1.w += __shfl_xor(a1.w, mask);
  }
  if (g == 0) {
    int cnt = e1 - s;
    float r = 1.f / (float)(cnt > 0 ? cnt : 1);
    uint4 w = make_uint4(packbf(a0.x * r, a0.y * r), packbf(a0.z * r, a0.w * r),
                         packbf(a1.x * r, a1.y * r), packbf(a1.z * r, a1.w * r));
    *(uint4*)(m_e16 + (size_t)m * HF + fl * 8) = w;
  }
}

__global__ __launch_bounds__(256) void seg_mean_v_add(float* __restrict__ h,
                                                      const unsigned short* __restrict__ m_e16,
                                                      const int* __restrict__ off_v,
                                                      const unsigned short* __restrict__ by_v,
                                                      int N) {
  int n = (blockIdx.x * blockDim.x + threadIdx.x) >> 6;
  if (n >= N) return;
  int lane = threadIdx.x & 63;
  int g = lane >> 4;
  int fl = lane & 15;
  int s = off_v[n], e1 = off_v[n + 1];
  float4 a0 = make_float4(0.f, 0.f, 0.f, 0.f), a1 = a0;
  for (int j = s + g; j < e1; j += 4) {
    int he = by_v[j];
    uint4 hw = *(const uint4*)(m_e16 + (size_t)he * HF + fl * 8);
    a0.x += BFLO(hw.x); a0.y += BFHI(hw.x); a0.z += BFLO(hw.y); a0.w += BFHI(hw.y);
    a1.x += BFLO(hw.z); a1.y += BFHI(hw.z); a1.z += BFLO(hw.w); a1.w += BFHI(hw.w);
  }
#pragma unroll
  for (int mask = 16; mask <= 32; mask <<= 1) {
    a0.x += __shfl_xor(a0.x, mask); a0.y += __shfl_xor(a0.y, mask);
    a0.z += __shfl_xor(a0.z, mask); a0.w += __shfl_xor(a0.w, mask);
    a1.x += __shfl_xor(a1.x, mask); a1.y += __shfl_xor(a1.y, mask);
    a1.z += __shfl_xor(a1.z, mask); a1.w += __shfl_xor(a1.w, mask);
  }
  if (g == 0) {
    int cnt = e1 - s;
    float r = 1.f / (float)(cnt > 0 ? cnt : 1);
    float* hp = h + (size_t)n * HF + fl * 8;
    float4 h0 = *(const float4*)hp;
    float4 h1 = *(const float4*)(hp + 4);
    *(float4*)hp = make_float4(h0.x + a0.x * r, h0.y + a0.y * r, h0.z + a0.z * r, h0.w + a0.w * r);
    *(float4*)(hp + 4) = make_float4(h1.x + a1.x * r, h1.y + a1.y * r, h1.z + a1.z * r, h1.w + a1.w * r);
  }
}

// Fused GAT attention: one wave per node; q = h2 (fp32, score scale pre-folded into Wqk);
// kv bf16 [M][256]; software prefetch + defer-max rescale (THR=8).
__global__ __launch_bounds__(256) void att_fused(const float* __restrict__ q,
                                                 const unsigned short* __restrict__ kv,
                                                 const int* __restrict__ off_v,
                                                 const unsigned short* __restrict__ by_v,
                                                 unsigned short* __restrict__ ho16, int N) {
  int n = (blockIdx.x * blockDim.x + threadIdx.x) >> 6;
  if (n >= N) return;
  int lane = threadIdx.x & 63;
  int g = lane >> 4;
  int fl = lane & 15;
  int s0 = off_v[n], s1 = off_v[n + 1];
  const float* qp = q + (size_t)n * HF + fl * 8;
  float4 q0 = *(const float4*)qp;
  float4 q1 = *(const float4*)(qp + 4);
  float m = -INFINITY, l = 0.f;
  float4 a0 = make_float4(0.f, 0.f, 0.f, 0.f), a1 = a0;
  int j = s0 + g;
  uint4 kw = make_uint4(0, 0, 0, 0), vw = kw;
  if (j < s1) {
    const unsigned short* base = kv + (size_t)by_v[j] * 256 + fl * 8;
    kw = *(const uint4*)base;
    vw = *(const uint4*)(base + 128);
  }
  while (j < s1) {
    int jn = j + 4;
    uint4 kw2 = make_uint4(0, 0, 0, 0), vw2 = kw2;
    if (jn < s1) {
      const unsigned short* b2 = kv + (size_t)by_v[jn] * 256 + fl * 8;
      kw2 = *(const uint4*)b2;
      vw2 = *(const uint4*)(b2 + 128);
    }
    float d = q0.x * BFLO(kw.x) + q0.y * BFHI(kw.x) + q0.z * BFLO(kw.y) + q0.w * BFHI(kw.y)
            + q1.x * BFLO(kw.z) + q1.y * BFHI(kw.z) + q1.z * BFLO(kw.w) + q1.w * BFHI(kw.w);
    d += __shfl_xor(d, 1);
    d += __shfl_xor(d, 2);
    d += __shfl_xor(d, 4);
    d += __shfl_xor(d, 8);
    d = d > 0.f ? d : 0.2f * d;   // scale already folded into Wqk
    if (d > m + 8.f) {
      float sc = __expf(m - d);   // first edge: exp(-inf)=0 zeroes l,a
      l *= sc;
      a0.x *= sc; a0.y *= sc; a0.z *= sc; a0.w *= sc;
      a1.x *= sc; a1.y *= sc; a1.z *= sc; a1.w *= sc;
      m = d;
    }
    float p = __expf(d - m);
    l += p;
    a0.x += p * BFLO(vw.x); a0.y += p * BFHI(vw.x);
    a0.z += p * BFLO(vw.y); a0.w += p * BFHI(vw.y);
    a1.x += p * BFLO(vw.z); a1.y += p * BFHI(vw.z);
    a1.z += p * BFLO(vw.w); a1.w += p * BFHI(vw.w);
    kw = kw2; vw = vw2; j = jn;
  }
#pragma unroll
  for (int mask = 16; mask <= 32; mask <<= 1) {
    float m2 = __shfl_xor(m, mask);
    float l2 = __shfl_xor(l, mask);
    float b0x = __shfl_xor(a0.x, mask), b0y = __shfl_xor(a0.y, mask);
    float b0z = __shfl_xor(a0.z, mask), b0w = __shfl_xor(a0.w, mask);
    float b1x = __shfl_xor(a1.x, mask), b1y = __shfl_xor(a1.y, mask);
    float b1z = __shfl_xor(a1.z, mask), b1w = __shfl_xor(a1.w, mask);
    float mn = fmaxf(fmaxf(m, m2), -1e30f);
    float ea = __expf(m - mn), eb = __expf(m2 - mn);
    l = l * ea + l2 * eb;
    a0.x = a0.x * ea + b0x * eb; a0.y = a0.y * ea + b0y * eb;
    a0.z = a0.z * ea + b0z * eb; a0.w = a0.w * ea + b0w * eb;
    a1.x = a1.x * ea + b1x * eb; a1.y = a1.y * ea + b1y * eb;
    a1.z = a1.z * ea + b1z * eb; a1.w = a1.w * ea + b1w * eb;
    m = fmaxf(m, m2);
  }
  if (g == 0) {
    float inv = 1.f / fmaxf(l, 1e-16f);
    uint4 w = make_uint4(packbf(a0.x * inv, a0.y * inv), packbf(a0.z * inv, a0.w * inv),
                         packbf(a1.x * inv, a1.y * inv), packbf(a1.z * inv, a1.w * inv));
    *(uint4*)(ho16 + (size_t)n * HF + fl * 8) = w;
  }
}

// z[m][0:128] = segment_min(ho16[node]) (0 if empty); z[m][128:256] = xe[m]
__global__ __launch_bounds__(256) void seg_min_z(const unsigned short* __restrict__ ho16,
                                                 const int* __restrict__ off_e,
                                                 const unsigned short* __restrict__ by_h,
                                                 const float* __restrict__ xe,
                                                 float* __restrict__ z, int M) {
  int m = (blockIdx.x * blockDim.x + threadIdx.x) >> 6;
  if (m >= M) return;
  int lane = threadIdx.x & 63;
  int g = lane >> 4;
  int fl = lane & 15;
  int s = off_e[m], e1 = off_e[m + 1];
  float4 a0 = make_float4(FLT_MAX, FLT_MAX, FLT_MAX, FLT_MAX), a1 = a0;
  for (int j = s + g; j < e1; j += 4) {
    int vi = by_h[j];
    uint4 hw = *(const uint4*)(ho16 + (size_t)vi * HF + fl * 8);
    a0.x = fminf(a0.x, BFLO(hw.x)); a0.y = fminf(a0.y, BFHI(hw.x));
    a0.z = fminf(a0.z, BFLO(hw.y)); a0.w = fminf(a0.w, BFHI(hw.y));
    a1.x = fminf(a1.x, BFLO(hw.z)); a1.y = fminf(a1.y, BFHI(hw.z));
    a1.z = fminf(a1.z, BFLO(hw.w)); a1.w = fminf(a1.w, BFHI(hw.w));
  }
#pragma unroll
  for (int mask = 16; mask <= 32; mask <<= 1) {
    a0.x = fminf(a0.x, __shfl_xor(a0.x, mask)); a0.y = fminf(a0.y, __shfl_xor(a0.y, mask));
    a0.z = fminf(a0.z, __shfl_xor(a0.z, mask)); a0.w = fminf(a0.w, __shfl_xor(a0.w, mask));
    a1.x = fminf(a1.x, __shfl_xor(a1.x, mask)); a1.y = fminf(a1.y, __shfl_xor(a1.y, mask));
    a1.z = fminf(a1.z, __shfl_xor(a1.z, mask)); a1.w = fminf(a1.w, __shfl_xor(a1.w, mask));
  }
  if (g == 0) {
    bool nz = (e1 > s);
    float* op = z + (size_t)m * 256 + fl * 8;
    *(float4*)op = nz ? a0 : make_float4(0.f, 0.f, 0.f, 0.f);
    *(float4*)(op + 4) = nz ? a1 : make_float4(0.f, 0.f, 0.f, 0.f);
  } else if (g == 1) {
    const float* xp = xe + (size_t)m * HF + fl * 8;
    float* op = z + (size_t)m * 256 + 128 + fl * 8;
    *(float4*)op = *(const float4*)xp;
    *(float4*)(op + 4) = *(const float4*)(xp + 4);
  }
}

// ---------------- GraphNorm stats: two-kernel deterministic reduction ----------------
// Round-5 evidence: padded-atomic colstats still ~30us each (41.7 -> ~30; total -22us
// vs predicted -73). Residual is NOT the stats atomic chain -> delete ALL suspicious
// machinery: per-block partials via plain stores (no atomics, no __threadfence, no
// ticket), then a tiny finalize kernel. Also removes the need for any ws zeroing.

__global__ __launch_bounds__(1024) void colstats_part(const float* __restrict__ z, int rows, int C,
                                                      float* __restrict__ part) {
  int tid = threadIdx.x;
  int RL = 1024 / C;
  int col = tid & (C - 1);
  int ro = tid / C;
  float s1 = 0.f, s2 = 0.f;
  for (int r = blockIdx.x * RL + ro; r < rows; r += gridDim.x * RL) {
    float v = z[(size_t)r * C + col];
    s1 += v;
    s2 += v * v;
  }
  __shared__ float l1[1024], l2[1024];
  l1[tid] = s1;
  l2[tid] = s2;
  __syncthreads();
  for (int off = 512; off >= C; off >>= 1) {
    if (tid < off) { l1[tid] += l1[tid + off]; l2[tid] += l2[tid + off]; }
    __syncthreads();
  }
  if (tid < C) {
    part[(size_t)blockIdx.x * 2 * C + tid] = l1[tid];
    part[(size_t)blockIdx.x * 2 * C + C + tid] = l2[tid];
  }
}

__global__ void colstats_fin(const float* __restrict__ part, int nb, int C,
                             const float* __restrict__ w, const float* __restrict__ b,
                             const float* __restrict__ a, float invrows,
                             float* __restrict__ sc, float* __restrict__ sh) {
  int col = threadIdx.x;
  if (col >= C) return;
  float s1 = 0.f, s2 = 0.f;
#pragma unroll 8
  for (int i = 0; i < nb; ++i) {
    s1 += part[(size_t)i * 2 * C + col];
    s2 += part[(size_t)i * 2 * C + C + col];
  }
  float mu = s1 * invrows;
  float ex2 = s2 * invrows;
  float av = a[col];
  float var = ex2 - 2.f * av * mu * mu + av * av * mu * mu;
  float s = w[col] * rsqrtf(var + 1e-5f);
  sc[col] = s;
  sh[col] = b[col] - av * mu * s;
}

// ---------------- launch ----------------

extern "C" void kernel_launch(void* const* d_in, const int* in_sizes, int n_in,
                              void* d_out, int out_size, void* d_ws, size_t ws_size,
                              hipStream_t stream) {
  const float* x        = (const float*)d_in[0];
  const float* x_e      = (const float*)d_in[2];
  const int*   node_idx = (const int*)d_in[3];
  const int*   hedge_idx= (const int*)d_in[4];
  const float* her_W1   = (const float*)d_in[5];
  const float* her_b1   = (const float*)d_in[6];
  const float* her_W2   = (const float*)d_in[7];
  const float* her_b2   = (const float*)d_in[8];
  const float* sr_W1    = (const float*)d_in[9];
  const float* sr_b1    = (const float*)d_in[10];
  const float* sr_W2    = (const float*)d_in[11];
  const float* sr_b2    = (const float*)d_in[12];
  const float* att_Wq   = (const float*)d_in[13];
  const float* att_Wk   = (const float*)d_in[14];
  const float* att_Wv   = (const float*)d_in[15];
  const float* ef_W     = (const float*)d_in[16];
  const float* ef_b     = (const float*)d_in[17];
  const float* gn1_w    = (const float*)d_in[18];
  const float* gn1_b    = (const float*)d_in[19];
  const float* gn1_a    = (const float*)d_in[20];
  const float* gn2_w    = (const float*)d_in[21];
  const float* gn2_b    = (const float*)d_in[22];
  const float* gn2_a    = (const float*)d_in[23];
  const float* cls_W1   = (const float*)d_in[24];
  const float* cls_b1   = (const float*)d_in[25];
  const float* cls_W2   = (const float*)d_in[26];
  const float* cls_b2   = (const float*)d_in[27];

  const int N = in_sizes[0] / HF;
  const int M = in_sizes[2] / HF;
  const int E = in_sizes[3];
  const int NVR = idiv(N, VRANGE);  // node range count (2 for N=50000)

  // ---- workspace layout (nothing needs zeroing: counting sort writes every cell) ----
  char* wp = (char*)d_ws;
  float* part1 = (float*)wp; wp += (size_t)CS_GRID * 512 * 4;  // gn1 partials (2*256 per blk)
  float* part2 = (float*)wp; wp += (size_t)CS_GRID * 256 * 4;  // gn2 partials (2*128 per blk)
  int* cnt_e = (int*)wp; wp += (size_t)M * 4;
  int* cnt_v = (int*)wp; wp += (size_t)N * 4;
  int* off_e = (int*)wp; wp += (size_t)(M + 1) * 4;
  int* off_v = (int*)wp; wp += (size_t)(N + 1) * 4;
  unsigned short* by_h = (unsigned short*)wp; wp += ((size_t)E * 2 + 3) & ~(size_t)3;
  unsigned short* by_v = (unsigned short*)wp; wp += ((size_t)E * 2 + 3) & ~(size_t)3;
  int* part_e = (int*)wp; wp += 257 * 4;
  int* part_v = (int*)wp; wp += 257 * 4;
  float* sc1 = (float*)wp; wp += 256 * 4;
  float* sh1 = (float*)wp; wp += 256 * 4;
  float* sc2 = (float*)wp; wp += 128 * 4;
  float* sh2 = (float*)wp; wp += 128 * 4;
  wp = (char*)(((uintptr_t)wp + 255) & ~(uintptr_t)255);
  float* wqt  = (float*)wp; wp += (size_t)128 * 128 * 4;   // Wq^T * scale
  float* wcat = (float*)wp; wp += (size_t)128 * 256 * 4;   // [Wqk | Wv]
  float* h   = (float*)wp; wp += (size_t)N * HF * 4;       // sr1 out, += m_v, sr2 in; later c1
  float* h2  = (float*)wp; wp += (size_t)N * HF * 4;       // sr2 out = q; later z [M,256]
  float* xe  = (float*)wp; wp += (size_t)M * HF * 4;
  float* kvf = (float*)wp; wp += (size_t)M * 256 * 4;      // t1 fp32 alias / kv bf16
  float* z2  = (float*)wp; wp += (size_t)M * HF * 4;
  unsigned short* h16   = (unsigned short*)wp; wp += (size_t)N * HF * 2;  // sr1 bf16 shadow
  unsigned short* ho16  = (unsigned short*)wp; wp += (size_t)N * HF * 2;  // att out bf16
  unsigned short* m_e16 = (unsigned short*)wp; wp += (size_t)M * HF * 2;

  unsigned short* kv = (unsigned short*)kvf;   // [M][256] bf16
  float* t1  = kvf;                // her hidden [M,128] fp32 (dead before kv written)
  float* z   = h2;                 // [M,256] (h2 dead as q after att_fused)
  float* c1  = h;                  // [M,128] (h dead after sr2)

  // Histogram matrices alias h (dead until sr1): NB*M + NVR*NB*VPACK ints = 17.9MB < 25.6MB
  int* HE = (int*)h;
  int* HV = HE + (size_t)NB_CSR * M;

  // ---- CSR build: counting sort, zero device-scope atomics ----
  csr_hist<<<dim3(NB_CSR, 1 + NVR), 512, 0, stream>>>(node_idx, hedge_idx, E, M, HE, HV);
  csr_colscan<<<idiv(M + NVR * VPACK, 256), 256, 0, stream>>>(HE, HV, M, N, NVR, cnt_e, cnt_v);
  int nbE = idiv(M, SCAN_CHUNK);
  int nbV = idiv(N, SCAN_CHUNK);
  scanA2<<<nbE + nbV, 256, 0, stream>>>(cnt_e, M, nbE, part_e, cnt_v, N, part_v);
  scanB2<<<2, 256, 0, stream>>>(part_e, nbE, part_v, nbV);
  scanC2<<<nbE + nbV, 256, 0, stream>>>(cnt_e, M, nbE, part_e, off_e, cnt_v, N, nbV, part_v, off_v);
  csr_scatter<<<dim3(NB_CSR, 1 + NVR), 512, 0, stream>>>(node_idx, hedge_idx, E, M, HE, HV,
                                                         off_e, off_v, by_h, by_v);

  // wqt = Wq^T*scale, wcat right = Wv; then wcat left = Wk @ wqt
  prep_att<<<64, 256, 0, stream>>>(att_Wq, att_Wv, wqt, wcat);
  gemm64<<<dim3(2, 2), 256, 0, stream>>>(att_Wk, wqt, nullptr, wcat, 128, 128, 128, 0,
                                         nullptr, nullptr, 0, 256, 0, nullptr);

  dim3 blk(256);
  // her MLP: xe
  gemm64<<<dim3(idiv(M, 64), 2), blk, 0, stream>>>(x_e, her_W1, her_b1, t1, M, HF, HF, 1,
                                                   nullptr, nullptr, 0, HF, 0, nullptr);
  gemm64<<<dim3(idiv(M, 64), 2), blk, 0, stream>>>(t1, her_W2, her_b2, xe, M, HF, HF, 0,
                                                   nullptr, nullptr, 0, HF, 0, nullptr);
  // sr layer1 (fp32 + bf16 shadow), 64x64 tiles -> 1564 blocks (overwrites HE/HV)
  gemm64<<<dim3(idiv(N, 64), 2), blk, 0, stream>>>(x, sr_W1, sr_b1, h, N, HF, HF, 1,
                                                   nullptr, nullptr, 0, HF, 0, h16);
  // message passing means (bf16 gathers)
  seg_mean_e<<<idiv(M * 64, 256), blk, 0, stream>>>(h16, off_e, by_h, m_e16, M);
  seg_mean_v_add<<<idiv(N * 64, 256), blk, 0, stream>>>(h, m_e16, off_v, by_v, N);
  // sr layer2 -> h2 (doubles as q)
  gemm64<<<dim3(idiv(N, 64), 2), blk, 0, stream>>>(h, sr_W2, sr_b2, h2, N, HF, HF, 1,
                                                   nullptr, nullptr, 0, HF, 0, nullptr);
  // kv projection: [xe@Wqk | xe@Wv] in bf16
  gemm64<<<dim3(idiv(M, 64), 4), blk, 0, stream>>>(xe, wcat, nullptr, (float*)kv, M, HF, 256, 0,
                                                   nullptr, nullptr, 0, 256, 1, nullptr);
  // fused attention (q = h2)
  att_fused<<<idiv(N * 64, 256), blk, 0, stream>>>(h2, kv, off_v, by_v, ho16, N);
  // min aggregation + concat (z overwrites h2)
  seg_min_z<<<idiv(M * 64, 256), blk, 0, stream>>>(ho16, off_e, by_h, xe, z, M);
  // gn1 stats (partials + finalize) -> ef linear(+act) -> gn2 stats
  colstats_part<<<CS_GRID, 1024, 0, stream>>>(z, M, 256, part1);
  colstats_fin<<<1, 256, 0, stream>>>(part1, CS_GRID, 256, gn1_w, gn1_b, gn1_a,
                                      1.f / (float)M, sc1, sh1);
  gemm64<<<dim3(idiv(M, 64), 2), blk, 0, stream>>>(z, ef_W, ef_b, z2, M, 2 * HF, HF, 1,
                                                   sc1, sh1, 0, HF, 0, nullptr);
  colstats_part<<<CS_GRID, 1024, 0, stream>>>(z2, M, 128, part2);
  colstats_fin<<<1, 128, 0, stream>>>(part2, CS_GRID, 128, gn2_w, gn2_b, gn2_a,
                                      1.f / (float)M, sc2, sh2);
  // classifier
  gemm64<<<dim3(idiv(M, 64), 2), blk, 0, stream>>>(z2, cls_W1, cls_b1, c1, M, HF, HF, 1,
                                                   sc2, sh2, 1, HF, 0, nullptr);
  gemm64<<<dim3(idiv(M, 64), 1), blk, 0, stream>>>(c1, cls_W2, cls_b2, (float*)d_out, M, HF, 64, 0,
                                                   nullptr, nullptr, 0, 64, 0, nullptr);
}

// Round 7
// 385.498 us; speedup vs baseline: 1.7331x; 1.0125x over previous
//
#include <hip/hip_runtime.h>
#include <float.h>
#include <math.h>

#define HF 128
#define SCAN_CHUNK 4096  // 256 threads x 16 elems
#define NB_CSR 128       // chunks for counting-sort CSR build
#define VPACK 12500      // packed (2-per-int) node bins per range: 25000 nodes / range
#define VRANGE (2 * VPACK)
#define CS_GRID 256      // colstats_part grid (per-block partials, no atomics)

static inline int idiv(int a, int b) { return (a + b - 1) / b; }

__device__ inline unsigned short f2bf(float x) {  // RNE float->bf16
  unsigned u = __float_as_uint(x);
  return (unsigned short)((u + 0x7fffu + ((u >> 16) & 1u)) >> 16);
}
__device__ inline unsigned packbf(float a, float b) {
  return (unsigned)f2bf(a) | ((unsigned)f2bf(b) << 16);
}
#define BFLO(w) __uint_as_float((w) << 16)
#define BFHI(w) __uint_as_float((w) & 0xffff0000u)

// ---------------- CSR build: LDS-histogram counting sort (ZERO device-scope atomics) ----------------
// Round-2 evidence: 1.2M global atomics = 24.7 G/s RMW wall (48.5us, invariant to
// occupancy/batching). Replaced by per-chunk LDS histograms + column scan + scatter.

__global__ __launch_bounds__(512) void csr_hist(const int* __restrict__ nidx,
                                                const int* __restrict__ hidx,
                                                int E, int M,
                                                int* __restrict__ HE,
                                                int* __restrict__ HV) {
  __shared__ int bins[VPACK];
  int b = blockIdx.x, y = blockIdx.y, tid = threadIdx.x;
  int chunk = (E + NB_CSR - 1) / NB_CSR;
  int e0 = b * chunk;
  int e1 = e0 + chunk; if (e1 > E) e1 = E;
  if (y == 0) {
    for (int s = tid; s < M; s += 512) bins[s] = 0;
    __syncthreads();
    for (int e = e0 + tid; e < e1; e += 512) atomicAdd(&bins[hidx[e]], 1);
    __syncthreads();
    for (int s = tid; s < M; s += 512) HE[(size_t)b * M + s] = bins[s];
  } else {
    int R = (y - 1) * VRANGE;
    int* HVr = HV + ((size_t)(y - 1) * NB_CSR + b) * VPACK;
    for (int q = tid; q < VPACK; q += 512) bins[q] = 0;
    __syncthreads();
    for (int e = e0 + tid; e < e1; e += 512) {
      int v = nidx[e] - R;
      if ((unsigned)v < (unsigned)VRANGE) atomicAdd(&bins[v >> 1], (v & 1) ? 0x10000 : 1);
    }
    __syncthreads();
    for (int q = tid; q < VPACK; q += 512) HVr[q] = bins[q];
  }
}

// Per-segment exclusive scan over the NB_CSR chunks (in place) + dense counts.
__global__ __launch_bounds__(256) void csr_colscan(int* __restrict__ HE,
                                                   int* __restrict__ HV,
                                                   int M, int N, int NVR,
                                                   int* __restrict__ cnt_e,
                                                   int* __restrict__ cnt_v) {
  int col = blockIdx.x * 256 + threadIdx.x;
  if (col < M) {
    int run = 0;
    for (int b = 0; b < NB_CSR; ++b) {
      size_t i = (size_t)b * M + col;
      int t = HE[i]; HE[i] = run; run += t;
    }
    cnt_e[col] = run;
  } else if (col < M + NVR * VPACK) {
    int c = col - M;
    int r = c / VPACK, q = c - r * VPACK;
    int* HVr = HV + (size_t)r * NB_CSR * VPACK;
    int run = 0;
    for (int b = 0; b < NB_CSR; ++b) {
      size_t i = (size_t)b * VPACK + q;
      int t = HVr[i]; HVr[i] = run; run += t;
    }
    int node = r * VRANGE + 2 * q;
    if (node < N) cnt_v[node] = run & 0xffff;
    if (node + 1 < N) cnt_v[node + 1] = run >> 16;
  }
}

// Scatter: preload LDS bins with global base (off + chunk-exclusive), LDS-atomic rank.
__global__ __launch_bounds__(512) void csr_scatter(const int* __restrict__ nidx,
                                                   const int* __restrict__ hidx,
                                                   int E, int M,
                                                   const int* __restrict__ HE,
                                                   const int* __restrict__ HV,
                                                   const int* __restrict__ off_e,
                                                   const int* __restrict__ off_v,
                                                   unsigned short* __restrict__ by_h,
                                                   unsigned short* __restrict__ by_v) {
  __shared__ int bins[VPACK];
  int b = blockIdx.x, y = blockIdx.y, tid = threadIdx.x;
  int chunk = (E + NB_CSR - 1) / NB_CSR;
  int e0 = b * chunk;
  int e1 = e0 + chunk; if (e1 > E) e1 = E;
  if (y == 0) {
    for (int s = tid; s < M; s += 512) bins[s] = off_e[s] + HE[(size_t)b * M + s];
    __syncthreads();
    for (int e = e0 + tid; e < e1; e += 512) {
      int pos = atomicAdd(&bins[hidx[e]], 1);
      by_h[pos] = (unsigned short)nidx[e];
    }
  } else {
    int R = (y - 1) * VRANGE;
    const int* HVr = HV + ((size_t)(y - 1) * NB_CSR + b) * VPACK;
    for (int q = tid; q < VPACK; q += 512) bins[q] = HVr[q];
    __syncthreads();
    for (int e = e0 + tid; e < e1; e += 512) {
      int v = nidx[e];
      int vr = v - R;
      if ((unsigned)vr < (unsigned)VRANGE) {
        int old = atomicAdd(&bins[vr >> 1], (vr & 1) ? 0x10000 : 1);
        int rank = (vr & 1) ? (old >> 16) : (old & 0xffff);
        by_v[off_v[v] + rank] = (unsigned short)hidx[e];
      }
    }
  }
}

// ---- fused 3-phase multi-block exclusive scan over both dense count arrays ----

__global__ __launch_bounds__(256) void scanA2(const int* __restrict__ inE, int nE, int nbE,
                                              int* __restrict__ partE,
                                              const int* __restrict__ inV, int nV,
                                              int* __restrict__ partV) {
  const int* in; int n, b; int* partials;
  if ((int)blockIdx.x < nbE) { in = inE; n = nE; b = blockIdx.x; partials = partE; }
  else { in = inV; n = nV; b = blockIdx.x - nbE; partials = partV; }
  __shared__ int lds[256];
  int tid = threadIdx.x;
  int base = b * SCAN_CHUNK + tid * 16;
  int s = 0;
#pragma unroll
  for (int i = 0; i < 16; ++i) {
    int idx = base + i;
    if (idx < n) s += in[idx];
  }
  lds[tid] = s;
  __syncthreads();
  for (int off = 128; off; off >>= 1) {
    if (tid < off) lds[tid] += lds[tid + off];
    __syncthreads();
  }
  if (tid == 0) partials[b] = lds[0];
}

__global__ __launch_bounds__(256) void scanB2(int* __restrict__ partE, int nbE,
                                              int* __restrict__ partV, int nbV) {
  int* partials = (blockIdx.x == 0) ? partE : partV;
  int nb = (blockIdx.x == 0) ? nbE : nbV;
  __shared__ int lds[256];
  int tid = threadIdx.x;
  int v = (tid < nb) ? partials[tid] : 0;
  lds[tid] = v;
  __syncthreads();
  for (int off = 1; off < 256; off <<= 1) {
    int add = (tid >= off) ? lds[tid - off] : 0;
    __syncthreads();
    lds[tid] += add;
    __syncthreads();
  }
  if (tid < nb) partials[tid] = lds[tid] - v;  // exclusive
  if (tid == nb - 1) partials[nb] = lds[tid];  // total
}

__global__ __launch_bounds__(256) void scanC2(const int* __restrict__ inE, int nE, int nbE,
                                              const int* __restrict__ partE, int* __restrict__ outE,
                                              const int* __restrict__ inV, int nV, int nbV,
                                              const int* __restrict__ partV, int* __restrict__ outV) {
  const int* in; const int* partials; int* out; int n, b, nb;
  if ((int)blockIdx.x < nbE) { in = inE; n = nE; b = blockIdx.x; partials = partE; out = outE; nb = nbE; }
  else { in = inV; n = nV; b = blockIdx.x - nbE; partials = partV; out = outV; nb = nbV; }
  __shared__ int lds[256];
  int tid = threadIdx.x;
  int base = b * SCAN_CHUNK + tid * 16;
  int vals[16];
  int s = 0;
#pragma unroll
  for (int i = 0; i < 16; ++i) {
    int idx = base + i;
    int v = (idx < n) ? in[idx] : 0;
    vals[i] = s;
    s += v;
  }
  lds[tid] = s;
  __syncthreads();
  int own = s;
  for (int off = 1; off < 256; off <<= 1) {
    int add = (tid >= off) ? lds[tid - off] : 0;
    __syncthreads();
    lds[tid] += add;
    __syncthreads();
  }
  int excl = lds[tid] - own + partials[b];
#pragma unroll
  for (int i = 0; i < 16; ++i) {
    int idx = base + i;
    if (idx < n) out[idx] = excl + vals[i];
  }
  if (b == 0 && tid == 0) out[n] = partials[nb];
}

// wqt = Wq^T * (1/sqrt(128)) [score scale folded]; wcat[:,128:256] = Wv.
__global__ void prep_att(const float* __restrict__ Wq, const float* __restrict__ Wv,
                         float* __restrict__ wqt, float* __restrict__ wcat) {
  int i = blockIdx.x * blockDim.x + threadIdx.x;  // 128*128
  if (i >= 128 * 128) return;
  int r = i >> 7, c = i & 127;
  wqt[c * 128 + r] = Wq[i] * 0.08838834764831845f;
  wcat[r * 256 + 128 + c] = Wv[i];
}

// ---------------- GEMM: 64x64 tile, 4x4 micro; fused input-norm / act / bf16-out / fp32+bf16 shadow ----------------

__global__ __launch_bounds__(256) void gemm64(const float* __restrict__ A,
                                              const float* __restrict__ W,
                                              const float* __restrict__ bias,
                                              float* __restrict__ out,
                                              int R, int K, int C, int act,
                                              const float* __restrict__ insc,
                                              const float* __restrict__ insh, int inact,
                                              int ldo, int obf16,
                                              unsigned short* __restrict__ out16) {
  __shared__ __align__(16) float As[64][20];
  __shared__ __align__(16) float Bs[16][64];
  int tid = threadIdx.x;
  int tx = tid & 15;
  int ty = tid >> 4;
  int rowBase = blockIdx.x * 64;
  int colBase = blockIdx.y * 64;

  float acc[4][4] = {};

  for (int k0 = 0; k0 < K; k0 += 16) {
    {
      int arow = tid >> 2, ac = (tid & 3) * 4;
      int gr = rowBase + arow;
      float4 av = make_float4(0.f, 0.f, 0.f, 0.f);
      if (gr < R) av = *(const float4*)(A + (size_t)gr * K + k0 + ac);
      if (insc) {
        float vv[4] = {av.x, av.y, av.z, av.w};
#pragma unroll
        for (int i = 0; i < 4; ++i) {
          float s = insc[k0 + ac + i], sh = insh[k0 + ac + i];
          float v = vv[i] * s + sh;
          if (inact) v = v > 0.f ? v : 0.01f * v;
          vv[i] = v;
        }
        av = make_float4(vv[0], vv[1], vv[2], vv[3]);
      }
      *(float4*)&As[arow][ac] = av;
    }
    {
      int bk = tid >> 4, bc = (tid & 15) * 4;
      *(float4*)&Bs[bk][bc] = *(const float4*)(W + (size_t)(k0 + bk) * C + colBase + bc);
    }
    __syncthreads();
#pragma unroll
    for (int kg = 0; kg < 16; kg += 4) {
      float af[4][4], bf[4][4];
#pragma unroll
      for (int i = 0; i < 4; ++i)
        *(float4*)af[i] = *(const float4*)&As[ty * 4 + i][kg];
#pragma unroll
      for (int kk = 0; kk < 4; ++kk)
        *(float4*)bf[kk] = *(const float4*)&Bs[kg + kk][tx * 4];
#pragma unroll
      for (int kk = 0; kk < 4; ++kk)
#pragma unroll
        for (int i = 0; i < 4; ++i)
#pragma unroll
          for (int j = 0; j < 4; ++j)
            acc[i][j] = fmaf(af[i][kk], bf[kk][j], acc[i][j]);
    }
    __syncthreads();
  }

#pragma unroll
  for (int i = 0; i < 4; ++i) {
    int r = rowBase + ty * 4 + i;
    if (r >= R) continue;
    float vals[4];
#pragma unroll
    for (int j = 0; j < 4; ++j) {
      float v = acc[i][j];
      if (bias) v += bias[colBase + tx * 4 + j];
      if (act) v = v > 0.f ? v : 0.01f * v;
      vals[j] = v;
    }
    if (obf16) {
      unsigned short* o16 = (unsigned short*)out;
      ushort4 w = make_ushort4(f2bf(vals[0]), f2bf(vals[1]), f2bf(vals[2]), f2bf(vals[3]));
      *(ushort4*)(o16 + (size_t)r * ldo + colBase + tx * 4) = w;
    } else {
      *(float4*)(out + (size_t)r * ldo + colBase + tx * 4) =
          make_float4(vals[0], vals[1], vals[2], vals[3]);
      if (out16) {
        uint2 w = make_uint2(packbf(vals[0], vals[1]), packbf(vals[2], vals[3]));
        *(uint2*)(out16 + (size_t)r * ldo + colBase + tx * 4) = w;
      }
    }
  }
}

// ---------------- segment ops: one wave per segment; 4 x 16-lane groups, 8 feats/lane ----------------
// Round-6 evidence: gather kernels are latency-bound on the 2-deep dependent chain
// idx load -> row load (att_fused: ~585 cyc/iter-slot at 4.8 waves/SIMD, VALU ~17%
// per-SIMD, HBM 26%). Fix: software pipeline — idx stream 3 stages ahead, row data
// 2-deep ping-pong. Accumulation order unchanged -> bit-identical results.

__global__ __launch_bounds__(256) void seg_mean_e(const unsigned short* __restrict__ h16,
                                                  const int* __restrict__ off_e,
                                                  const unsigned short* __restrict__ by_h,
                                                  unsigned short* __restrict__ m_e16, int M) {
  int m = (blockIdx.x * blockDim.x + threadIdx.x) >> 6;
  if (m >= M) return;
  int lane = threadIdx.x & 63;
  int g = lane >> 4;
  int fl = lane & 15;
  int s = off_e[m], e1 = off_e[m + 1];
  float4 a0 = make_float4(0.f, 0.f, 0.f, 0.f), a1 = a0;
  uint4 z4 = make_uint4(0, 0, 0, 0);
  int j = s + g;
  int iC = (j + 8 < e1) ? by_h[j + 8] : 0;
  uint4 hwA = z4, hwB = z4;
  if (j < e1) {
    int i0 = by_h[j];
    hwA = *(const uint4*)(h16 + (size_t)i0 * HF + fl * 8);
  }
  if (j + 4 < e1) {
    int i1 = by_h[j + 4];
    hwB = *(const uint4*)(h16 + (size_t)i1 * HF + fl * 8);
  }
  while (j < e1) {
    uint4 hwC = z4;
    if (j + 8 < e1) hwC = *(const uint4*)(h16 + (size_t)iC * HF + fl * 8);
    int iD = (j + 12 < e1) ? by_h[j + 12] : 0;
    a0.x += BFLO(hwA.x); a0.y += BFHI(hwA.x); a0.z += BFLO(hwA.y); a0.w += BFHI(hwA.y);
    a1.x += BFLO(hwA.z); a1.y += BFHI(hwA.z); a1.z += BFLO(hwA.w); a1.w += BFHI(hwA.w);
    hwA = hwB; hwB = hwC; iC = iD;
    j += 4;
  }
#pragma unroll
  for (int mask = 16; mask <= 32; mask <<= 1) {
    a0.x += __shfl_xor(a0.x, mask); a0.y += __shfl_xor(a0.y, mask);
    a0.z += __shfl_xor(a0.z, mask); a0.w += __shfl_xor(a0.w, mask);
    a1.x += __shfl_xor(a1.x, mask); a1.y += __shfl_xor(a1.y, mask);
    a1.z += __shfl_xor(a1.z, mask); a1.w += __shfl_xor(a1.w, mask);
  }
  if (g == 0) {
    int cnt = e1 - s;
    float r = 1.f / (float)(cnt > 0 ? cnt : 1);
    uint4 w = make_uint4(packbf(a0.x * r, a0.y * r), packbf(a0.z * r, a0.w * r),
                         packbf(a1.x * r, a1.y * r), packbf(a1.z * r, a1.w * r));
    *(uint4*)(m_e16 + (size_t)m * HF + fl * 8) = w;
  }
}

__global__ __launch_bounds__(256) void seg_mean_v_add(float* __restrict__ h,
                                                      const unsigned short* __restrict__ m_e16,
                                                      const int* __restrict__ off_v,
                                                      const unsigned short* __restrict__ by_v,
                                                      int N) {
  int n = (blockIdx.x * blockDim.x + threadIdx.x) >> 6;
  if (n >= N) return;
  int lane = threadIdx.x & 63;
  int g = lane >> 4;
  int fl = lane & 15;
  int s = off_v[n], e1 = off_v[n + 1];
  float4 a0 = make_float4(0.f, 0.f, 0.f, 0.f), a1 = a0;
  uint4 z4 = make_uint4(0, 0, 0, 0);
  int j = s + g;
  int iC = (j + 8 < e1) ? by_v[j + 8] : 0;
  uint4 hwA = z4, hwB = z4;
  if (j < e1) {
    int i0 = by_v[j];
    hwA = *(const uint4*)(m_e16 + (size_t)i0 * HF + fl * 8);
  }
  if (j + 4 < e1) {
    int i1 = by_v[j + 4];
    hwB = *(const uint4*)(m_e16 + (size_t)i1 * HF + fl * 8);
  }
  while (j < e1) {
    uint4 hwC = z4;
    if (j + 8 < e1) hwC = *(const uint4*)(m_e16 + (size_t)iC * HF + fl * 8);
    int iD = (j + 12 < e1) ? by_v[j + 12] : 0;
    a0.x += BFLO(hwA.x); a0.y += BFHI(hwA.x); a0.z += BFLO(hwA.y); a0.w += BFHI(hwA.y);
    a1.x += BFLO(hwA.z); a1.y += BFHI(hwA.z); a1.z += BFLO(hwA.w); a1.w += BFHI(hwA.w);
    hwA = hwB; hwB = hwC; iC = iD;
    j += 4;
  }
#pragma unroll
  for (int mask = 16; mask <= 32; mask <<= 1) {
    a0.x += __shfl_xor(a0.x, mask); a0.y += __shfl_xor(a0.y, mask);
    a0.z += __shfl_xor(a0.z, mask); a0.w += __shfl_xor(a0.w, mask);
    a1.x += __shfl_xor(a1.x, mask); a1.y += __shfl_xor(a1.y, mask);
    a1.z += __shfl_xor(a1.z, mask); a1.w += __shfl_xor(a1.w, mask);
  }
  if (g == 0) {
    int cnt = e1 - s;
    float r = 1.f / (float)(cnt > 0 ? cnt : 1);
    float* hp = h + (size_t)n * HF + fl * 8;
    float4 h0 = *(const float4*)hp;
    float4 h1 = *(const float4*)(hp + 4);
    *(float4*)hp = make_float4(h0.x + a0.x * r, h0.y + a0.y * r, h0.z + a0.z * r, h0.w + a0.w * r);
    *(float4*)(hp + 4) = make_float4(h1.x + a1.x * r, h1.y + a1.y * r, h1.z + a1.z * r, h1.w + a1.w * r);
  }
}

// Fused GAT attention: one wave per node; q = h2 (fp32, score scale pre-folded into Wqk);
// kv bf16 [M][256]; 2-deep kv pipeline + idx 3-ahead; defer-max rescale (THR=8).
__global__ __launch_bounds__(256) void att_fused(const float* __restrict__ q,
                                                 const unsigned short* __restrict__ kv,
                                                 const int* __restrict__ off_v,
                                                 const unsigned short* __restrict__ by_v,
                                                 unsigned short* __restrict__ ho16, int N) {
  int n = (blockIdx.x * blockDim.x + threadIdx.x) >> 6;
  if (n >= N) return;
  int lane = threadIdx.x & 63;
  int g = lane >> 4;
  int fl = lane & 15;
  int s0 = off_v[n], s1 = off_v[n + 1];
  const float* qp = q + (size_t)n * HF + fl * 8;
  float4 q0 = *(const float4*)qp;
  float4 q1 = *(const float4*)(qp + 4);
  float m = -INFINITY, l = 0.f;
  float4 a0 = make_float4(0.f, 0.f, 0.f, 0.f), a1 = a0;
  uint4 z4 = make_uint4(0, 0, 0, 0);
  int j = s0 + g;
  int iC = (j + 8 < s1) ? by_v[j + 8] : 0;
  uint4 kwA = z4, vwA = z4, kwB = z4, vwB = z4;
  if (j < s1) {
    const unsigned short* b = kv + (size_t)by_v[j] * 256 + fl * 8;
    kwA = *(const uint4*)b;
    vwA = *(const uint4*)(b + 128);
  }
  if (j + 4 < s1) {
    const unsigned short* b = kv + (size_t)by_v[j + 4] * 256 + fl * 8;
    kwB = *(const uint4*)b;
    vwB = *(const uint4*)(b + 128);
  }
  while (j < s1) {
    uint4 kwC = z4, vwC = z4;
    if (j + 8 < s1) {
      const unsigned short* b = kv + (size_t)iC * 256 + fl * 8;
      kwC = *(const uint4*)b;
      vwC = *(const uint4*)(b + 128);
    }
    int iD = (j + 12 < s1) ? by_v[j + 12] : 0;
    float d = q0.x * BFLO(kwA.x) + q0.y * BFHI(kwA.x) + q0.z * BFLO(kwA.y) + q0.w * BFHI(kwA.y)
            + q1.x * BFLO(kwA.z) + q1.y * BFHI(kwA.z) + q1.z * BFLO(kwA.w) + q1.w * BFHI(kwA.w);
    d += __shfl_xor(d, 1);
    d += __shfl_xor(d, 2);
    d += __shfl_xor(d, 4);
    d += __shfl_xor(d, 8);
    d = d > 0.f ? d : 0.2f * d;   // scale already folded into Wqk
    if (d > m + 8.f) {
      float sc = __expf(m - d);   // first edge: exp(-inf)=0 zeroes l,a
      l *= sc;
      a0.x *= sc; a0.y *= sc; a0.z *= sc; a0.w *= sc;
      a1.x *= sc; a1.y *= sc; a1.z *= sc; a1.w *= sc;
      m = d;
    }
    float p = __expf(d - m);
    l += p;
    a0.x += p * BFLO(vwA.x); a0.y += p * BFHI(vwA.x);
    a0.z += p * BFLO(vwA.y); a0.w += p * BFHI(vwA.y);
    a1.x += p * BFLO(vwA.z); a1.y += p * BFHI(vwA.z);
    a1.z += p * BFLO(vwA.w); a1.w += p * BFHI(vwA.w);
    kwA = kwB; vwA = vwB; kwB = kwC; vwB = vwC; iC = iD;
    j += 4;
  }
#pragma unroll
  for (int mask = 16; mask <= 32; mask <<= 1) {
    float m2 = __shfl_xor(m, mask);
    float l2 = __shfl_xor(l, mask);
    float b0x = __shfl_xor(a0.x, mask), b0y = __shfl_xor(a0.y, mask);
    float b0z = __shfl_xor(a0.z, mask), b0w = __shfl_xor(a0.w, mask);
    float b1x = __shfl_xor(a1.x, mask), b1y = __shfl_xor(a1.y, mask);
    float b1z = __shfl_xor(a1.z, mask), b1w = __shfl_xor(a1.w, mask);
    float mn = fmaxf(fmaxf(m, m2), -1e30f);
    float ea = __expf(m - mn), eb = __expf(m2 - mn);
    l = l * ea + l2 * eb;
    a0.x = a0.x * ea + b0x * eb; a0.y = a0.y * ea + b0y * eb;
    a0.z = a0.z * ea + b0z * eb; a0.w = a0.w * ea + b0w * eb;
    a1.x = a1.x * ea + b1x * eb; a1.y = a1.y * ea + b1y * eb;
    a1.z = a1.z * ea + b1z * eb; a1.w = a1.w * ea + b1w * eb;
    m = fmaxf(m, m2);
  }
  if (g == 0) {
    float inv = 1.f / fmaxf(l, 1e-16f);
    uint4 w = make_uint4(packbf(a0.x * inv, a0.y * inv), packbf(a0.z * inv, a0.w * inv),
                         packbf(a1.x * inv, a1.y * inv), packbf(a1.z * inv, a1.w * inv));
    *(uint4*)(ho16 + (size_t)n * HF + fl * 8) = w;
  }
}

// z[m][0:128] = segment_min(ho16[node]) (0 if empty); z[m][128:256] = xe[m]
__global__ __launch_bounds__(256) void seg_min_z(const unsigned short* __restrict__ ho16,
                                                 const int* __restrict__ off_e,
                                                 const unsigned short* __restrict__ by_h,
                                                 const float* __restrict__ xe,
                                                 float* __restrict__ z, int M) {
  int m = (blockIdx.x * blockDim.x + threadIdx.x) >> 6;
  if (m >= M) return;
  int lane = threadIdx.x & 63;
  int g = lane >> 4;
  int fl = lane & 15;
  int s = off_e[m], e1 = off_e[m + 1];
  float4 a0 = make_float4(FLT_MAX, FLT_MAX, FLT_MAX, FLT_MAX), a1 = a0;
  uint4 z4 = make_uint4(0, 0, 0, 0);
  int j = s + g;
  int iC = (j + 8 < e1) ? by_h[j + 8] : 0;
  uint4 hwA = z4, hwB = z4;
  if (j < e1) {
    int i0 = by_h[j];
    hwA = *(const uint4*)(ho16 + (size_t)i0 * HF + fl * 8);
  }
  if (j + 4 < e1) {
    int i1 = by_h[j + 4];
    hwB = *(const uint4*)(ho16 + (size_t)i1 * HF + fl * 8);
  }
  while (j < e1) {
    uint4 hwC = z4;
    if (j + 8 < e1) hwC = *(const uint4*)(ho16 + (size_t)iC * HF + fl * 8);
    int iD = (j + 12 < e1) ? by_h[j + 12] : 0;
    a0.x = fminf(a0.x, BFLO(hwA.x)); a0.y = fminf(a0.y, BFHI(hwA.x));
    a0.z = fminf(a0.z, BFLO(hwA.y)); a0.w = fminf(a0.w, BFHI(hwA.y));
    a1.x = fminf(a1.x, BFLO(hwA.z)); a1.y = fminf(a1.y, BFHI(hwA.z));
    a1.z = fminf(a1.z, BFLO(hwA.w)); a1.w = fminf(a1.w, BFHI(hwA.w));
    hwA = hwB; hwB = hwC; iC = iD;
    j += 4;
  }
#pragma unroll
  for (int mask = 16; mask <= 32; mask <<= 1) {
    a0.x = fminf(a0.x, __shfl_xor(a0.x, mask)); a0.y = fminf(a0.y, __shfl_xor(a0.y, mask));
    a0.z = fminf(a0.z, __shfl_xor(a0.z, mask)); a0.w = fminf(a0.w, __shfl_xor(a0.w, mask));
    a1.x = fminf(a1.x, __shfl_xor(a1.x, mask)); a1.y = fminf(a1.y, __shfl_xor(a1.y, mask));
    a1.z = fminf(a1.z, __shfl_xor(a1.z, mask)); a1.w = fminf(a1.w, __shfl_xor(a1.w, mask));
  }
  if (g == 0) {
    bool nz = (e1 > s);
    float* op = z + (size_t)m * 256 + fl * 8;
    *(float4*)op = nz ? a0 : make_float4(0.f, 0.f, 0.f, 0.f);
    *(float4*)(op + 4) = nz ? a1 : make_float4(0.f, 0.f, 0.f, 0.f);
  } else if (g == 1) {
    const float* xp = xe + (size_t)m * HF + fl * 8;
    float* op = z + (size_t)m * 256 + 128 + fl * 8;
    *(float4*)op = *(const float4*)xp;
    *(float4*)(op + 4) = *(const float4*)(xp + 4);
  }
}

// ---------------- GraphNorm stats: two-kernel deterministic reduction ----------------

__global__ __launch_bounds__(1024) void colstats_part(const float* __restrict__ z, int rows, int C,
                                                      float* __restrict__ part) {
  int tid = threadIdx.x;
  int RL = 1024 / C;
  int col = tid & (C - 1);
  int ro = tid / C;
  float s1 = 0.f, s2 = 0.f;
  for (int r = blockIdx.x * RL + ro; r < rows; r += gridDim.x * RL) {
    float v = z[(size_t)r * C + col];
    s1 += v;
    s2 += v * v;
  }
  __shared__ float l1[1024], l2[1024];
  l1[tid] = s1;
  l2[tid] = s2;
  __syncthreads();
  for (int off = 512; off >= C; off >>= 1) {
    if (tid < off) { l1[tid] += l1[tid + off]; l2[tid] += l2[tid + off]; }
    __syncthreads();
  }
  if (tid < C) {
    part[(size_t)blockIdx.x * 2 * C + tid] = l1[tid];
    part[(size_t)blockIdx.x * 2 * C + C + tid] = l2[tid];
  }
}

__global__ void colstats_fin(const float* __restrict__ part, int nb, int C,
                             const float* __restrict__ w, const float* __restrict__ b,
                             const float* __restrict__ a, float invrows,
                             float* __restrict__ sc, float* __restrict__ sh) {
  int col = threadIdx.x;
  if (col >= C) return;
  float s1 = 0.f, s2 = 0.f;
#pragma unroll 8
  for (int i = 0; i < nb; ++i) {
    s1 += part[(size_t)i * 2 * C + col];
    s2 += part[(size_t)i * 2 * C + C + col];
  }
  float mu = s1 * invrows;
  float ex2 = s2 * invrows;
  float av = a[col];
  float var = ex2 - 2.f * av * mu * mu + av * av * mu * mu;
  float s = w[col] * rsqrtf(var + 1e-5f);
  sc[col] = s;
  sh[col] = b[col] - av * mu * s;
}

// ---------------- launch ----------------

extern "C" void kernel_launch(void* const* d_in, const int* in_sizes, int n_in,
                              void* d_out, int out_size, void* d_ws, size_t ws_size,
                              hipStream_t stream) {
  const float* x        = (const float*)d_in[0];
  const float* x_e      = (const float*)d_in[2];
  const int*   node_idx = (const int*)d_in[3];
  const int*   hedge_idx= (const int*)d_in[4];
  const float* her_W1   = (const float*)d_in[5];
  const float* her_b1   = (const float*)d_in[6];
  const float* her_W2   = (const float*)d_in[7];
  const float* her_b2   = (const float*)d_in[8];
  const float* sr_W1    = (const float*)d_in[9];
  const float* sr_b1    = (const float*)d_in[10];
  const float* sr_W2    = (const float*)d_in[11];
  const float* sr_b2    = (const float*)d_in[12];
  const float* att_Wq   = (const float*)d_in[13];
  const float* att_Wk   = (const float*)d_in[14];
  const float* att_Wv   = (const float*)d_in[15];
  const float* ef_W     = (const float*)d_in[16];
  const float* ef_b     = (const float*)d_in[17];
  const float* gn1_w    = (const float*)d_in[18];
  const float* gn1_b    = (const float*)d_in[19];
  const float* gn1_a    = (const float*)d_in[20];
  const float* gn2_w    = (const float*)d_in[21];
  const float* gn2_b    = (const float*)d_in[22];
  const float* gn2_a    = (const float*)d_in[23];
  const float* cls_W1   = (const float*)d_in[24];
  const float* cls_b1   = (const float*)d_in[25];
  const float* cls_W2   = (const float*)d_in[26];
  const float* cls_b2   = (const float*)d_in[27];

  const int N = in_sizes[0] / HF;
  const int M = in_sizes[2] / HF;
  const int E = in_sizes[3];
  const int NVR = idiv(N, VRANGE);  // node range count (2 for N=50000)

  // ---- workspace layout (nothing needs zeroing: counting sort writes every cell) ----
  char* wp = (char*)d_ws;
  float* part1 = (float*)wp; wp += (size_t)CS_GRID * 512 * 4;  // gn1 partials (2*256 per blk)
  float* part2 = (float*)wp; wp += (size_t)CS_GRID * 256 * 4;  // gn2 partials (2*128 per blk)
  int* cnt_e = (int*)wp; wp += (size_t)M * 4;
  int* cnt_v = (int*)wp; wp += (size_t)N * 4;
  int* off_e = (int*)wp; wp += (size_t)(M + 1) * 4;
  int* off_v = (int*)wp; wp += (size_t)(N + 1) * 4;
  unsigned short* by_h = (unsigned short*)wp; wp += ((size_t)E * 2 + 3) & ~(size_t)3;
  unsigned short* by_v = (unsigned short*)wp; wp += ((size_t)E * 2 + 3) & ~(size_t)3;
  int* part_e = (int*)wp; wp += 257 * 4;
  int* part_v = (int*)wp; wp += 257 * 4;
  float* sc1 = (float*)wp; wp += 256 * 4;
  float* sh1 = (float*)wp; wp += 256 * 4;
  float* sc2 = (float*)wp; wp += 128 * 4;
  float* sh2 = (float*)wp; wp += 128 * 4;
  wp = (char*)(((uintptr_t)wp + 255) & ~(uintptr_t)255);
  float* wqt  = (float*)wp; wp += (size_t)128 * 128 * 4;   // Wq^T * scale
  float* wcat = (float*)wp; wp += (size_t)128 * 256 * 4;   // [Wqk | Wv]
  float* h   = (float*)wp; wp += (size_t)N * HF * 4;       // sr1 out, += m_v, sr2 in; later c1
  float* h2  = (float*)wp; wp += (size_t)N * HF * 4;       // sr2 out = q; later z [M,256]
  float* xe  = (float*)wp; wp += (size_t)M * HF * 4;
  float* kvf = (float*)wp; wp += (size_t)M * 256 * 4;      // t1 fp32 alias / kv bf16
  float* z2  = (float*)wp; wp += (size_t)M * HF * 4;
  unsigned short* h16   = (unsigned short*)wp; wp += (size_t)N * HF * 2;  // sr1 bf16 shadow
  unsigned short* ho16  = (unsigned short*)wp; wp += (size_t)N * HF * 2;  // att out bf16
  unsigned short* m_e16 = (unsigned short*)wp; wp += (size_t)M * HF * 2;

  unsigned short* kv = (unsigned short*)kvf;   // [M][256] bf16
  float* t1  = kvf;                // her hidden [M,128] fp32 (dead before kv written)
  float* z   = h2;                 // [M,256] (h2 dead as q after att_fused)
  float* c1  = h;                  // [M,128] (h dead after sr2)

  // Histogram matrices alias h (dead until sr1): NB*M + NVR*NB*VPACK ints = 17.9MB < 25.6MB
  int* HE = (int*)h;
  int* HV = HE + (size_t)NB_CSR * M;

  // ---- CSR build: counting sort, zero device-scope atomics ----
  csr_hist<<<dim3(NB_CSR, 1 + NVR), 512, 0, stream>>>(node_idx, hedge_idx, E, M, HE, HV);
  csr_colscan<<<idiv(M + NVR * VPACK, 256), 256, 0, stream>>>(HE, HV, M, N, NVR, cnt_e, cnt_v);
  int nbE = idiv(M, SCAN_CHUNK);
  int nbV = idiv(N, SCAN_CHUNK);
  scanA2<<<nbE + nbV, 256, 0, stream>>>(cnt_e, M, nbE, part_e, cnt_v, N, part_v);
  scanB2<<<2, 256, 0, stream>>>(part_e, nbE, part_v, nbV);
  scanC2<<<nbE + nbV, 256, 0, stream>>>(cnt_e, M, nbE, part_e, off_e, cnt_v, N, nbV, part_v, off_v);
  csr_scatter<<<dim3(NB_CSR, 1 + NVR), 512, 0, stream>>>(node_idx, hedge_idx, E, M, HE, HV,
                                                         off_e, off_v, by_h, by_v);

  // wqt = Wq^T*scale, wcat right = Wv; then wcat left = Wk @ wqt
  prep_att<<<64, 256, 0, stream>>>(att_Wq, att_Wv, wqt, wcat);
  gemm64<<<dim3(2, 2), 256, 0, stream>>>(att_Wk, wqt, nullptr, wcat, 128, 128, 128, 0,
                                         nullptr, nullptr, 0, 256, 0, nullptr);

  dim3 blk(256);
  // her MLP: xe
  gemm64<<<dim3(idiv(M, 64), 2), blk, 0, stream>>>(x_e, her_W1, her_b1, t1, M, HF, HF, 1,
                                                   nullptr, nullptr, 0, HF, 0, nullptr);
  gemm64<<<dim3(idiv(M, 64), 2), blk, 0, stream>>>(t1, her_W2, her_b2, xe, M, HF, HF, 0,
                                                   nullptr, nullptr, 0, HF, 0, nullptr);
  // sr layer1 (fp32 + bf16 shadow), 64x64 tiles -> 1564 blocks (overwrites HE/HV)
  gemm64<<<dim3(idiv(N, 64), 2), blk, 0, stream>>>(x, sr_W1, sr_b1, h, N, HF, HF, 1,
                                                   nullptr, nullptr, 0, HF, 0, h16);
  // message passing means (bf16 gathers, 2-deep pipelined)
  seg_mean_e<<<idiv(M * 64, 256), blk, 0, stream>>>(h16, off_e, by_h, m_e16, M);
  seg_mean_v_add<<<idiv(N * 64, 256), blk, 0, stream>>>(h, m_e16, off_v, by_v, N);
  // sr layer2 -> h2 (doubles as q)
  gemm64<<<dim3(idiv(N, 64), 2), blk, 0, stream>>>(h, sr_W2, sr_b2, h2, N, HF, HF, 1,
                                                   nullptr, nullptr, 0, HF, 0, nullptr);
  // kv projection: [xe@Wqk | xe@Wv] in bf16
  gemm64<<<dim3(idiv(M, 64), 4), blk, 0, stream>>>(xe, wcat, nullptr, (float*)kv, M, HF, 256, 0,
                                                   nullptr, nullptr, 0, 256, 1, nullptr);
  // fused attention (q = h2)
  att_fused<<<idiv(N * 64, 256), blk, 0, stream>>>(h2, kv, off_v, by_v, ho16, N);
  // min aggregation + concat (z overwrites h2)
  seg_min_z<<<idiv(M * 64, 256), blk, 0, stream>>>(ho16, off_e, by_h, xe, z, M);
  // gn1 stats (partials + finalize) -> ef linear(+act) -> gn2 stats
  colstats_part<<<CS_GRID, 1024, 0, stream>>>(z, M, 256, part1);
  colstats_fin<<<1, 256, 0, stream>>>(part1, CS_GRID, 256, gn1_w, gn1_b, gn1_a,
                                      1.f / (float)M, sc1, sh1);
  gemm64<<<dim3(idiv(M, 64), 2), blk, 0, stream>>>(z, ef_W, ef_b, z2, M, 2 * HF, HF, 1,
                                                   sc1, sh1, 0, HF, 0, nullptr);
  colstats_part<<<CS_GRID, 1024, 0, stream>>>(z2, M, 128, part2);
  colstats_fin<<<1, 128, 0, stream>>>(part2, CS_GRID, 128, gn2_w, gn2_b, gn2_a,
                                      1.f / (float)M, sc2, sh2);
  // classifier
  gemm64<<<dim3(idiv(M, 64), 2), blk, 0, stream>>>(z2, cls_W1, cls_b1, c1, M, HF, HF, 1,
                                                   sc2, sh2, 1, HF, 0, nullptr);
  gemm64<<<dim3(idiv(M, 64), 1), blk, 0, stream>>>(c1, cls_W2, cls_b2, (float*)d_out, M, HF, 64, 0,
                                                   nullptr, nullptr, 0, 64, 0, nullptr);
}

// Round 8
// 384.386 us; speedup vs baseline: 1.7381x; 1.0029x over previous
//
#include <hip/hip_runtime.h>
#include <float.h>
#include <math.h>

#define HF 128
#define SCAN_CHUNK 4096  // 256 threads x 16 elems
#define NB_CSR 128       // chunks for counting-sort CSR build
#define VPACK 12500      // packed (2-per-int) node bins per range: 25000 nodes / range
#define VRANGE (2 * VPACK)
#define CS_GRID 256      // colstats_part grid (per-block partials, no atomics)

static inline int idiv(int a, int b) { return (a + b - 1) / b; }

__device__ inline unsigned short f2bf(float x) {  // RNE float->bf16
  unsigned u = __float_as_uint(x);
  return (unsigned short)((u + 0x7fffu + ((u >> 16) & 1u)) >> 16);
}
__device__ inline unsigned packbf(float a, float b) {
  return (unsigned)f2bf(a) | ((unsigned)f2bf(b) << 16);
}
#define BFLO(w) __uint_as_float((w) << 16)
#define BFHI(w) __uint_as_float((w) & 0xffff0000u)

// ---------------- CSR build: LDS-histogram counting sort (ZERO device-scope atomics) ----------------
// Round-2 evidence: 1.2M global atomics = 24.7 G/s RMW wall (48.5us, invariant to
// occupancy/batching). Replaced by per-chunk LDS histograms + column scan + scatter.

__global__ __launch_bounds__(512) void csr_hist(const int* __restrict__ nidx,
                                                const int* __restrict__ hidx,
                                                int E, int M,
                                                int* __restrict__ HE,
                                                int* __restrict__ HV) {
  __shared__ int bins[VPACK];
  int b = blockIdx.x, y = blockIdx.y, tid = threadIdx.x;
  int chunk = (E + NB_CSR - 1) / NB_CSR;
  int e0 = b * chunk;
  int e1 = e0 + chunk; if (e1 > E) e1 = E;
  if (y == 0) {
    for (int s = tid; s < M; s += 512) bins[s] = 0;
    __syncthreads();
    for (int e = e0 + tid; e < e1; e += 512) atomicAdd(&bins[hidx[e]], 1);
    __syncthreads();
    for (int s = tid; s < M; s += 512) HE[(size_t)b * M + s] = bins[s];
  } else {
    int R = (y - 1) * VRANGE;
    int* HVr = HV + ((size_t)(y - 1) * NB_CSR + b) * VPACK;
    for (int q = tid; q < VPACK; q += 512) bins[q] = 0;
    __syncthreads();
    for (int e = e0 + tid; e < e1; e += 512) {
      int v = nidx[e] - R;
      if ((unsigned)v < (unsigned)VRANGE) atomicAdd(&bins[v >> 1], (v & 1) ? 0x10000 : 1);
    }
    __syncthreads();
    for (int q = tid; q < VPACK; q += 512) HVr[q] = bins[q];
  }
}

// Per-segment exclusive scan over the NB_CSR chunks (in place) + dense counts.
__global__ __launch_bounds__(256) void csr_colscan(int* __restrict__ HE,
                                                   int* __restrict__ HV,
                                                   int M, int N, int NVR,
                                                   int* __restrict__ cnt_e,
                                                   int* __restrict__ cnt_v) {
  int col = blockIdx.x * 256 + threadIdx.x;
  if (col < M) {
    int run = 0;
    for (int b = 0; b < NB_CSR; ++b) {
      size_t i = (size_t)b * M + col;
      int t = HE[i]; HE[i] = run; run += t;
    }
    cnt_e[col] = run;
  } else if (col < M + NVR * VPACK) {
    int c = col - M;
    int r = c / VPACK, q = c - r * VPACK;
    int* HVr = HV + (size_t)r * NB_CSR * VPACK;
    int run = 0;
    for (int b = 0; b < NB_CSR; ++b) {
      size_t i = (size_t)b * VPACK + q;
      int t = HVr[i]; HVr[i] = run; run += t;
    }
    int node = r * VRANGE + 2 * q;
    if (node < N) cnt_v[node] = run & 0xffff;
    if (node + 1 < N) cnt_v[node + 1] = run >> 16;
  }
}

// Scatter: preload LDS bins with global base (off + chunk-exclusive), LDS-atomic rank.
__global__ __launch_bounds__(512) void csr_scatter(const int* __restrict__ nidx,
                                                   const int* __restrict__ hidx,
                                                   int E, int M,
                                                   const int* __restrict__ HE,
                                                   const int* __restrict__ HV,
                                                   const int* __restrict__ off_e,
                                                   const int* __restrict__ off_v,
                                                   unsigned short* __restrict__ by_h,
                                                   unsigned short* __restrict__ by_v) {
  __shared__ int bins[VPACK];
  int b = blockIdx.x, y = blockIdx.y, tid = threadIdx.x;
  int chunk = (E + NB_CSR - 1) / NB_CSR;
  int e0 = b * chunk;
  int e1 = e0 + chunk; if (e1 > E) e1 = E;
  if (y == 0) {
    for (int s = tid; s < M; s += 512) bins[s] = off_e[s] + HE[(size_t)b * M + s];
    __syncthreads();
    for (int e = e0 + tid; e < e1; e += 512) {
      int pos = atomicAdd(&bins[hidx[e]], 1);
      by_h[pos] = (unsigned short)nidx[e];
    }
  } else {
    int R = (y - 1) * VRANGE;
    const int* HVr = HV + ((size_t)(y - 1) * NB_CSR + b) * VPACK;
    for (int q = tid; q < VPACK; q += 512) bins[q] = HVr[q];
    __syncthreads();
    for (int e = e0 + tid; e < e1; e += 512) {
      int v = nidx[e];
      int vr = v - R;
      if ((unsigned)vr < (unsigned)VRANGE) {
        int old = atomicAdd(&bins[vr >> 1], (vr & 1) ? 0x10000 : 1);
        int rank = (vr & 1) ? (old >> 16) : (old & 0xffff);
        by_v[off_v[v] + rank] = (unsigned short)hidx[e];
      }
    }
  }
}

// ---- fused 3-phase multi-block exclusive scan over both dense count arrays ----

__global__ __launch_bounds__(256) void scanA2(const int* __restrict__ inE, int nE, int nbE,
                                              int* __restrict__ partE,
                                              const int* __restrict__ inV, int nV,
                                              int* __restrict__ partV) {
  const int* in; int n, b; int* partials;
  if ((int)blockIdx.x < nbE) { in = inE; n = nE; b = blockIdx.x; partials = partE; }
  else { in = inV; n = nV; b = blockIdx.x - nbE; partials = partV; }
  __shared__ int lds[256];
  int tid = threadIdx.x;
  int base = b * SCAN_CHUNK + tid * 16;
  int s = 0;
#pragma unroll
  for (int i = 0; i < 16; ++i) {
    int idx = base + i;
    if (idx < n) s += in[idx];
  }
  lds[tid] = s;
  __syncthreads();
  for (int off = 128; off; off >>= 1) {
    if (tid < off) lds[tid] += lds[tid + off];
    __syncthreads();
  }
  if (tid == 0) partials[b] = lds[0];
}

__global__ __launch_bounds__(256) void scanB2(int* __restrict__ partE, int nbE,
                                              int* __restrict__ partV, int nbV) {
  int* partials = (blockIdx.x == 0) ? partE : partV;
  int nb = (blockIdx.x == 0) ? nbE : nbV;
  __shared__ int lds[256];
  int tid = threadIdx.x;
  int v = (tid < nb) ? partials[tid] : 0;
  lds[tid] = v;
  __syncthreads();
  for (int off = 1; off < 256; off <<= 1) {
    int add = (tid >= off) ? lds[tid - off] : 0;
    __syncthreads();
    lds[tid] += add;
    __syncthreads();
  }
  if (tid < nb) partials[tid] = lds[tid] - v;  // exclusive
  if (tid == nb - 1) partials[nb] = lds[tid];  // total
}

__global__ __launch_bounds__(256) void scanC2(const int* __restrict__ inE, int nE, int nbE,
                                              const int* __restrict__ partE, int* __restrict__ outE,
                                              const int* __restrict__ inV, int nV, int nbV,
                                              const int* __restrict__ partV, int* __restrict__ outV) {
  const int* in; const int* partials; int* out; int n, b, nb;
  if ((int)blockIdx.x < nbE) { in = inE; n = nE; b = blockIdx.x; partials = partE; out = outE; nb = nbE; }
  else { in = inV; n = nV; b = blockIdx.x - nbE; partials = partV; out = outV; nb = nbV; }
  __shared__ int lds[256];
  int tid = threadIdx.x;
  int base = b * SCAN_CHUNK + tid * 16;
  int vals[16];
  int s = 0;
#pragma unroll
  for (int i = 0; i < 16; ++i) {
    int idx = base + i;
    int v = (idx < n) ? in[idx] : 0;
    vals[i] = s;
    s += v;
  }
  lds[tid] = s;
  __syncthreads();
  int own = s;
  for (int off = 1; off < 256; off <<= 1) {
    int add = (tid >= off) ? lds[tid - off] : 0;
    __syncthreads();
    lds[tid] += add;
    __syncthreads();
  }
  int excl = lds[tid] - own + partials[b];
#pragma unroll
  for (int i = 0; i < 16; ++i) {
    int idx = base + i;
    if (idx < n) out[idx] = excl + vals[i];
  }
  if (b == 0 && tid == 0) out[n] = partials[nb];
}

// wqt = Wq^T * (1/sqrt(128)) [score scale folded]; wcat[:,128:256] = Wv.
__global__ void prep_att(const float* __restrict__ Wq, const float* __restrict__ Wv,
                         float* __restrict__ wqt, float* __restrict__ wcat) {
  int i = blockIdx.x * blockDim.x + threadIdx.x;  // 128*128
  if (i >= 128 * 128) return;
  int r = i >> 7, c = i & 127;
  wqt[c * 128 + r] = Wq[i] * 0.08838834764831845f;
  wcat[r * 256 + 128 + c] = Wv[i];
}

// ---------------- GEMM: 64x64 tile, 4x4 micro; fused input-norm / act / bf16-out / fp32+bf16 shadow ----------------

__global__ __launch_bounds__(256) void gemm64(const float* __restrict__ A,
                                              const float* __restrict__ W,
                                              const float* __restrict__ bias,
                                              float* __restrict__ out,
                                              int R, int K, int C, int act,
                                              const float* __restrict__ insc,
                                              const float* __restrict__ insh, int inact,
                                              int ldo, int obf16,
                                              unsigned short* __restrict__ out16) {
  __shared__ __align__(16) float As[64][20];
  __shared__ __align__(16) float Bs[16][64];
  int tid = threadIdx.x;
  int tx = tid & 15;
  int ty = tid >> 4;
  int rowBase = blockIdx.x * 64;
  int colBase = blockIdx.y * 64;

  float acc[4][4] = {};

  for (int k0 = 0; k0 < K; k0 += 16) {
    {
      int arow = tid >> 2, ac = (tid & 3) * 4;
      int gr = rowBase + arow;
      float4 av = make_float4(0.f, 0.f, 0.f, 0.f);
      if (gr < R) av = *(const float4*)(A + (size_t)gr * K + k0 + ac);
      if (insc) {
        float vv[4] = {av.x, av.y, av.z, av.w};
#pragma unroll
        for (int i = 0; i < 4; ++i) {
          float s = insc[k0 + ac + i], sh = insh[k0 + ac + i];
          float v = vv[i] * s + sh;
          if (inact) v = v > 0.f ? v : 0.01f * v;
          vv[i] = v;
        }
        av = make_float4(vv[0], vv[1], vv[2], vv[3]);
      }
      *(float4*)&As[arow][ac] = av;
    }
    {
      int bk = tid >> 4, bc = (tid & 15) * 4;
      *(float4*)&Bs[bk][bc] = *(const float4*)(W + (size_t)(k0 + bk) * C + colBase + bc);
    }
    __syncthreads();
#pragma unroll
    for (int kg = 0; kg < 16; kg += 4) {
      float af[4][4], bf[4][4];
#pragma unroll
      for (int i = 0; i < 4; ++i)
        *(float4*)af[i] = *(const float4*)&As[ty * 4 + i][kg];
#pragma unroll
      for (int kk = 0; kk < 4; ++kk)
        *(float4*)bf[kk] = *(const float4*)&Bs[kg + kk][tx * 4];
#pragma unroll
      for (int kk = 0; kk < 4; ++kk)
#pragma unroll
        for (int i = 0; i < 4; ++i)
#pragma unroll
          for (int j = 0; j < 4; ++j)
            acc[i][j] = fmaf(af[i][kk], bf[kk][j], acc[i][j]);
    }
    __syncthreads();
  }

#pragma unroll
  for (int i = 0; i < 4; ++i) {
    int r = rowBase + ty * 4 + i;
    if (r >= R) continue;
    float vals[4];
#pragma unroll
    for (int j = 0; j < 4; ++j) {
      float v = acc[i][j];
      if (bias) v += bias[colBase + tx * 4 + j];
      if (act) v = v > 0.f ? v : 0.01f * v;
      vals[j] = v;
    }
    if (obf16) {
      unsigned short* o16 = (unsigned short*)out;
      ushort4 w = make_ushort4(f2bf(vals[0]), f2bf(vals[1]), f2bf(vals[2]), f2bf(vals[3]));
      *(ushort4*)(o16 + (size_t)r * ldo + colBase + tx * 4) = w;
    } else {
      *(float4*)(out + (size_t)r * ldo + colBase + tx * 4) =
          make_float4(vals[0], vals[1], vals[2], vals[3]);
      if (out16) {
        uint2 w = make_uint2(packbf(vals[0], vals[1]), packbf(vals[2], vals[3]));
        *(uint2*)(out16 + (size_t)r * ldo + colBase + tx * 4) = w;
      }
    }
  }
}

// ---------------- segment ops: one wave per segment; 4 x 16-lane groups, 8 feats/lane ----------------
// Round-6/7 evidence: seg gathers gained ~8us from the 2-deep idx/data pipeline (kept).

__global__ __launch_bounds__(256) void seg_mean_e(const unsigned short* __restrict__ h16,
                                                  const int* __restrict__ off_e,
                                                  const unsigned short* __restrict__ by_h,
                                                  unsigned short* __restrict__ m_e16, int M) {
  int m = (blockIdx.x * blockDim.x + threadIdx.x) >> 6;
  if (m >= M) return;
  int lane = threadIdx.x & 63;
  int g = lane >> 4;
  int fl = lane & 15;
  int s = off_e[m], e1 = off_e[m + 1];
  float4 a0 = make_float4(0.f, 0.f, 0.f, 0.f), a1 = a0;
  uint4 z4 = make_uint4(0, 0, 0, 0);
  int j = s + g;
  int iC = (j + 8 < e1) ? by_h[j + 8] : 0;
  uint4 hwA = z4, hwB = z4;
  if (j < e1) {
    int i0 = by_h[j];
    hwA = *(const uint4*)(h16 + (size_t)i0 * HF + fl * 8);
  }
  if (j + 4 < e1) {
    int i1 = by_h[j + 4];
    hwB = *(const uint4*)(h16 + (size_t)i1 * HF + fl * 8);
  }
  while (j < e1) {
    uint4 hwC = z4;
    if (j + 8 < e1) hwC = *(const uint4*)(h16 + (size_t)iC * HF + fl * 8);
    int iD = (j + 12 < e1) ? by_h[j + 12] : 0;
    a0.x += BFLO(hwA.x); a0.y += BFHI(hwA.x); a0.z += BFLO(hwA.y); a0.w += BFHI(hwA.y);
    a1.x += BFLO(hwA.z); a1.y += BFHI(hwA.z); a1.z += BFLO(hwA.w); a1.w += BFHI(hwA.w);
    hwA = hwB; hwB = hwC; iC = iD;
    j += 4;
  }
#pragma unroll
  for (int mask = 16; mask <= 32; mask <<= 1) {
    a0.x += __shfl_xor(a0.x, mask); a0.y += __shfl_xor(a0.y, mask);
    a0.z += __shfl_xor(a0.z, mask); a0.w += __shfl_xor(a0.w, mask);
    a1.x += __shfl_xor(a1.x, mask); a1.y += __shfl_xor(a1.y, mask);
    a1.z += __shfl_xor(a1.z, mask); a1.w += __shfl_xor(a1.w, mask);
  }
  if (g == 0) {
    int cnt = e1 - s;
    float r = 1.f / (float)(cnt > 0 ? cnt : 1);
    uint4 w = make_uint4(packbf(a0.x * r, a0.y * r), packbf(a0.z * r, a0.w * r),
                         packbf(a1.x * r, a1.y * r), packbf(a1.z * r, a1.w * r));
    *(uint4*)(m_e16 + (size_t)m * HF + fl * 8) = w;
  }
}

__global__ __launch_bounds__(256) void seg_mean_v_add(float* __restrict__ h,
                                                      const unsigned short* __restrict__ m_e16,
                                                      const int* __restrict__ off_v,
                                                      const unsigned short* __restrict__ by_v,
                                                      int N) {
  int n = (blockIdx.x * blockDim.x + threadIdx.x) >> 6;
  if (n >= N) return;
  int lane = threadIdx.x & 63;
  int g = lane >> 4;
  int fl = lane & 15;
  int s = off_v[n], e1 = off_v[n + 1];
  float4 a0 = make_float4(0.f, 0.f, 0.f, 0.f), a1 = a0;
  uint4 z4 = make_uint4(0, 0, 0, 0);
  int j = s + g;
  int iC = (j + 8 < e1) ? by_v[j + 8] : 0;
  uint4 hwA = z4, hwB = z4;
  if (j < e1) {
    int i0 = by_v[j];
    hwA = *(const uint4*)(m_e16 + (size_t)i0 * HF + fl * 8);
  }
  if (j + 4 < e1) {
    int i1 = by_v[j + 4];
    hwB = *(const uint4*)(m_e16 + (size_t)i1 * HF + fl * 8);
  }
  while (j < e1) {
    uint4 hwC = z4;
    if (j + 8 < e1) hwC = *(const uint4*)(m_e16 + (size_t)iC * HF + fl * 8);
    int iD = (j + 12 < e1) ? by_v[j + 12] : 0;
    a0.x += BFLO(hwA.x); a0.y += BFHI(hwA.x); a0.z += BFLO(hwA.y); a0.w += BFHI(hwA.y);
    a1.x += BFLO(hwA.z); a1.y += BFHI(hwA.z); a1.z += BFLO(hwA.w); a1.w += BFHI(hwA.w);
    hwA = hwB; hwB = hwC; iC = iD;
    j += 4;
  }
#pragma unroll
  for (int mask = 16; mask <= 32; mask <<= 1) {
    a0.x += __shfl_xor(a0.x, mask); a0.y += __shfl_xor(a0.y, mask);
    a0.z += __shfl_xor(a0.z, mask); a0.w += __shfl_xor(a0.w, mask);
    a1.x += __shfl_xor(a1.x, mask); a1.y += __shfl_xor(a1.y, mask);
    a1.z += __shfl_xor(a1.z, mask); a1.w += __shfl_xor(a1.w, mask);
  }
  if (g == 0) {
    int cnt = e1 - s;
    float r = 1.f / (float)(cnt > 0 ? cnt : 1);
    float* hp = h + (size_t)n * HF + fl * 8;
    float4 h0 = *(const float4*)hp;
    float4 h1 = *(const float4*)(hp + 4);
    *(float4*)hp = make_float4(h0.x + a0.x * r, h0.y + a0.y * r, h0.z + a0.z * r, h0.w + a0.w * r);
    *(float4*)(hp + 4) = make_float4(h1.x + a1.x * r, h1.y + a1.y * r, h1.z + a1.z * r, h1.w + a1.w * r);
  }
}

// Fused GAT attention: one wave per node; q = h2 (fp32, score scale pre-folded into Wqk);
// kv bf16 [M][256]. Round-7 evidence: VALU-issue-bound (~400 cyc/trip, deeper pipeline
// REGRESSED). Restructure: 8 groups x 8 lanes, 16 feats/lane -> 8 edges/trip, halving
// the per-trip overhead per edge. Lean loop: idx 1-ahead, no register rotation, all 4
// data loads fold into one base address.
__global__ __launch_bounds__(256) void att_fused(const float* __restrict__ q,
                                                 const unsigned short* __restrict__ kv,
                                                 const int* __restrict__ off_v,
                                                 const unsigned short* __restrict__ by_v,
                                                 unsigned short* __restrict__ ho16, int N) {
  int n = (blockIdx.x * blockDim.x + threadIdx.x) >> 6;
  if (n >= N) return;
  int lane = threadIdx.x & 63;
  int g = lane >> 3;   // 8 groups of 8 lanes: 8 edges per trip
  int fl = lane & 7;   // 16 features per lane
  int s0 = off_v[n], s1 = off_v[n + 1];
  const float* qp = q + (size_t)n * HF + fl * 16;
  float4 q0 = *(const float4*)qp;
  float4 q1 = *(const float4*)(qp + 4);
  float4 q2 = *(const float4*)(qp + 8);
  float4 q3 = *(const float4*)(qp + 12);
  float m = -INFINITY, l = 0.f;
  float4 a0 = make_float4(0.f, 0.f, 0.f, 0.f), a1 = a0, a2 = a0, a3 = a0;
  int j = s0 + g;
  int idx = (j < s1) ? by_v[j] : 0;
  while (j < s1) {
    const unsigned short* b = kv + (size_t)idx * 256 + fl * 16;
    uint4 k0 = *(const uint4*)b;
    uint4 k1 = *(const uint4*)(b + 8);
    uint4 v0 = *(const uint4*)(b + 128);
    uint4 v1 = *(const uint4*)(b + 136);
    int jn = j + 8;
    idx = (jn < s1) ? by_v[jn] : 0;   // next-trip idx overlaps with compute
    float d = q0.x * BFLO(k0.x) + q0.y * BFHI(k0.x) + q0.z * BFLO(k0.y) + q0.w * BFHI(k0.y)
            + q1.x * BFLO(k0.z) + q1.y * BFHI(k0.z) + q1.z * BFLO(k0.w) + q1.w * BFHI(k0.w)
            + q2.x * BFLO(k1.x) + q2.y * BFHI(k1.x) + q2.z * BFLO(k1.y) + q2.w * BFHI(k1.y)
            + q3.x * BFLO(k1.z) + q3.y * BFHI(k1.z) + q3.z * BFLO(k1.w) + q3.w * BFHI(k1.w);
    d += __shfl_xor(d, 1);
    d += __shfl_xor(d, 2);
    d += __shfl_xor(d, 4);
    d = d > 0.f ? d : 0.2f * d;   // scale already folded into Wqk
    if (d > m + 8.f) {
      float sc = __expf(m - d);   // first edge: exp(-inf)=0 zeroes l,a
      l *= sc;
      a0.x *= sc; a0.y *= sc; a0.z *= sc; a0.w *= sc;
      a1.x *= sc; a1.y *= sc; a1.z *= sc; a1.w *= sc;
      a2.x *= sc; a2.y *= sc; a2.z *= sc; a2.w *= sc;
      a3.x *= sc; a3.y *= sc; a3.z *= sc; a3.w *= sc;
      m = d;
    }
    float p = __expf(d - m);
    l += p;
    a0.x += p * BFLO(v0.x); a0.y += p * BFHI(v0.x);
    a0.z += p * BFLO(v0.y); a0.w += p * BFHI(v0.y);
    a1.x += p * BFLO(v0.z); a1.y += p * BFHI(v0.z);
    a1.z += p * BFLO(v0.w); a1.w += p * BFHI(v0.w);
    a2.x += p * BFLO(v1.x); a2.y += p * BFHI(v1.x);
    a2.z += p * BFLO(v1.y); a2.w += p * BFHI(v1.y);
    a3.x += p * BFLO(v1.z); a3.y += p * BFHI(v1.z);
    a3.z += p * BFLO(v1.w); a3.w += p * BFHI(v1.w);
    j = jn;
  }
#pragma unroll
  for (int mask = 8; mask <= 32; mask <<= 1) {
    float m2 = __shfl_xor(m, mask);
    float l2 = __shfl_xor(l, mask);
    float b0x = __shfl_xor(a0.x, mask), b0y = __shfl_xor(a0.y, mask);
    float b0z = __shfl_xor(a0.z, mask), b0w = __shfl_xor(a0.w, mask);
    float b1x = __shfl_xor(a1.x, mask), b1y = __shfl_xor(a1.y, mask);
    float b1z = __shfl_xor(a1.z, mask), b1w = __shfl_xor(a1.w, mask);
    float b2x = __shfl_xor(a2.x, mask), b2y = __shfl_xor(a2.y, mask);
    float b2z = __shfl_xor(a2.z, mask), b2w = __shfl_xor(a2.w, mask);
    float b3x = __shfl_xor(a3.x, mask), b3y = __shfl_xor(a3.y, mask);
    float b3z = __shfl_xor(a3.z, mask), b3w = __shfl_xor(a3.w, mask);
    float mn = fmaxf(fmaxf(m, m2), -1e30f);
    float ea = __expf(m - mn), eb = __expf(m2 - mn);
    l = l * ea + l2 * eb;
    a0.x = a0.x * ea + b0x * eb; a0.y = a0.y * ea + b0y * eb;
    a0.z = a0.z * ea + b0z * eb; a0.w = a0.w * ea + b0w * eb;
    a1.x = a1.x * ea + b1x * eb; a1.y = a1.y * ea + b1y * eb;
    a1.z = a1.z * ea + b1z * eb; a1.w = a1.w * ea + b1w * eb;
    a2.x = a2.x * ea + b2x * eb; a2.y = a2.y * ea + b2y * eb;
    a2.z = a2.z * ea + b2z * eb; a2.w = a2.w * ea + b2w * eb;
    a3.x = a3.x * ea + b3x * eb; a3.y = a3.y * ea + b3y * eb;
    a3.z = a3.z * ea + b3z * eb; a3.w = a3.w * ea + b3w * eb;
    m = fmaxf(m, m2);
  }
  if (g == 0) {
    float inv = 1.f / fmaxf(l, 1e-16f);
    unsigned short* op = ho16 + (size_t)n * HF + fl * 16;
    uint4 w0 = make_uint4(packbf(a0.x * inv, a0.y * inv), packbf(a0.z * inv, a0.w * inv),
                          packbf(a1.x * inv, a1.y * inv), packbf(a1.z * inv, a1.w * inv));
    uint4 w1 = make_uint4(packbf(a2.x * inv, a2.y * inv), packbf(a2.z * inv, a2.w * inv),
                          packbf(a3.x * inv, a3.y * inv), packbf(a3.z * inv, a3.w * inv));
    *(uint4*)op = w0;
    *(uint4*)(op + 8) = w1;
  }
}

// z[m][0:128] = segment_min(ho16[node]) (0 if empty); z[m][128:256] = xe[m]
__global__ __launch_bounds__(256) void seg_min_z(const unsigned short* __restrict__ ho16,
                                                 const int* __restrict__ off_e,
                                                 const unsigned short* __restrict__ by_h,
                                                 const float* __restrict__ xe,
                                                 float* __restrict__ z, int M) {
  int m = (blockIdx.x * blockDim.x + threadIdx.x) >> 6;
  if (m >= M) return;
  int lane = threadIdx.x & 63;
  int g = lane >> 4;
  int fl = lane & 15;
  int s = off_e[m], e1 = off_e[m + 1];
  float4 a0 = make_float4(FLT_MAX, FLT_MAX, FLT_MAX, FLT_MAX), a1 = a0;
  uint4 z4 = make_uint4(0, 0, 0, 0);
  int j = s + g;
  int iC = (j + 8 < e1) ? by_h[j + 8] : 0;
  uint4 hwA = z4, hwB = z4;
  if (j < e1) {
    int i0 = by_h[j];
    hwA = *(const uint4*)(ho16 + (size_t)i0 * HF + fl * 8);
  }
  if (j + 4 < e1) {
    int i1 = by_h[j + 4];
    hwB = *(const uint4*)(ho16 + (size_t)i1 * HF + fl * 8);
  }
  while (j < e1) {
    uint4 hwC = z4;
    if (j + 8 < e1) hwC = *(const uint4*)(ho16 + (size_t)iC * HF + fl * 8);
    int iD = (j + 12 < e1) ? by_h[j + 12] : 0;
    a0.x = fminf(a0.x, BFLO(hwA.x)); a0.y = fminf(a0.y, BFHI(hwA.x));
    a0.z = fminf(a0.z, BFLO(hwA.y)); a0.w = fminf(a0.w, BFHI(hwA.y));
    a1.x = fminf(a1.x, BFLO(hwA.z)); a1.y = fminf(a1.y, BFHI(hwA.z));
    a1.z = fminf(a1.z, BFLO(hwA.w)); a1.w = fminf(a1.w, BFHI(hwA.w));
    hwA = hwB; hwB = hwC; iC = iD;
    j += 4;
  }
#pragma unroll
  for (int mask = 16; mask <= 32; mask <<= 1) {
    a0.x = fminf(a0.x, __shfl_xor(a0.x, mask)); a0.y = fminf(a0.y, __shfl_xor(a0.y, mask));
    a0.z = fminf(a0.z, __shfl_xor(a0.z, mask)); a0.w = fminf(a0.w, __shfl_xor(a0.w, mask));
    a1.x = fminf(a1.x, __shfl_xor(a1.x, mask)); a1.y = fminf(a1.y, __shfl_xor(a1.y, mask));
    a1.z = fminf(a1.z, __shfl_xor(a1.z, mask)); a1.w = fminf(a1.w, __shfl_xor(a1.w, mask));
  }
  if (g == 0) {
    bool nz = (e1 > s);
    float* op = z + (size_t)m * 256 + fl * 8;
    *(float4*)op = nz ? a0 : make_float4(0.f, 0.f, 0.f, 0.f);
    *(float4*)(op + 4) = nz ? a1 : make_float4(0.f, 0.f, 0.f, 0.f);
  } else if (g == 1) {
    const float* xp = xe + (size_t)m * HF + fl * 8;
    float* op = z + (size_t)m * 256 + 128 + fl * 8;
    *(float4*)op = *(const float4*)xp;
    *(float4*)(op + 4) = *(const float4*)(xp + 4);
  }
}

// ---------------- GraphNorm stats: two-kernel deterministic reduction ----------------

__global__ __launch_bounds__(1024) void colstats_part(const float* __restrict__ z, int rows, int C,
                                                      float* __restrict__ part) {
  int tid = threadIdx.x;
  int RL = 1024 / C;
  int col = tid & (C - 1);
  int ro = tid / C;
  float s1 = 0.f, s2 = 0.f;
  for (int r = blockIdx.x * RL + ro; r < rows; r += gridDim.x * RL) {
    float v = z[(size_t)r * C + col];
    s1 += v;
    s2 += v * v;
  }
  __shared__ float l1[1024], l2[1024];
  l1[tid] = s1;
  l2[tid] = s2;
  __syncthreads();
  for (int off = 512; off >= C; off >>= 1) {
    if (tid < off) { l1[tid] += l1[tid + off]; l2[tid] += l2[tid + off]; }
    __syncthreads();
  }
  if (tid < C) {
    part[(size_t)blockIdx.x * 2 * C + tid] = l1[tid];
    part[(size_t)blockIdx.x * 2 * C + C + tid] = l2[tid];
  }
}

__global__ void colstats_fin(const float* __restrict__ part, int nb, int C,
                             const float* __restrict__ w, const float* __restrict__ b,
                             const float* __restrict__ a, float invrows,
                             float* __restrict__ sc, float* __restrict__ sh) {
  int col = threadIdx.x;
  if (col >= C) return;
  float s1 = 0.f, s2 = 0.f;
#pragma unroll 8
  for (int i = 0; i < nb; ++i) {
    s1 += part[(size_t)i * 2 * C + col];
    s2 += part[(size_t)i * 2 * C + C + col];
  }
  float mu = s1 * invrows;
  float ex2 = s2 * invrows;
  float av = a[col];
  float var = ex2 - 2.f * av * mu * mu + av * av * mu * mu;
  float s = w[col] * rsqrtf(var + 1e-5f);
  sc[col] = s;
  sh[col] = b[col] - av * mu * s;
}

// ---------------- launch ----------------

extern "C" void kernel_launch(void* const* d_in, const int* in_sizes, int n_in,
                              void* d_out, int out_size, void* d_ws, size_t ws_size,
                              hipStream_t stream) {
  const float* x        = (const float*)d_in[0];
  const float* x_e      = (const float*)d_in[2];
  const int*   node_idx = (const int*)d_in[3];
  const int*   hedge_idx= (const int*)d_in[4];
  const float* her_W1   = (const float*)d_in[5];
  const float* her_b1   = (const float*)d_in[6];
  const float* her_W2   = (const float*)d_in[7];
  const float* her_b2   = (const float*)d_in[8];
  const float* sr_W1    = (const float*)d_in[9];
  const float* sr_b1    = (const float*)d_in[10];
  const float* sr_W2    = (const float*)d_in[11];
  const float* sr_b2    = (const float*)d_in[12];
  const float* att_Wq   = (const float*)d_in[13];
  const float* att_Wk   = (const float*)d_in[14];
  const float* att_Wv   = (const float*)d_in[15];
  const float* ef_W     = (const float*)d_in[16];
  const float* ef_b     = (const float*)d_in[17];
  const float* gn1_w    = (const float*)d_in[18];
  const float* gn1_b    = (const float*)d_in[19];
  const float* gn1_a    = (const float*)d_in[20];
  const float* gn2_w    = (const float*)d_in[21];
  const float* gn2_b    = (const float*)d_in[22];
  const float* gn2_a    = (const float*)d_in[23];
  const float* cls_W1   = (const float*)d_in[24];
  const float* cls_b1   = (const float*)d_in[25];
  const float* cls_W2   = (const float*)d_in[26];
  const float* cls_b2   = (const float*)d_in[27];

  const int N = in_sizes[0] / HF;
  const int M = in_sizes[2] / HF;
  const int E = in_sizes[3];
  const int NVR = idiv(N, VRANGE);  // node range count (2 for N=50000)

  // ---- workspace layout (nothing needs zeroing: counting sort writes every cell) ----
  char* wp = (char*)d_ws;
  float* part1 = (float*)wp; wp += (size_t)CS_GRID * 512 * 4;  // gn1 partials (2*256 per blk)
  float* part2 = (float*)wp; wp += (size_t)CS_GRID * 256 * 4;  // gn2 partials (2*128 per blk)
  int* cnt_e = (int*)wp; wp += (size_t)M * 4;
  int* cnt_v = (int*)wp; wp += (size_t)N * 4;
  int* off_e = (int*)wp; wp += (size_t)(M + 1) * 4;
  int* off_v = (int*)wp; wp += (size_t)(N + 1) * 4;
  unsigned short* by_h = (unsigned short*)wp; wp += ((size_t)E * 2 + 3) & ~(size_t)3;
  unsigned short* by_v = (unsigned short*)wp; wp += ((size_t)E * 2 + 3) & ~(size_t)3;
  int* part_e = (int*)wp; wp += 257 * 4;
  int* part_v = (int*)wp; wp += 257 * 4;
  float* sc1 = (float*)wp; wp += 256 * 4;
  float* sh1 = (float*)wp; wp += 256 * 4;
  float* sc2 = (float*)wp; wp += 128 * 4;
  float* sh2 = (float*)wp; wp += 128 * 4;
  wp = (char*)(((uintptr_t)wp + 255) & ~(uintptr_t)255);
  float* wqt  = (float*)wp; wp += (size_t)128 * 128 * 4;   // Wq^T * scale
  float* wcat = (float*)wp; wp += (size_t)128 * 256 * 4;   // [Wqk | Wv]
  float* h   = (float*)wp; wp += (size_t)N * HF * 4;       // sr1 out, += m_v, sr2 in; later c1
  float* h2  = (float*)wp; wp += (size_t)N * HF * 4;       // sr2 out = q; later z [M,256]
  float* xe  = (float*)wp; wp += (size_t)M * HF * 4;
  float* kvf = (float*)wp; wp += (size_t)M * 256 * 4;      // t1 fp32 alias / kv bf16
  float* z2  = (float*)wp; wp += (size_t)M * HF * 4;
  unsigned short* h16   = (unsigned short*)wp; wp += (size_t)N * HF * 2;  // sr1 bf16 shadow
  unsigned short* ho16  = (unsigned short*)wp; wp += (size_t)N * HF * 2;  // att out bf16
  unsigned short* m_e16 = (unsigned short*)wp; wp += (size_t)M * HF * 2;

  unsigned short* kv = (unsigned short*)kvf;   // [M][256] bf16
  float* t1  = kvf;                // her hidden [M,128] fp32 (dead before kv written)
  float* z   = h2;                 // [M,256] (h2 dead as q after att_fused)
  float* c1  = h;                  // [M,128] (h dead after sr2)

  // Histogram matrices alias h (dead until sr1): NB*M + NVR*NB*VPACK ints = 17.9MB < 25.6MB
  int* HE = (int*)h;
  int* HV = HE + (size_t)NB_CSR * M;

  // ---- CSR build: counting sort, zero device-scope atomics ----
  csr_hist<<<dim3(NB_CSR, 1 + NVR), 512, 0, stream>>>(node_idx, hedge_idx, E, M, HE, HV);
  csr_colscan<<<idiv(M + NVR * VPACK, 256), 256, 0, stream>>>(HE, HV, M, N, NVR, cnt_e, cnt_v);
  int nbE = idiv(M, SCAN_CHUNK);
  int nbV = idiv(N, SCAN_CHUNK);
  scanA2<<<nbE + nbV, 256, 0, stream>>>(cnt_e, M, nbE, part_e, cnt_v, N, part_v);
  scanB2<<<2, 256, 0, stream>>>(part_e, nbE, part_v, nbV);
  scanC2<<<nbE + nbV, 256, 0, stream>>>(cnt_e, M, nbE, part_e, off_e, cnt_v, N, nbV, part_v, off_v);
  csr_scatter<<<dim3(NB_CSR, 1 + NVR), 512, 0, stream>>>(node_idx, hedge_idx, E, M, HE, HV,
                                                         off_e, off_v, by_h, by_v);

  // wqt = Wq^T*scale, wcat right = Wv; then wcat left = Wk @ wqt
  prep_att<<<64, 256, 0, stream>>>(att_Wq, att_Wv, wqt, wcat);
  gemm64<<<dim3(2, 2), 256, 0, stream>>>(att_Wk, wqt, nullptr, wcat, 128, 128, 128, 0,
                                         nullptr, nullptr, 0, 256, 0, nullptr);

  dim3 blk(256);
  // her MLP: xe
  gemm64<<<dim3(idiv(M, 64), 2), blk, 0, stream>>>(x_e, her_W1, her_b1, t1, M, HF, HF, 1,
                                                   nullptr, nullptr, 0, HF, 0, nullptr);
  gemm64<<<dim3(idiv(M, 64), 2), blk, 0, stream>>>(t1, her_W2, her_b2, xe, M, HF, HF, 0,
                                                   nullptr, nullptr, 0, HF, 0, nullptr);
  // sr layer1 (fp32 + bf16 shadow), 64x64 tiles -> 1564 blocks (overwrites HE/HV)
  gemm64<<<dim3(idiv(N, 64), 2), blk, 0, stream>>>(x, sr_W1, sr_b1, h, N, HF, HF, 1,
                                                   nullptr, nullptr, 0, HF, 0, h16);
  // message passing means (bf16 gathers, 2-deep pipelined)
  seg_mean_e<<<idiv(M * 64, 256), blk, 0, stream>>>(h16, off_e, by_h, m_e16, M);
  seg_mean_v_add<<<idiv(N * 64, 256), blk, 0, stream>>>(h, m_e16, off_v, by_v, N);
  // sr layer2 -> h2 (doubles as q)
  gemm64<<<dim3(idiv(N, 64), 2), blk, 0, stream>>>(h, sr_W2, sr_b2, h2, N, HF, HF, 1,
                                                   nullptr, nullptr, 0, HF, 0, nullptr);
  // kv projection: [xe@Wqk | xe@Wv] in bf16
  gemm64<<<dim3(idiv(M, 64), 4), blk, 0, stream>>>(xe, wcat, nullptr, (float*)kv, M, HF, 256, 0,
                                                   nullptr, nullptr, 0, 256, 1, nullptr);
  // fused attention (q = h2), 8-edge trips
  att_fused<<<idiv(N * 64, 256), blk, 0, stream>>>(h2, kv, off_v, by_v, ho16, N);
  // min aggregation + concat (z overwrites h2)
  seg_min_z<<<idiv(M * 64, 256), blk, 0, stream>>>(ho16, off_e, by_h, xe, z, M);
  // gn1 stats (partials + finalize) -> ef linear(+act) -> gn2 stats
  colstats_part<<<CS_GRID, 1024, 0, stream>>>(z, M, 256, part1);
  colstats_fin<<<1, 256, 0, stream>>>(part1, CS_GRID, 256, gn1_w, gn1_b, gn1_a,
                                      1.f / (float)M, sc1, sh1);
  gemm64<<<dim3(idiv(M, 64), 2), blk, 0, stream>>>(z, ef_W, ef_b, z2, M, 2 * HF, HF, 1,
                                                   sc1, sh1, 0, HF, 0, nullptr);
  colstats_part<<<CS_GRID, 1024, 0, stream>>>(z2, M, 128, part2);
  colstats_fin<<<1, 128, 0, stream>>>(part2, CS_GRID, 128, gn2_w, gn2_b, gn2_a,
                                      1.f / (float)M, sc2, sh2);
  // classifier
  gemm64<<<dim3(idiv(M, 64), 2), blk, 0, stream>>>(z2, cls_W1, cls_b1, c1, M, HF, HF, 1,
                                                   sc2, sh2, 1, HF, 0, nullptr);
  gemm64<<<dim3(idiv(M, 64), 1), blk, 0, stream>>>(c1, cls_W2, cls_b2, (float*)d_out, M, HF, 64, 0,
                                                   nullptr, nullptr, 0, 64, 0, nullptr);
}

// Round 9
// 344.418 us; speedup vs baseline: 1.9398x; 1.1160x over previous
//
#include <hip/hip_runtime.h>
#include <float.h>
#include <math.h>

#define HF 128
#define SCAN_CHUNK 4096  // 256 threads x 16 elems
#define NB_CSR 128       // chunks for counting-sort CSR build
#define VPACK 12500      // packed (2-per-int) node bins per range: 25000 nodes / range
#define VRANGE (2 * VPACK)
#define CS_GRID 256      // colstats_part grid (per-block partials, no atomics)

static inline int idiv(int a, int b) { return (a + b - 1) / b; }

__device__ inline unsigned short f2bf(float x) {  // RNE float->bf16
  unsigned u = __float_as_uint(x);
  return (unsigned short)((u + 0x7fffu + ((u >> 16) & 1u)) >> 16);
}
__device__ inline unsigned packbf(float a, float b) {
  return (unsigned)f2bf(a) | ((unsigned)f2bf(b) << 16);
}
#define BFLO(w) __uint_as_float((w) << 16)
#define BFHI(w) __uint_as_float((w) & 0xffff0000u)

// ---------------- CSR build: LDS-histogram counting sort (ZERO device-scope atomics) ----------------
// Round-2 evidence: 1.2M global atomics = 24.7 G/s RMW wall. Per-chunk LDS histograms
// + column scan + scatter instead.

__global__ __launch_bounds__(512) void csr_hist(const int* __restrict__ nidx,
                                                const int* __restrict__ hidx,
                                                int E, int M,
                                                int* __restrict__ HE,
                                                int* __restrict__ HV) {
  __shared__ int bins[VPACK];
  int b = blockIdx.x, y = blockIdx.y, tid = threadIdx.x;
  int chunk = (E + NB_CSR - 1) / NB_CSR;
  int e0 = b * chunk;
  int e1 = e0 + chunk; if (e1 > E) e1 = E;
  if (y == 0) {
    for (int s = tid; s < M; s += 512) bins[s] = 0;
    __syncthreads();
    for (int e = e0 + tid; e < e1; e += 512) atomicAdd(&bins[hidx[e]], 1);
    __syncthreads();
    for (int s = tid; s < M; s += 512) HE[(size_t)b * M + s] = bins[s];
  } else {
    int R = (y - 1) * VRANGE;
    int* HVr = HV + ((size_t)(y - 1) * NB_CSR + b) * VPACK;
    for (int q = tid; q < VPACK; q += 512) bins[q] = 0;
    __syncthreads();
    for (int e = e0 + tid; e < e1; e += 512) {
      int v = nidx[e] - R;
      if ((unsigned)v < (unsigned)VRANGE) atomicAdd(&bins[v >> 1], (v & 1) ? 0x10000 : 1);
    }
    __syncthreads();
    for (int q = tid; q < VPACK; q += 512) HVr[q] = bins[q];
  }
}

// Per-segment exclusive scan over the NB_CSR chunks (in place) + dense counts.
__global__ __launch_bounds__(256) void csr_colscan(int* __restrict__ HE,
                                                   int* __restrict__ HV,
                                                   int M, int N, int NVR,
                                                   int* __restrict__ cnt_e,
                                                   int* __restrict__ cnt_v) {
  int col = blockIdx.x * 256 + threadIdx.x;
  if (col < M) {
    int run = 0;
    for (int b = 0; b < NB_CSR; ++b) {
      size_t i = (size_t)b * M + col;
      int t = HE[i]; HE[i] = run; run += t;
    }
    cnt_e[col] = run;
  } else if (col < M + NVR * VPACK) {
    int c = col - M;
    int r = c / VPACK, q = c - r * VPACK;
    int* HVr = HV + (size_t)r * NB_CSR * VPACK;
    int run = 0;
    for (int b = 0; b < NB_CSR; ++b) {
      size_t i = (size_t)b * VPACK + q;
      int t = HVr[i]; HVr[i] = run; run += t;
    }
    int node = r * VRANGE + 2 * q;
    if (node < N) cnt_v[node] = run & 0xffff;
    if (node + 1 < N) cnt_v[node + 1] = run >> 16;
  }
}

// Scatter: preload LDS bins with global base (off + chunk-exclusive), LDS-atomic rank.
__global__ __launch_bounds__(512) void csr_scatter(const int* __restrict__ nidx,
                                                   const int* __restrict__ hidx,
                                                   int E, int M,
                                                   const int* __restrict__ HE,
                                                   const int* __restrict__ HV,
                                                   const int* __restrict__ off_e,
                                                   const int* __restrict__ off_v,
                                                   unsigned short* __restrict__ by_h,
                                                   unsigned short* __restrict__ by_v) {
  __shared__ int bins[VPACK];
  int b = blockIdx.x, y = blockIdx.y, tid = threadIdx.x;
  int chunk = (E + NB_CSR - 1) / NB_CSR;
  int e0 = b * chunk;
  int e1 = e0 + chunk; if (e1 > E) e1 = E;
  if (y == 0) {
    for (int s = tid; s < M; s += 512) bins[s] = off_e[s] + HE[(size_t)b * M + s];
    __syncthreads();
    for (int e = e0 + tid; e < e1; e += 512) {
      int pos = atomicAdd(&bins[hidx[e]], 1);
      by_h[pos] = (unsigned short)nidx[e];
    }
  } else {
    int R = (y - 1) * VRANGE;
    const int* HVr = HV + ((size_t)(y - 1) * NB_CSR + b) * VPACK;
    for (int q = tid; q < VPACK; q += 512) bins[q] = HVr[q];
    __syncthreads();
    for (int e = e0 + tid; e < e1; e += 512) {
      int v = nidx[e];
      int vr = v - R;
      if ((unsigned)vr < (unsigned)VRANGE) {
        int old = atomicAdd(&bins[vr >> 1], (vr & 1) ? 0x10000 : 1);
        int rank = (vr & 1) ? (old >> 16) : (old & 0xffff);
        by_v[off_v[v] + rank] = (unsigned short)hidx[e];
      }
    }
  }
}

// ---- fused 3-phase multi-block exclusive scan over both dense count arrays ----

__global__ __launch_bounds__(256) void scanA2(const int* __restrict__ inE, int nE, int nbE,
                                              int* __restrict__ partE,
                                              const int* __restrict__ inV, int nV,
                                              int* __restrict__ partV) {
  const int* in; int n, b; int* partials;
  if ((int)blockIdx.x < nbE) { in = inE; n = nE; b = blockIdx.x; partials = partE; }
  else { in = inV; n = nV; b = blockIdx.x - nbE; partials = partV; }
  __shared__ int lds[256];
  int tid = threadIdx.x;
  int base = b * SCAN_CHUNK + tid * 16;
  int s = 0;
#pragma unroll
  for (int i = 0; i < 16; ++i) {
    int idx = base + i;
    if (idx < n) s += in[idx];
  }
  lds[tid] = s;
  __syncthreads();
  for (int off = 128; off; off >>= 1) {
    if (tid < off) lds[tid] += lds[tid + off];
    __syncthreads();
  }
  if (tid == 0) partials[b] = lds[0];
}

__global__ __launch_bounds__(256) void scanB2(int* __restrict__ partE, int nbE,
                                              int* __restrict__ partV, int nbV) {
  int* partials = (blockIdx.x == 0) ? partE : partV;
  int nb = (blockIdx.x == 0) ? nbE : nbV;
  __shared__ int lds[256];
  int tid = threadIdx.x;
  int v = (tid < nb) ? partials[tid] : 0;
  lds[tid] = v;
  __syncthreads();
  for (int off = 1; off < 256; off <<= 1) {
    int add = (tid >= off) ? lds[tid - off] : 0;
    __syncthreads();
    lds[tid] += add;
    __syncthreads();
  }
  if (tid < nb) partials[tid] = lds[tid] - v;  // exclusive
  if (tid == nb - 1) partials[nb] = lds[tid];  // total
}

__global__ __launch_bounds__(256) void scanC2(const int* __restrict__ inE, int nE, int nbE,
                                              const int* __restrict__ partE, int* __restrict__ outE,
                                              const int* __restrict__ inV, int nV, int nbV,
                                              const int* __restrict__ partV, int* __restrict__ outV) {
  const int* in; const int* partials; int* out; int n, b, nb;
  if ((int)blockIdx.x < nbE) { in = inE; n = nE; b = blockIdx.x; partials = partE; out = outE; nb = nbE; }
  else { in = inV; n = nV; b = blockIdx.x - nbE; partials = partV; out = outV; nb = nbV; }
  __shared__ int lds[256];
  int tid = threadIdx.x;
  int base = b * SCAN_CHUNK + tid * 16;
  int vals[16];
  int s = 0;
#pragma unroll
  for (int i = 0; i < 16; ++i) {
    int idx = base + i;
    int v = (idx < n) ? in[idx] : 0;
    vals[i] = s;
    s += v;
  }
  lds[tid] = s;
  __syncthreads();
  int own = s;
  for (int off = 1; off < 256; off <<= 1) {
    int add = (tid >= off) ? lds[tid - off] : 0;
    __syncthreads();
    lds[tid] += add;
    __syncthreads();
  }
  int excl = lds[tid] - own + partials[b];
#pragma unroll
  for (int i = 0; i < 16; ++i) {
    int idx = base + i;
    if (idx < n) out[idx] = excl + vals[i];
  }
  if (b == 0 && tid == 0) out[n] = partials[nb];
}

// wqt = Wq^T * (1/sqrt(128)) [score scale folded]; wcat[:,128:256] = Wv.
__global__ void prep_att(const float* __restrict__ Wq, const float* __restrict__ Wv,
                         float* __restrict__ wqt, float* __restrict__ wcat) {
  int i = blockIdx.x * blockDim.x + threadIdx.x;  // 128*128
  if (i >= 128 * 128) return;
  int r = i >> 7, c = i & 127;
  wqt[c * 128 + r] = Wq[i] * 0.08838834764831845f;
  wcat[r * 256 + 128 + c] = Wv[i];
}

// ---------------- GEMM: 64x64 tile, 4x4 micro; fused input-norm / act / bf16-out / fp32+bf16 shadow ----------------
// Device body with exactly ONE call site per kernel -> single LDS instance (round-1
// fusion failure was summed LDS from multiple inlined bodies).

__device__ __forceinline__ void gemm64_body(const float* __restrict__ A,
                                            const float* __restrict__ W,
                                            const float* __restrict__ bias,
                                            float* __restrict__ out,
                                            int R, int K, int C, int act,
                                            const float* __restrict__ insc,
                                            const float* __restrict__ insh, int inact,
                                            int ldo, int obf16,
                                            unsigned short* __restrict__ out16,
                                            int bx, int by) {
  __shared__ __align__(16) float As[64][20];
  __shared__ __align__(16) float Bs[16][64];
  int tid = threadIdx.x;
  int tx = tid & 15;
  int ty = tid >> 4;
  int rowBase = bx * 64;
  int colBase = by * 64;

  float acc[4][4] = {};

  for (int k0 = 0; k0 < K; k0 += 16) {
    {
      int arow = tid >> 2, ac = (tid & 3) * 4;
      int gr = rowBase + arow;
      float4 av = make_float4(0.f, 0.f, 0.f, 0.f);
      if (gr < R) av = *(const float4*)(A + (size_t)gr * K + k0 + ac);
      if (insc) {
        float vv[4] = {av.x, av.y, av.z, av.w};
#pragma unroll
        for (int i = 0; i < 4; ++i) {
          float s = insc[k0 + ac + i], sh = insh[k0 + ac + i];
          float v = vv[i] * s + sh;
          if (inact) v = v > 0.f ? v : 0.01f * v;
          vv[i] = v;
        }
        av = make_float4(vv[0], vv[1], vv[2], vv[3]);
      }
      *(float4*)&As[arow][ac] = av;
    }
    {
      int bk = tid >> 4, bc = (tid & 15) * 4;
      *(float4*)&Bs[bk][bc] = *(const float4*)(W + (size_t)(k0 + bk) * C + colBase + bc);
    }
    __syncthreads();
#pragma unroll
    for (int kg = 0; kg < 16; kg += 4) {
      float af[4][4], bf[4][4];
#pragma unroll
      for (int i = 0; i < 4; ++i)
        *(float4*)af[i] = *(const float4*)&As[ty * 4 + i][kg];
#pragma unroll
      for (int kk = 0; kk < 4; ++kk)
        *(float4*)bf[kk] = *(const float4*)&Bs[kg + kk][tx * 4];
#pragma unroll
      for (int kk = 0; kk < 4; ++kk)
#pragma unroll
        for (int i = 0; i < 4; ++i)
#pragma unroll
          for (int j = 0; j < 4; ++j)
            acc[i][j] = fmaf(af[i][kk], bf[kk][j], acc[i][j]);
    }
    __syncthreads();
  }

#pragma unroll
  for (int i = 0; i < 4; ++i) {
    int r = rowBase + ty * 4 + i;
    if (r >= R) continue;
    float vals[4];
#pragma unroll
    for (int j = 0; j < 4; ++j) {
      float v = acc[i][j];
      if (bias) v += bias[colBase + tx * 4 + j];
      if (act) v = v > 0.f ? v : 0.01f * v;
      vals[j] = v;
    }
    if (obf16) {
      unsigned short* o16 = (unsigned short*)out;
      ushort4 w = make_ushort4(f2bf(vals[0]), f2bf(vals[1]), f2bf(vals[2]), f2bf(vals[3]));
      *(ushort4*)(o16 + (size_t)r * ldo + colBase + tx * 4) = w;
    } else {
      *(float4*)(out + (size_t)r * ldo + colBase + tx * 4) =
          make_float4(vals[0], vals[1], vals[2], vals[3]);
      if (out16) {
        uint2 w = make_uint2(packbf(vals[0], vals[1]), packbf(vals[2], vals[3]));
        *(uint2*)(out16 + (size_t)r * ldo + colBase + tx * 4) = w;
      }
    }
  }
}

struct GArgs {
  const float* A; const float* W; const float* bias; float* out;
  int R, K, C, act;
  const float* insc; const float* insh; int inact, ldo, obf16;
  unsigned short* out16;
  int nbx, nb;   // nbx = idiv(R,64); nb = nbx * ncols
};

__global__ __launch_bounds__(256) void gemm64(GArgs g) {
  gemm64_body(g.A, g.W, g.bias, g.out, g.R, g.K, g.C, g.act, g.insc, g.insh, g.inact,
              g.ldo, g.obf16, g.out16, blockIdx.x % g.nbx, blockIdx.x / g.nbx);
}

// Horizontal fusion of up to 3 independent GEMMs (identical body -> identical
// resources; block->arg selection is wave-uniform SGPR work).
__global__ __launch_bounds__(256) void gemm64_multi(GArgs g0, GArgs g1, GArgs g2) {
  int b = blockIdx.x;
  GArgs g = g0;
  if (b >= g0.nb) {
    b -= g0.nb;
    if (b < g1.nb) g = g1;
    else { b -= g1.nb; g = g2; }
  }
  gemm64_body(g.A, g.W, g.bias, g.out, g.R, g.K, g.C, g.act, g.insc, g.insh, g.inact,
              g.ldo, g.obf16, g.out16, b % g.nbx, b / g.nbx);
}

// ---------------- segment ops: one wave per segment; 4 x 16-lane groups, 8 feats/lane ----------------
// Round-6/7 evidence: 2-deep idx/data pipeline gained ~8us on the seg gathers (kept).

__device__ __forceinline__ void seg_mean_e_body(const unsigned short* __restrict__ h16,
                                                const int* __restrict__ off_e,
                                                const unsigned short* __restrict__ by_h,
                                                unsigned short* __restrict__ m_e16, int M, int bx) {
  int m = (bx * 256 + (int)threadIdx.x) >> 6;
  if (m >= M) return;
  int lane = threadIdx.x & 63;
  int g = lane >> 4;
  int fl = lane & 15;
  int s = off_e[m], e1 = off_e[m + 1];
  float4 a0 = make_float4(0.f, 0.f, 0.f, 0.f), a1 = a0;
  uint4 z4 = make_uint4(0, 0, 0, 0);
  int j = s + g;
  int iC = (j + 8 < e1) ? by_h[j + 8] : 0;
  uint4 hwA = z4, hwB = z4;
  if (j < e1) {
    int i0 = by_h[j];
    hwA = *(const uint4*)(h16 + (size_t)i0 * HF + fl * 8);
  }
  if (j + 4 < e1) {
    int i1 = by_h[j + 4];
    hwB = *(const uint4*)(h16 + (size_t)i1 * HF + fl * 8);
  }
  while (j < e1) {
    uint4 hwC = z4;
    if (j + 8 < e1) hwC = *(const uint4*)(h16 + (size_t)iC * HF + fl * 8);
    int iD = (j + 12 < e1) ? by_h[j + 12] : 0;
    a0.x += BFLO(hwA.x); a0.y += BFHI(hwA.x); a0.z += BFLO(hwA.y); a0.w += BFHI(hwA.y);
    a1.x += BFLO(hwA.z); a1.y += BFHI(hwA.z); a1.z += BFLO(hwA.w); a1.w += BFHI(hwA.w);
    hwA = hwB; hwB = hwC; iC = iD;
    j += 4;
  }
#pragma unroll
  for (int mask = 16; mask <= 32; mask <<= 1) {
    a0.x += __shfl_xor(a0.x, mask); a0.y += __shfl_xor(a0.y, mask);
    a0.z += __shfl_xor(a0.z, mask); a0.w += __shfl_xor(a0.w, mask);
    a1.x += __shfl_xor(a1.x, mask); a1.y += __shfl_xor(a1.y, mask);
    a1.z += __shfl_xor(a1.z, mask); a1.w += __shfl_xor(a1.w, mask);
  }
  if (g == 0) {
    int cnt = e1 - s;
    float r = 1.f / (float)(cnt > 0 ? cnt : 1);
    uint4 w = make_uint4(packbf(a0.x * r, a0.y * r), packbf(a0.z * r, a0.w * r),
                         packbf(a1.x * r, a1.y * r), packbf(a1.z * r, a1.w * r));
    *(uint4*)(m_e16 + (size_t)m * HF + fl * 8) = w;
  }
}

// Phase-B fusion: her2 GEMM blocks + seg_mean_e gather blocks (complementary pipes).
__global__ __launch_bounds__(256) void gemm_segmean(GArgs g,
                                                    const unsigned short* __restrict__ h16,
                                                    const int* __restrict__ off_e,
                                                    const unsigned short* __restrict__ by_h,
                                                    unsigned short* __restrict__ m_e16, int M) {
  int b = blockIdx.x;
  if (b < g.nb) {
    gemm64_body(g.A, g.W, g.bias, g.out, g.R, g.K, g.C, g.act, g.insc, g.insh, g.inact,
                g.ldo, g.obf16, g.out16, b % g.nbx, b / g.nbx);
    return;
  }
  seg_mean_e_body(h16, off_e, by_h, m_e16, M, b - g.nb);
}

__global__ __launch_bounds__(256) void seg_mean_v_add(float* __restrict__ h,
                                                      const unsigned short* __restrict__ m_e16,
                                                      const int* __restrict__ off_v,
                                                      const unsigned short* __restrict__ by_v,
                                                      int N) {
  int n = (blockIdx.x * blockDim.x + threadIdx.x) >> 6;
  if (n >= N) return;
  int lane = threadIdx.x & 63;
  int g = lane >> 4;
  int fl = lane & 15;
  int s = off_v[n], e1 = off_v[n + 1];
  float4 a0 = make_float4(0.f, 0.f, 0.f, 0.f), a1 = a0;
  uint4 z4 = make_uint4(0, 0, 0, 0);
  int j = s + g;
  int iC = (j + 8 < e1) ? by_v[j + 8] : 0;
  uint4 hwA = z4, hwB = z4;
  if (j < e1) {
    int i0 = by_v[j];
    hwA = *(const uint4*)(m_e16 + (size_t)i0 * HF + fl * 8);
  }
  if (j + 4 < e1) {
    int i1 = by_v[j + 4];
    hwB = *(const uint4*)(m_e16 + (size_t)i1 * HF + fl * 8);
  }
  while (j < e1) {
    uint4 hwC = z4;
    if (j + 8 < e1) hwC = *(const uint4*)(m_e16 + (size_t)iC * HF + fl * 8);
    int iD = (j + 12 < e1) ? by_v[j + 12] : 0;
    a0.x += BFLO(hwA.x); a0.y += BFHI(hwA.x); a0.z += BFLO(hwA.y); a0.w += BFHI(hwA.y);
    a1.x += BFLO(hwA.z); a1.y += BFHI(hwA.z); a1.z += BFLO(hwA.w); a1.w += BFHI(hwA.w);
    hwA = hwB; hwB = hwC; iC = iD;
    j += 4;
  }
#pragma unroll
  for (int mask = 16; mask <= 32; mask <<= 1) {
    a0.x += __shfl_xor(a0.x, mask); a0.y += __shfl_xor(a0.y, mask);
    a0.z += __shfl_xor(a0.z, mask); a0.w += __shfl_xor(a0.w, mask);
    a1.x += __shfl_xor(a1.x, mask); a1.y += __shfl_xor(a1.y, mask);
    a1.z += __shfl_xor(a1.z, mask); a1.w += __shfl_xor(a1.w, mask);
  }
  if (g == 0) {
    int cnt = e1 - s;
    float r = 1.f / (float)(cnt > 0 ? cnt : 1);
    float* hp = h + (size_t)n * HF + fl * 8;
    float4 h0 = *(const float4*)hp;
    float4 h1 = *(const float4*)(hp + 4);
    *(float4*)hp = make_float4(h0.x + a0.x * r, h0.y + a0.y * r, h0.z + a0.z * r, h0.w + a0.w * r);
    *(float4*)(hp + 4) = make_float4(h1.x + a1.x * r, h1.y + a1.y * r, h1.z + a1.z * r, h1.w + a1.w * r);
  }
}

// Fused GAT attention: one wave per node; q = h2 (fp32, score scale pre-folded into Wqk);
// kv bf16 [M][256]; software prefetch + defer-max rescale (THR=8).
// Round-7/8 evidence: this 4x16 one-deep form is the measured optimum (41.6us);
// deeper pipelining (+3.4us) and 8-lane groups (+3.9us) both REGRESSED (epilogue
// merge scales with feats/lane; rotation movs add issue pressure). REVERTED.
__global__ __launch_bounds__(256) void att_fused(const float* __restrict__ q,
                                                 const unsigned short* __restrict__ kv,
                                                 const int* __restrict__ off_v,
                                                 const unsigned short* __restrict__ by_v,
                                                 unsigned short* __restrict__ ho16, int N) {
  int n = (blockIdx.x * blockDim.x + threadIdx.x) >> 6;
  if (n >= N) return;
  int lane = threadIdx.x & 63;
  int g = lane >> 4;
  int fl = lane & 15;
  int s0 = off_v[n], s1 = off_v[n + 1];
  const float* qp = q + (size_t)n * HF + fl * 8;
  float4 q0 = *(const float4*)qp;
  float4 q1 = *(const float4*)(qp + 4);
  float m = -INFINITY, l = 0.f;
  float4 a0 = make_float4(0.f, 0.f, 0.f, 0.f), a1 = a0;
  int j = s0 + g;
  uint4 kw = make_uint4(0, 0, 0, 0), vw = kw;
  if (j < s1) {
    const unsigned short* base = kv + (size_t)by_v[j] * 256 + fl * 8;
    kw = *(const uint4*)base;
    vw = *(const uint4*)(base + 128);
  }
  while (j < s1) {
    int jn = j + 4;
    uint4 kw2 = make_uint4(0, 0, 0, 0), vw2 = kw2;
    if (jn < s1) {
      const unsigned short* b2 = kv + (size_t)by_v[jn] * 256 + fl * 8;
      kw2 = *(const uint4*)b2;
      vw2 = *(const uint4*)(b2 + 128);
    }
    float d = q0.x * BFLO(kw.x) + q0.y * BFHI(kw.x) + q0.z * BFLO(kw.y) + q0.w * BFHI(kw.y)
            + q1.x * BFLO(kw.z) + q1.y * BFHI(kw.z) + q1.z * BFLO(kw.w) + q1.w * BFHI(kw.w);
    d += __shfl_xor(d, 1);
    d += __shfl_xor(d, 2);
    d += __shfl_xor(d, 4);
    d += __shfl_xor(d, 8);
    d = d > 0.f ? d : 0.2f * d;   // scale already folded into Wqk
    if (d > m + 8.f) {
      float sc = __expf(m - d);   // first edge: exp(-inf)=0 zeroes l,a
      l *= sc;
      a0.x *= sc; a0.y *= sc; a0.z *= sc; a0.w *= sc;
      a1.x *= sc; a1.y *= sc; a1.z *= sc; a1.w *= sc;
      m = d;
    }
    float p = __expf(d - m);
    l += p;
    a0.x += p * BFLO(vw.x); a0.y += p * BFHI(vw.x);
    a0.z += p * BFLO(vw.y); a0.w += p * BFHI(vw.y);
    a1.x += p * BFLO(vw.z); a1.y += p * BFHI(vw.z);
    a1.z += p * BFLO(vw.w); a1.w += p * BFHI(vw.w);
    kw = kw2; vw = vw2; j = jn;
  }
#pragma unroll
  for (int mask = 16; mask <= 32; mask <<= 1) {
    float m2 = __shfl_xor(m, mask);
    float l2 = __shfl_xor(l, mask);
    float b0x = __shfl_xor(a0.x, mask), b0y = __shfl_xor(a0.y, mask);
    float b0z = __shfl_xor(a0.z, mask), b0w = __shfl_xor(a0.w, mask);
    float b1x = __shfl_xor(a1.x, mask), b1y = __shfl_xor(a1.y, mask);
    float b1z = __shfl_xor(a1.z, mask), b1w = __shfl_xor(a1.w, mask);
    float mn = fmaxf(fmaxf(m, m2), -1e30f);
    float ea = __expf(m - mn), eb = __expf(m2 - mn);
    l = l * ea + l2 * eb;
    a0.x = a0.x * ea + b0x * eb; a0.y = a0.y * ea + b0y * eb;
    a0.z = a0.z * ea + b0z * eb; a0.w = a0.w * ea + b0w * eb;
    a1.x = a1.x * ea + b1x * eb; a1.y = a1.y * ea + b1y * eb;
    a1.z = a1.z * ea + b1z * eb; a1.w = a1.w * ea + b1w * eb;
    m = fmaxf(m, m2);
  }
  if (g == 0) {
    float inv = 1.f / fmaxf(l, 1e-16f);
    uint4 w = make_uint4(packbf(a0.x * inv, a0.y * inv), packbf(a0.z * inv, a0.w * inv),
                         packbf(a1.x * inv, a1.y * inv), packbf(a1.z * inv, a1.w * inv));
    *(uint4*)(ho16 + (size_t)n * HF + fl * 8) = w;
  }
}

// z[m][0:128] = segment_min(ho16[node]) (0 if empty); z[m][128:256] = xe[m]
__global__ __launch_bounds__(256) void seg_min_z(const unsigned short* __restrict__ ho16,
                                                 const int* __restrict__ off_e,
                                                 const unsigned short* __restrict__ by_h,
                                                 const float* __restrict__ xe,
                                                 float* __restrict__ z, int M) {
  int m = (blockIdx.x * blockDim.x + threadIdx.x) >> 6;
  if (m >= M) return;
  int lane = threadIdx.x & 63;
  int g = lane >> 4;
  int fl = lane & 15;
  int s = off_e[m], e1 = off_e[m + 1];
  float4 a0 = make_float4(FLT_MAX, FLT_MAX, FLT_MAX, FLT_MAX), a1 = a0;
  uint4 z4 = make_uint4(0, 0, 0, 0);
  int j = s + g;
  int iC = (j + 8 < e1) ? by_h[j + 8] : 0;
  uint4 hwA = z4, hwB = z4;
  if (j < e1) {
    int i0 = by_h[j];
    hwA = *(const uint4*)(ho16 + (size_t)i0 * HF + fl * 8);
  }
  if (j + 4 < e1) {
    int i1 = by_h[j + 4];
    hwB = *(const uint4*)(ho16 + (size_t)i1 * HF + fl * 8);
  }
  while (j < e1) {
    uint4 hwC = z4;
    if (j + 8 < e1) hwC = *(const uint4*)(ho16 + (size_t)iC * HF + fl * 8);
    int iD = (j + 12 < e1) ? by_h[j + 12] : 0;
    a0.x = fminf(a0.x, BFLO(hwA.x)); a0.y = fminf(a0.y, BFHI(hwA.x));
    a0.z = fminf(a0.z, BFLO(hwA.y)); a0.w = fminf(a0.w, BFHI(hwA.y));
    a1.x = fminf(a1.x, BFLO(hwA.z)); a1.y = fminf(a1.y, BFHI(hwA.z));
    a1.z = fminf(a1.z, BFLO(hwA.w)); a1.w = fminf(a1.w, BFHI(hwA.w));
    hwA = hwB; hwB = hwC; iC = iD;
    j += 4;
  }
#pragma unroll
  for (int mask = 16; mask <= 32; mask <<= 1) {
    a0.x = fminf(a0.x, __shfl_xor(a0.x, mask)); a0.y = fminf(a0.y, __shfl_xor(a0.y, mask));
    a0.z = fminf(a0.z, __shfl_xor(a0.z, mask)); a0.w = fminf(a0.w, __shfl_xor(a0.w, mask));
    a1.x = fminf(a1.x, __shfl_xor(a1.x, mask)); a1.y = fminf(a1.y, __shfl_xor(a1.y, mask));
    a1.z = fminf(a1.z, __shfl_xor(a1.z, mask)); a1.w = fminf(a1.w, __shfl_xor(a1.w, mask));
  }
  if (g == 0) {
    bool nz = (e1 > s);
    float* op = z + (size_t)m * 256 + fl * 8;
    *(float4*)op = nz ? a0 : make_float4(0.f, 0.f, 0.f, 0.f);
    *(float4*)(op + 4) = nz ? a1 : make_float4(0.f, 0.f, 0.f, 0.f);
  } else if (g == 1) {
    const float* xp = xe + (size_t)m * HF + fl * 8;
    float* op = z + (size_t)m * 256 + 128 + fl * 8;
    *(float4*)op = *(const float4*)xp;
    *(float4*)(op + 4) = *(const float4*)(xp + 4);
  }
}

// ---------------- GraphNorm stats: two-kernel deterministic reduction ----------------

__global__ __launch_bounds__(1024) void colstats_part(const float* __restrict__ z, int rows, int C,
                                                      float* __restrict__ part) {
  int tid = threadIdx.x;
  int RL = 1024 / C;
  int col = tid & (C - 1);
  int ro = tid / C;
  float s1 = 0.f, s2 = 0.f;
  for (int r = blockIdx.x * RL + ro; r < rows; r += gridDim.x * RL) {
    float v = z[(size_t)r * C + col];
    s1 += v;
    s2 += v * v;
  }
  __shared__ float l1[1024], l2[1024];
  l1[tid] = s1;
  l2[tid] = s2;
  __syncthreads();
  for (int off = 512; off >= C; off >>= 1) {
    if (tid < off) { l1[tid] += l1[tid + off]; l2[tid] += l2[tid + off]; }
    __syncthreads();
  }
  if (tid < C) {
    part[(size_t)blockIdx.x * 2 * C + tid] = l1[tid];
    part[(size_t)blockIdx.x * 2 * C + C + tid] = l2[tid];
  }
}

__global__ void colstats_fin(const float* __restrict__ part, int nb, int C,
                             const float* __restrict__ w, const float* __restrict__ b,
                             const float* __restrict__ a, float invrows,
                             float* __restrict__ sc, float* __restrict__ sh) {
  int col = threadIdx.x;
  if (col >= C) return;
  float s1 = 0.f, s2 = 0.f;
#pragma unroll 8
  for (int i = 0; i < nb; ++i) {
    s1 += part[(size_t)i * 2 * C + col];
    s2 += part[(size_t)i * 2 * C + C + col];
  }
  float mu = s1 * invrows;
  float ex2 = s2 * invrows;
  float av = a[col];
  float var = ex2 - 2.f * av * mu * mu + av * av * mu * mu;
  float s = w[col] * rsqrtf(var + 1e-5f);
  sc[col] = s;
  sh[col] = b[col] - av * mu * s;
}

// ---------------- launch ----------------

extern "C" void kernel_launch(void* const* d_in, const int* in_sizes, int n_in,
                              void* d_out, int out_size, void* d_ws, size_t ws_size,
                              hipStream_t stream) {
  const float* x        = (const float*)d_in[0];
  const float* x_e      = (const float*)d_in[2];
  const int*   node_idx = (const int*)d_in[3];
  const int*   hedge_idx= (const int*)d_in[4];
  const float* her_W1   = (const float*)d_in[5];
  const float* her_b1   = (const float*)d_in[6];
  const float* her_W2   = (const float*)d_in[7];
  const float* her_b2   = (const float*)d_in[8];
  const float* sr_W1    = (const float*)d_in[9];
  const float* sr_b1    = (const float*)d_in[10];
  const float* sr_W2    = (const float*)d_in[11];
  const float* sr_b2    = (const float*)d_in[12];
  const float* att_Wq   = (const float*)d_in[13];
  const float* att_Wk   = (const float*)d_in[14];
  const float* att_Wv   = (const float*)d_in[15];
  const float* ef_W     = (const float*)d_in[16];
  const float* ef_b     = (const float*)d_in[17];
  const float* gn1_w    = (const float*)d_in[18];
  const float* gn1_b    = (const float*)d_in[19];
  const float* gn1_a    = (const float*)d_in[20];
  const float* gn2_w    = (const float*)d_in[21];
  const float* gn2_b    = (const float*)d_in[22];
  const float* gn2_a    = (const float*)d_in[23];
  const float* cls_W1   = (const float*)d_in[24];
  const float* cls_b1   = (const float*)d_in[25];
  const float* cls_W2   = (const float*)d_in[26];
  const float* cls_b2   = (const float*)d_in[27];

  const int N = in_sizes[0] / HF;
  const int M = in_sizes[2] / HF;
  const int E = in_sizes[3];
  const int NVR = idiv(N, VRANGE);  // node range count (2 for N=50000)

  // ---- workspace layout (nothing needs zeroing: counting sort writes every cell) ----
  char* wp = (char*)d_ws;
  float* part1 = (float*)wp; wp += (size_t)CS_GRID * 512 * 4;  // gn1 partials (2*256 per blk)
  float* part2 = (float*)wp; wp += (size_t)CS_GRID * 256 * 4;  // gn2 partials (2*128 per blk)
  int* cnt_e = (int*)wp; wp += (size_t)M * 4;
  int* cnt_v = (int*)wp; wp += (size_t)N * 4;
  int* off_e = (int*)wp; wp += (size_t)(M + 1) * 4;
  int* off_v = (int*)wp; wp += (size_t)(N + 1) * 4;
  unsigned short* by_h = (unsigned short*)wp; wp += ((size_t)E * 2 + 3) & ~(size_t)3;
  unsigned short* by_v = (unsigned short*)wp; wp += ((size_t)E * 2 + 3) & ~(size_t)3;
  int* part_e = (int*)wp; wp += 257 * 4;
  int* part_v = (int*)wp; wp += 257 * 4;
  float* sc1 = (float*)wp; wp += 256 * 4;
  float* sh1 = (float*)wp; wp += 256 * 4;
  float* sc2 = (float*)wp; wp += 128 * 4;
  float* sh2 = (float*)wp; wp += 128 * 4;
  wp = (char*)(((uintptr_t)wp + 255) & ~(uintptr_t)255);
  float* wqt  = (float*)wp; wp += (size_t)128 * 128 * 4;   // Wq^T * scale
  float* wcat = (float*)wp; wp += (size_t)128 * 256 * 4;   // [Wqk | Wv]
  float* h   = (float*)wp; wp += (size_t)N * HF * 4;       // sr1 out, += m_v, sr2 in; later c1
  float* h2  = (float*)wp; wp += (size_t)N * HF * 4;       // sr2 out = q; later z [M,256]
  float* xe  = (float*)wp; wp += (size_t)M * HF * 4;
  float* kvf = (float*)wp; wp += (size_t)M * 256 * 4;      // t1 fp32 alias / kv bf16
  float* z2  = (float*)wp; wp += (size_t)M * HF * 4;
  unsigned short* h16   = (unsigned short*)wp; wp += (size_t)N * HF * 2;  // sr1 bf16 shadow
  unsigned short* ho16  = (unsigned short*)wp; wp += (size_t)N * HF * 2;  // att out bf16
  unsigned short* m_e16 = (unsigned short*)wp; wp += (size_t)M * HF * 2;

  unsigned short* kv = (unsigned short*)kvf;   // [M][256] bf16
  float* t1  = kvf;                // her hidden [M,128] fp32 (dead before kv written)
  float* z   = h2;                 // [M,256] (h2 dead as q after att_fused)
  float* c1  = h;                  // [M,128] (h dead after sr2)

  // Histogram matrices alias h (dead until sr1): NB*M + NVR*NB*VPACK ints = 17.9MB < 25.6MB
  int* HE = (int*)h;
  int* HV = HE + (size_t)NB_CSR * M;

  // ---- CSR build: counting sort, zero device-scope atomics ----
  csr_hist<<<dim3(NB_CSR, 1 + NVR), 512, 0, stream>>>(node_idx, hedge_idx, E, M, HE, HV);
  csr_colscan<<<idiv(M + NVR * VPACK, 256), 256, 0, stream>>>(HE, HV, M, N, NVR, cnt_e, cnt_v);
  int nbE = idiv(M, SCAN_CHUNK);
  int nbV = idiv(N, SCAN_CHUNK);
  scanA2<<<nbE + nbV, 256, 0, stream>>>(cnt_e, M, nbE, part_e, cnt_v, N, part_v);
  scanB2<<<2, 256, 0, stream>>>(part_e, nbE, part_v, nbV);
  scanC2<<<nbE + nbV, 256, 0, stream>>>(cnt_e, M, nbE, part_e, off_e, cnt_v, N, nbV, part_v, off_v);
  csr_scatter<<<dim3(NB_CSR, 1 + NVR), 512, 0, stream>>>(node_idx, hedge_idx, E, M, HE, HV,
                                                         off_e, off_v, by_h, by_v);

  // wqt = Wq^T*scale, wcat[:,128:256] = Wv
  prep_att<<<64, 256, 0, stream>>>(att_Wq, att_Wv, wqt, wcat);

  dim3 blk(256);
  int nbxN = idiv(N, 64), nbxM = idiv(M, 64);

  // ---- Phase A (fused): sr1 (fp32 + bf16 shadow; overwrites HE/HV) || her1 || wcatK ----
  GArgs gsr1 = {x, sr_W1, sr_b1, h, N, HF, HF, 1, nullptr, nullptr, 0, HF, 0, h16, nbxN, nbxN * 2};
  GArgs gher1 = {x_e, her_W1, her_b1, t1, M, HF, HF, 1, nullptr, nullptr, 0, HF, 0, nullptr, nbxM, nbxM * 2};
  GArgs gwk = {att_Wk, wqt, nullptr, wcat, 128, 128, 128, 0, nullptr, nullptr, 0, 256, 0, nullptr, 2, 4};
  gemm64_multi<<<gsr1.nb + gher1.nb + gwk.nb, blk, 0, stream>>>(gsr1, gher1, gwk);

  // ---- Phase B (fused): her2 || seg_mean_e (bf16 gather) ----
  GArgs gher2 = {t1, her_W2, her_b2, xe, M, HF, HF, 0, nullptr, nullptr, 0, HF, 0, nullptr, nbxM, nbxM * 2};
  gemm_segmean<<<gher2.nb + idiv(M * 64, 256), blk, 0, stream>>>(gher2, h16, off_e, by_h, m_e16, M);

  seg_mean_v_add<<<idiv(N * 64, 256), blk, 0, stream>>>(h, m_e16, off_v, by_v, N);

  // ---- Phase C (fused): sr2 -> h2 (q) || kv projection [xe@Wqk | xe@Wv] bf16 ----
  GArgs gsr2 = {h, sr_W2, sr_b2, h2, N, HF, HF, 1, nullptr, nullptr, 0, HF, 0, nullptr, nbxN, nbxN * 2};
  GArgs gkv = {xe, wcat, nullptr, (float*)kv, M, HF, 256, 0, nullptr, nullptr, 0, 256, 1, nullptr, nbxM, nbxM * 4};
  gemm64_multi<<<gsr2.nb + gkv.nb, blk, 0, stream>>>(gsr2, gkv, gkv);

  // fused attention (q = h2)
  att_fused<<<idiv(N * 64, 256), blk, 0, stream>>>(h2, kv, off_v, by_v, ho16, N);
  // min aggregation + concat (z overwrites h2)
  seg_min_z<<<idiv(M * 64, 256), blk, 0, stream>>>(ho16, off_e, by_h, xe, z, M);
  // gn1 stats (partials + finalize) -> ef linear(+act) -> gn2 stats
  colstats_part<<<CS_GRID, 1024, 0, stream>>>(z, M, 256, part1);
  colstats_fin<<<1, 256, 0, stream>>>(part1, CS_GRID, 256, gn1_w, gn1_b, gn1_a,
                                      1.f / (float)M, sc1, sh1);
  GArgs gef = {z, ef_W, ef_b, z2, M, 2 * HF, HF, 1, sc1, sh1, 0, HF, 0, nullptr, nbxM, nbxM * 2};
  gemm64<<<gef.nb, blk, 0, stream>>>(gef);
  colstats_part<<<CS_GRID, 1024, 0, stream>>>(z2, M, 128, part2);
  colstats_fin<<<1, 128, 0, stream>>>(part2, CS_GRID, 128, gn2_w, gn2_b, gn2_a,
                                      1.f / (float)M, sc2, sh2);
  // classifier
  GArgs gc1 = {z2, cls_W1, cls_b1, c1, M, HF, HF, 1, sc2, sh2, 1, HF, 0, nullptr, nbxM, nbxM * 2};
  gemm64<<<gc1.nb, blk, 0, stream>>>(gc1);
  GArgs gc2 = {c1, cls_W2, cls_b2, (float*)d_out, M, HF, 64, 0, nullptr, nullptr, 0, 64, 0, nullptr, nbxM, nbxM};
  gemm64<<<gc2.nb, blk, 0, stream>>>(gc2);
}